// Round 7
// baseline (2507.123 us; speedup 1.0000x reference)
//
#include <hip/hip_runtime.h>
#include <hip/hip_bf16.h>

#define NROWS 4096    // B*S
#define DDIM  1024
#define MKEYS 32768
#define HDIM  128
#define KSEL  16
#define NCAND 32      // rescored candidates per row

// ---- sims MFMA GEMM geometry: m97-style 128x128 tile, 4 waves, 32KB LDS, ~3 blocks/CU ----
#define SBM 128
#define SBN 128
#define SNKB (MKEYS / SBN)            // 256 key blocks
#define CANDS_PER_ROW (SNKB * KSEL)   // 4096
#define NSTEPS 16                     // K = 1024 bf16, BK = 64

typedef short bf16x8 __attribute__((ext_vector_type(8)));
typedef float f32x4  __attribute__((ext_vector_type(4)));

__device__ __forceinline__ float bf2f(unsigned short u) {
    union { unsigned int i; float f; } x; x.i = ((unsigned int)u) << 16; return x.f;
}
__device__ __forceinline__ unsigned short f2bf(float f) {
    union { float f; unsigned int u; } v; v.f = f;
    unsigned int r = (v.u + 0x7fffu + ((v.u >> 16) & 1u)) >> 16;   // RNE
    return (unsigned short)r;
}
__device__ __forceinline__ void gload16(const void* g, const void* l) {
    __builtin_amdgcn_global_load_lds((const __attribute__((address_space(1))) unsigned int*)g,
                                     (__attribute__((address_space(3))) unsigned int*)l, 16, 0, 0);
}
// sorted-descending top-N insertion, fully static indexing (no scratch)
template <int N>
__device__ __forceinline__ void insN(float v, int id, float* lv, int* li) {
    if (v > lv[N - 1]) {
#pragma unroll
        for (int i = 0; i < N; ++i) {
            const bool gt = v > lv[i];
            const float tv = gt ? lv[i] : v;
            const int   ti = gt ? li[i] : id;
            if (gt) { lv[i] = v; li[i] = id; }
            v = tv; id = ti;
        }
    }
}
// trunc-hi / RNE-lo split of two fp32 -> packed bf16 pair words
__device__ __forceinline__ void split2(float x0, float x1, unsigned int& hp, unsigned int& lp) {
    union { float f; unsigned int u; } u0, u1;
    u0.f = x0; u1.f = x1;
    hp = (u0.u >> 16) | (u1.u & 0xffff0000u);
    const float r0 = x0 - bf2f((unsigned short)(u0.u >> 16));
    const float r1 = x1 - bf2f((unsigned short)(u1.u >> 16));
    lp = (unsigned int)f2bf(r0) | ((unsigned int)f2bf(r1) << 16);
}

// ---------------- Kernel 0a: fp32 -> bf16 (RNE) ----------------
__global__ __launch_bounds__(256)
void conv_bf16_kernel(const float* __restrict__ x, unsigned short* __restrict__ hi, const int n4)
{
    int i = blockIdx.x * 256 + threadIdx.x;
    const int stride = gridDim.x * 256;
    for (; i < n4; i += stride) {
        const float4 f = ((const float4*)x)[i];
        ushort4 h;
        h.x = f2bf(f.x); h.y = f2bf(f.y); h.z = f2bf(f.z); h.w = f2bf(f.w);
        ((ushort4*)hi)[i] = h;
    }
}

// ---------------- Kernel 0b: fp32 -> (hi, lo) bf16 split (weights) ----------------
__global__ __launch_bounds__(256)
void split_bf16_kernel(const float* __restrict__ x, unsigned short* __restrict__ hi,
                       unsigned short* __restrict__ lo, const int n4)
{
    int i = blockIdx.x * 256 + threadIdx.x;
    const int stride = gridDim.x * 256;
    for (; i < n4; i += stride) {
        const float4 f = ((const float4*)x)[i];
        ushort4 h, l;
        h.x = f2bf(f.x); l.x = f2bf(f.x - bf2f(h.x));
        h.y = f2bf(f.y); l.y = f2bf(f.y - bf2f(h.y));
        h.z = f2bf(f.z); l.z = f2bf(f.z - bf2f(h.z));
        h.w = f2bf(f.w); l.w = f2bf(f.w - bf2f(h.w));
        ((ushort4*)hi)[i] = h;
        ((ushort4*)lo)[i] = l;
    }
}

// ---------------- Kernel A: sims(bf16) = Qhi.Khi^T, 128x128 single-buffer (m97 structure) ----------------
// 4 waves as 2x2 (wave tile 64x64, acc 4x4). LDS 32KB: A[128][64]bf16 @0, B[128][64] @16KB.
// Loop: sync -> stage(gload_lds x8/thread) -> sync(vmcnt drain) -> 32 MFMA/wave. ~3 blocks/CU
// hide the barrier drain via cross-block overlap (m114). Epilogue: [128][33] f32 C-tile, stride-33
// scalar scans (conflict-free), top-16 per 128-key block.
__global__ __launch_bounds__(256, 3)
void sims_mfma_kernel(const unsigned short* __restrict__ Qhi, const unsigned short* __restrict__ Khi,
                      float* __restrict__ cand_val, int* __restrict__ cand_idx)
{
    __shared__ char smem[32768];
    const int tid  = threadIdx.x;
    const int lane = tid & 63;
    const int w    = tid >> 6;
    const int wr   = w >> 1, wc = w & 1;
    const int row0 = blockIdx.x * SBM;
    const int key0 = blockIdx.y * SBN;

    const f32x4 zero = {0.f, 0.f, 0.f, 0.f};
    f32x4 acc[4][4];
#pragma unroll
    for (int mi = 0; mi < 4; ++mi)
#pragma unroll
        for (int ni = 0; ni < 4; ++ni) acc[mi][ni] = zero;

    const int srow = lane >> 3;
    const int scol = (((lane & 7) ^ srow) << 4);      // pre-swizzled source byte col

#pragma unroll 1
    for (int step = 0; step < NSTEPS; ++step) {
        const int kbyte = step << 7;
        __syncthreads();                               // prev compute's LDS reads retired
#pragma unroll
        for (int i = 0; i < 8; ++i) {
            const int chunk = w + (i << 2);            // 0..31, wave-uniform
            const char* src;
            if (chunk < 16) {                          // A: rows 0..127
                const int r = (chunk << 3) + srow;
                src = (const char*)Qhi + (((size_t)(row0 + r)) << 11) + kbyte + scol;
            } else {                                   // B: keys 0..127
                const int r = ((chunk - 16) << 3) + srow;
                src = (const char*)Khi + (((size_t)(key0 + r)) << 11) + kbyte + scol;
            }
            gload16(src, smem + (chunk << 10));
        }
        __syncthreads();                               // staging landed (vmcnt drained)
#pragma unroll
        for (int kk = 0; kk < 2; ++kk) {
            const int cb = (kk << 6) + ((lane >> 4) << 4);
            bf16x8 af[4], bf[4];
#pragma unroll
            for (int mi = 0; mi < 4; ++mi) {
                const int r = wr * 64 + mi * 16 + (lane & 15);
                af[mi] = *(const bf16x8*)(smem + r * 128 + (cb ^ ((r & 7) << 4)));
            }
#pragma unroll
            for (int ni = 0; ni < 4; ++ni) {
                const int r = wc * 64 + ni * 16 + (lane & 15);
                bf[ni] = *(const bf16x8*)(smem + 16384 + r * 128 + (cb ^ ((r & 7) << 4)));
            }
#pragma unroll
            for (int mi = 0; mi < 4; ++mi)
#pragma unroll
                for (int ni = 0; ni < 4; ++ni)
                    acc[mi][ni] = __builtin_amdgcn_mfma_f32_16x16x32_bf16(af[mi], bf[ni], acc[mi][ni], 0, 0, 0);
        }
    }

    // ---- fused top-16 epilogue: 4 passes of 32 cols through LDS C tile [128][33] f32 ----
    float lv[16]; int li[16];
#pragma unroll
    for (int i = 0; i < 16; ++i) { lv[i] = -3.4e38f; li[i] = 0; }
    float* C_lds = (float*)smem;

#pragma unroll
    for (int q = 0; q < 4; ++q) {
        __syncthreads();
        if (wc == (q >> 1)) {                          // 2 waves own these 32 global cols
#pragma unroll
            for (int mi = 0; mi < 4; ++mi)
#pragma unroll
                for (int nn = 0; nn < 2; ++nn) {
                    const int ni = ((q & 1) << 1) + nn;
                    const int r  = wr * 64 + mi * 16 + ((lane >> 4) << 2);
                    const int c  = (nn << 4) + (lane & 15);
                    const f32x4 v = acc[mi][ni];
#pragma unroll
                    for (int j = 0; j < 4; ++j) C_lds[(r + j) * 33 + c] = v[j];
                }
        }
        __syncthreads();
        if (tid < 128) {                               // thread t scans row t (stride 33: conflict-free)
            const int gbase = key0 + (q << 5);
#pragma unroll
            for (int half = 0; half < 2; ++half) {
                float tmp[16];
#pragma unroll
                for (int cc = 0; cc < 16; ++cc) tmp[cc] = C_lds[tid * 33 + (half << 4) + cc];
#pragma unroll
                for (int cc = 0; cc < 16; ++cc) insN<16>(tmp[cc], gbase + (half << 4) + cc, lv, li);
            }
        }
    }
    if (tid < 128) {
        const size_t o = (((size_t)(row0 + tid)) * SNKB + blockIdx.y) * KSEL;
#pragma unroll
        for (int i = 0; i < 16; ++i) { cand_val[o + i] = lv[i]; cand_idx[o + i] = li[i]; }
    }
}

// ---------------- Kernel B: merge 256x16 candidates -> top-32 (bf16 scores) per row ----------------
__global__ __launch_bounds__(256)
void topk_merge_kernel(const float* __restrict__ cand_val, const int* __restrict__ cand_idx,
                       int* __restrict__ cand32)
{
    const int row  = blockIdx.x * 4 + (threadIdx.x >> 6);
    const int lane = threadIdx.x & 63;
    const size_t base = (size_t)row * CANDS_PER_ROW;
    float lv[NCAND]; int li[NCAND];
#pragma unroll
    for (int i = 0; i < NCAND; ++i) { lv[i] = -3.4e38f; li[i] = 0x7fffffff; }
#pragma unroll 1
    for (int m = 0; m < CANDS_PER_ROW / 64; ++m) {                // 64 per lane
        const int p = lane + (m << 6);
        insN<NCAND>(cand_val[base + p], cand_idx[base + p], lv, li);
    }
    int out = 0;
#pragma unroll 1
    for (int it = 0; it < NCAND; ++it) {
        float rv = lv[0]; int ridx = li[0];
#pragma unroll
        for (int off = 1; off < 64; off <<= 1) {
            const float ov = __shfl_xor(rv, off);
            const int   oi = __shfl_xor(ridx, off);
            if (ov > rv || (ov == rv && oi < ridx)) { rv = ov; ridx = oi; }
        }
        if (lane == it) out = ridx;
        if (li[0] == ridx) {
#pragma unroll
            for (int i = 0; i < NCAND - 1; ++i) { lv[i] = lv[i + 1]; li[i] = li[i + 1]; }
            lv[NCAND - 1] = -3.4e38f; li[NCAND - 1] = 0x7fffffff;
        }
    }
    if (lane < NCAND) cand32[(size_t)row * NCAND + lane] = out;
}

// ---------------- Kernel B2: exact fp32 rescore of 32 candidates -> final top-16 ----------------
__global__ __launch_bounds__(256)
void rescore_kernel(const float* __restrict__ Q, const float* __restrict__ K,
                    const int* __restrict__ cand32, int* __restrict__ topk)
{
    const int row  = blockIdx.x;
    const int wv   = threadIdx.x >> 6;
    const int lane = threadIdx.x & 63;
    __shared__ float sv[NCAND];
    __shared__ int   si[NCAND];
    if (threadIdx.x < NCAND) si[threadIdx.x] = cand32[(size_t)row * NCAND + threadIdx.x];
    float4 qv[4];
#pragma unroll
    for (int u = 0; u < 4; ++u)
        qv[u] = ((const float4*)(Q + (size_t)row * DDIM))[(u << 6) + lane];
    __syncthreads();
#pragma unroll 1
    for (int c = 0; c < 8; ++c) {
        const int slot = wv * 8 + c;
        const float* kr = K + (size_t)si[slot] * DDIM;
        float s = 0.f;
#pragma unroll
        for (int u = 0; u < 4; ++u) {
            const float4 kv = ((const float4*)kr)[(u << 6) + lane];
            s += kv.x * qv[u].x + kv.y * qv[u].y + kv.z * qv[u].z + kv.w * qv[u].w;
        }
#pragma unroll
        for (int off = 32; off >= 1; off >>= 1) s += __shfl_xor(s, off);
        if (lane == 0) sv[slot] = s;
    }
    __syncthreads();
    if (wv == 0) {
        float v = (lane < NCAND) ? sv[lane] : -3.4e38f;
        int  id = (lane < NCAND) ? si[lane] : 0x7fffffff;
        int out = 0;
#pragma unroll 1
        for (int it = 0; it < KSEL; ++it) {
            float rv = v; int ridx = id;
#pragma unroll
            for (int off = 1; off < 64; off <<= 1) {
                const float ov = __shfl_xor(rv, off);
                const int   oi = __shfl_xor(ridx, off);
                if (ov > rv || (ov == rv && oi < ridx)) { rv = ov; ridx = oi; }
            }
            if (lane == it) out = ridx;
            if (id == ridx) v = -3.4e38f;
        }
        if (lane < KSEL) topk[(size_t)row * KSEL + lane] = out;
    }
}

// ---------------- Kernel C: projections via split-bf16 MFMA; LO=1 3-term, LO=0 1-term (48KB LDS) ----------------
template <int LO>
__global__ __launch_bounds__(256)
void proj_split_kernel(const float* __restrict__ X, const unsigned short* __restrict__ Whi,
                       const unsigned short* __restrict__ Wlo, const float* __restrict__ bias,
                       void* __restrict__ outp, const int store_bf16)
{
    __shared__ char smem[LO ? 65536 : 49152];
    const int tid  = threadIdx.x;
    const int lane = tid & 63;
    const int w    = tid >> 6;
    const int wr   = w >> 1, wc = w & 1;
    const int row0 = blockIdx.x * 128;
    const int col0 = blockIdx.y * 128;

    const f32x4 zero = {0.f, 0.f, 0.f, 0.f};
    f32x4 acc[4][4];
#pragma unroll
    for (int mi = 0; mi < 4; ++mi)
#pragma unroll
        for (int ni = 0; ni < 4; ++ni) acc[mi][ni] = zero;

    const int srow = lane >> 3;
    const int scol = (((lane & 7) ^ srow) << 4);
    const int xr = tid >> 1, xh = tid & 1;

    for (int step = 0; step < 16; ++step) {
        const int kbyte = step << 7;
        const int k0    = step << 6;
        __syncthreads();
#pragma unroll
        for (int i = 0; i < (LO ? 8 : 4); ++i) {
            const int chunk = w + (i << 2);            // 0..31 (LO) or 0..15
            const int plane = chunk >> 4;
            const int r     = ((chunk & 15) << 3) + srow;
            const unsigned short* Wb = plane ? Wlo : Whi;
            const char* src = (const char*)Wb + (((size_t)(col0 + r)) << 11) + kbyte + scol;
            gload16(src, smem + 32768 + (chunk << 10));
        }
        {
            const float* Xp = X + (size_t)(row0 + xr) * DDIM + k0 + xh * 32;
            float4 xa[8];
#pragma unroll
            for (int i = 0; i < 8; ++i) xa[i] = ((const float4*)Xp)[i];
            const int xbase = xr * 128;
#pragma unroll
            for (int s4 = 0; s4 < 4; ++s4) {
                const float4 a = xa[2 * s4], b = xa[2 * s4 + 1];
                uint4 hw, lw;
                if (LO) {
                    split2(a.x, a.y, hw.x, lw.x);
                    split2(a.z, a.w, hw.y, lw.y);
                    split2(b.x, b.y, hw.z, lw.z);
                    split2(b.z, b.w, hw.w, lw.w);
                } else {
                    hw.x = (unsigned int)f2bf(a.x) | ((unsigned int)f2bf(a.y) << 16);
                    hw.y = (unsigned int)f2bf(a.z) | ((unsigned int)f2bf(a.w) << 16);
                    hw.z = (unsigned int)f2bf(b.x) | ((unsigned int)f2bf(b.y) << 16);
                    hw.w = (unsigned int)f2bf(b.z) | ((unsigned int)f2bf(b.w) << 16);
                }
                const int off = xbase + ((((xh << 2) + s4) ^ (xr & 7)) << 4);
                *(uint4*)(smem + off) = hw;
                if (LO) *(uint4*)(smem + 16384 + off) = lw;
            }
        }
        asm volatile("s_waitcnt vmcnt(0)" ::: "memory");
        __syncthreads();
#pragma unroll
        for (int kk = 0; kk < 2; ++kk) {
            const int cb = (kk << 6) + ((lane >> 4) << 4);
            bf16x8 ah[4], bh[4];
#pragma unroll
            for (int mi = 0; mi < 4; ++mi) {
                const int r = wr * 64 + mi * 16 + (lane & 15);
                ah[mi] = *(const bf16x8*)(smem + r * 128 + (cb ^ ((r & 7) << 4)));
            }
#pragma unroll
            for (int ni = 0; ni < 4; ++ni) {
                const int r = wc * 64 + ni * 16 + (lane & 15);
                bh[ni] = *(const bf16x8*)(smem + 32768 + r * 128 + (cb ^ ((r & 7) << 4)));
            }
#pragma unroll
            for (int mi = 0; mi < 4; ++mi)
#pragma unroll
                for (int ni = 0; ni < 4; ++ni)
                    acc[mi][ni] = __builtin_amdgcn_mfma_f32_16x16x32_bf16(ah[mi], bh[ni], acc[mi][ni], 0, 0, 0);
            if (LO) {
                bf16x8 al[4];
#pragma unroll
                for (int mi = 0; mi < 4; ++mi) {
                    const int r = wr * 64 + mi * 16 + (lane & 15);
                    al[mi] = *(const bf16x8*)(smem + 16384 + r * 128 + (cb ^ ((r & 7) << 4)));
                }
#pragma unroll
                for (int mi = 0; mi < 4; ++mi)
#pragma unroll
                    for (int ni = 0; ni < 4; ++ni)
                        acc[mi][ni] = __builtin_amdgcn_mfma_f32_16x16x32_bf16(al[mi], bh[ni], acc[mi][ni], 0, 0, 0);
                bf16x8 bl[4];
#pragma unroll
                for (int ni = 0; ni < 4; ++ni) {
                    const int r = wc * 64 + ni * 16 + (lane & 15);
                    bl[ni] = *(const bf16x8*)(smem + 49152 + r * 128 + (cb ^ ((r & 7) << 4)));
                }
#pragma unroll
                for (int mi = 0; mi < 4; ++mi)
#pragma unroll
                    for (int ni = 0; ni < 4; ++ni)
                        acc[mi][ni] = __builtin_amdgcn_mfma_f32_16x16x32_bf16(ah[mi], bl[ni], acc[mi][ni], 0, 0, 0);
            }
        }
    }

#pragma unroll
    for (int ni = 0; ni < 4; ++ni) {
        const int col = col0 + wc * 64 + ni * 16 + (lane & 15);
        const float bz = bias[col];
#pragma unroll
        for (int mi = 0; mi < 4; ++mi) {
            const int rbase = row0 + wr * 64 + mi * 16 + ((lane >> 4) << 2);
            const f32x4 v = acc[mi][ni];
#pragma unroll
            for (int j = 0; j < 4; ++j) {
                const float val = v[j] + bz;
                if (store_bf16)
                    ((unsigned short*)outp)[(size_t)(rbase + j) * DDIM + col] = f2bf(val);
                else
                    ((float*)outp)[(size_t)(rbase + j) * DDIM + col] = val;
            }
        }
    }
}

// ---------------- Kernel D: per-token 8-head attention over 16 retrieved slots ----------------
__global__ __launch_bounds__(256)
void attn_kernel(const float* __restrict__ Qp, const __hip_bfloat16* __restrict__ Kp,
                 const __hip_bfloat16* __restrict__ Vp, const int* __restrict__ topk,
                 float* __restrict__ attn_out)
{
    const int t = blockIdx.x;
    __shared__ int   idx_s[KSEL];
    __shared__ float sc_s[4][KSEL];
    if (threadIdx.x < KSEL) idx_s[threadIdx.x] = topk[(size_t)t * KSEL + threadIdx.x];
    __syncthreads();
    const int wv   = threadIdx.x >> 6;
    const int lane = threadIdx.x & 63;
    const int jj = lane >> 2, p = lane & 3;
    const float scale = 0.08838834764831845f;  // 1/sqrt(128)
    const unsigned short* Kpu = (const unsigned short*)Kp;
    const unsigned short* Vpu = (const unsigned short*)Vp;

#pragma unroll 1
    for (int hh = 0; hh < 2; ++hh) {
        const int h = wv * 2 + hh;
        const float* qh = Qp + (size_t)t * DDIM + h * HDIM + p * 32;
        const unsigned short* krow = Kpu + (size_t)idx_s[jj] * DDIM + h * HDIM + p * 32;
        float s = 0.f;
#pragma unroll
        for (int u = 0; u < 32; u += 8) {
            uint4  kv = *(const uint4*)(krow + u);
            float4 qa = *(const float4*)(qh + u);
            float4 qb = *(const float4*)(qh + u + 4);
            const unsigned short* kk = (const unsigned short*)&kv;
            s += bf2f(kk[0]) * qa.x + bf2f(kk[1]) * qa.y + bf2f(kk[2]) * qa.z + bf2f(kk[3]) * qa.w
               + bf2f(kk[4]) * qb.x + bf2f(kk[5]) * qb.y + bf2f(kk[6]) * qb.z + bf2f(kk[7]) * qb.w;
        }
        s += __shfl_xor(s, 1);
        s += __shfl_xor(s, 2);
        if (p == 0) sc_s[wv][jj] = s * scale;
        __syncthreads();
        float mx = -__builtin_inff();
#pragma unroll
        for (int n = 0; n < KSEL; ++n) mx = fmaxf(mx, sc_s[wv][n]);
        float wj[KSEL]; float wsum = 0.f;
#pragma unroll
        for (int n = 0; n < KSEL; ++n) { wj[n] = __expf(sc_s[wv][n] - mx); wsum += wj[n]; }
        const float inv = 1.f / wsum;
        const int d = lane * 2;
        float o0 = 0.f, o1 = 0.f;
#pragma unroll
        for (int n = 0; n < KSEL; ++n) {
            const unsigned int vv = *(const unsigned int*)(Vpu + (size_t)idx_s[n] * DDIM + h * HDIM + d);
            const float w = wj[n] * inv;
            o0 += w * bf2f((unsigned short)(vv & 0xffffu));
            o1 += w * bf2f((unsigned short)(vv >> 16));
        }
        *(float2*)(attn_out + (size_t)t * DDIM + h * HDIM + d) = make_float2(o0, o1);
        __syncthreads();
    }
}

extern "C" void kernel_launch(void* const* d_in, const int* in_sizes, int n_in,
                              void* d_out, int out_size, void* d_ws, size_t ws_size,
                              hipStream_t stream)
{
    const float* queries = (const float*)d_in[0];
    const float* mkeys   = (const float*)d_in[1];
    const float* mvals   = (const float*)d_in[2];
    const float* ipw     = (const float*)d_in[3];
    const float* ipb     = (const float*)d_in[4];
    const float* opw     = (const float*)d_in[5];
    const float* opb     = (const float*)d_in[6];

    char* ws = (char*)d_ws;
    size_t off = 0;
    auto alloc = [&](size_t bytes) -> char* {
        char* p = ws + off;
        off += (bytes + 255) & ~(size_t)255;
        return p;
    };
    unsigned short* Khi  = (unsigned short*)alloc((size_t)MKEYS * DDIM * 2);    // 67.1 MB
    unsigned short* Qhi  = (unsigned short*)alloc((size_t)NROWS * DDIM * 2);    // 8.4 MB
    unsigned short* IPhi = (unsigned short*)alloc((size_t)3 * DDIM * DDIM * 2); // 6.3 MB
    unsigned short* IPlo = (unsigned short*)alloc((size_t)3 * DDIM * DDIM * 2); // 6.3 MB
    unsigned short* OPhi = (unsigned short*)alloc((size_t)DDIM * DDIM * 2);     // 2.1 MB
    unsigned short* OPlo = (unsigned short*)alloc((size_t)DDIM * DDIM * 2);     // 2.1 MB
    float* cand_val = (float*)alloc((size_t)NROWS * CANDS_PER_ROW * 4);         // 67.1 MB
    int*   cand_idx = (int*)  alloc((size_t)NROWS * CANDS_PER_ROW * 4);         // 67.1 MB
    int*   cand32   = (int*)  alloc((size_t)NROWS * NCAND * 4);                 // 0.52 MB
    int*   topk     = (int*)  alloc((size_t)NROWS * KSEL * 4);                  // 0.26 MB
    // stream-ordered aliases (total ws ~227 MB):
    float* Qp       = (float*)cand_val;                          // cand_val dead after merge
    float* attn_out = (float*)cand_val + (size_t)NROWS * DDIM;   // second 16.8 MB of cand_val
    __hip_bfloat16* Kp = (__hip_bfloat16*)Khi;                   // Khi dead after sims
    __hip_bfloat16* Vp = (__hip_bfloat16*)cand_idx;              // cand_idx dead after merge

    // 0) converts (sims operands, hi-only) + weight splits
    conv_bf16_kernel<<<2048, 256, 0, stream>>>(queries, Qhi, NROWS * DDIM / 4);
    conv_bf16_kernel<<<2048, 256, 0, stream>>>(mkeys, Khi, MKEYS * DDIM / 4);
    split_bf16_kernel<<<1024, 256, 0, stream>>>(ipw, IPhi, IPlo, 3 * DDIM * DDIM / 4);
    split_bf16_kernel<<<512,  256, 0, stream>>>(opw, OPhi, OPlo, DDIM * DDIM / 4);
    // 1) bf16 similarity GEMM + per-keyblock top-16
    sims_mfma_kernel<<<dim3(NROWS / SBM, MKEYS / SBN), 256, 0, stream>>>(Qhi, Khi, cand_val, cand_idx);
    // 2) merge to top-32 candidates (bf16 scores)
    topk_merge_kernel<<<NROWS / 4, 256, 0, stream>>>(cand_val, cand_idx, cand32);
    // 3) exact fp32 rescore -> final top-16
    rescore_kernel<<<NROWS, 256, 0, stream>>>(queries, mkeys, cand32, topk);
    // 4) projections: q (3-term, f32 out), memory bank K/V (1-term, bf16 out)
    proj_split_kernel<1><<<dim3(NROWS / 128, 8), 256, 0, stream>>>(queries, IPhi, IPlo, ipb, Qp, 0);
    proj_split_kernel<0><<<dim3(MKEYS / 128, 8), 256, 0, stream>>>(mkeys, IPhi + (size_t)DDIM * DDIM,
                                                                   IPlo + (size_t)DDIM * DDIM, ipb + DDIM, Kp, 1);
    proj_split_kernel<0><<<dim3(MKEYS / 128, 8), 256, 0, stream>>>(mvals, IPhi + 2 * (size_t)DDIM * DDIM,
                                                                   IPlo + 2 * (size_t)DDIM * DDIM, ipb + 2 * DDIM, Vp, 1);
    // 5) gather + attention
    attn_kernel<<<NROWS, 256, 0, stream>>>(Qp, Kp, Vp, topk, attn_out);
    // 6) output projection (3-term) -> d_out (f32)
    proj_split_kernel<1><<<dim3(NROWS / 128, 8), 256, 0, stream>>>(attn_out, OPhi, OPlo, opb, d_out, 0);
}

// Round 8
// 1585.431 us; speedup vs baseline: 1.5814x; 1.5814x over previous
//
#include <hip/hip_runtime.h>
#include <hip/hip_bf16.h>

#define NROWS 4096    // B*S
#define DDIM  1024
#define MKEYS 32768
#define HDIM  128
#define KSEL  16
#define NCAND 32      // rescored candidates per row

// ---- sims MFMA GEMM geometry: m97-style 128x128 tile, 4 waves, 32KB LDS ----
#define SBM 128
#define SBN 128
#define SNKB (MKEYS / SBN)            // 256 key blocks
#define CANDS_PER_ROW (SNKB * KSEL)   // 4096
#define NSTEPS 16                     // K = 1024 bf16, BK = 64

typedef short bf16x8 __attribute__((ext_vector_type(8)));
typedef float f32x4  __attribute__((ext_vector_type(4)));

__device__ __forceinline__ float bf2f(unsigned short u) {
    union { unsigned int i; float f; } x; x.i = ((unsigned int)u) << 16; return x.f;
}
__device__ __forceinline__ unsigned short f2bf(float f) {
    union { float f; unsigned int u; } v; v.f = f;
    unsigned int r = (v.u + 0x7fffu + ((v.u >> 16) & 1u)) >> 16;   // RNE
    return (unsigned short)r;
}
__device__ __forceinline__ void gload16(const void* g, const void* l) {
    __builtin_amdgcn_global_load_lds((const __attribute__((address_space(1))) unsigned int*)g,
                                     (__attribute__((address_space(3))) unsigned int*)l, 16, 0, 0);
}
// sorted-descending top-N insertion, fully static indexing (no scratch)
template <int N>
__device__ __forceinline__ void insN(float v, int id, float* lv, int* li) {
    if (v > lv[N - 1]) {
#pragma unroll
        for (int i = 0; i < N; ++i) {
            const bool gt = v > lv[i];
            const float tv = gt ? lv[i] : v;
            const int   ti = gt ? li[i] : id;
            if (gt) { lv[i] = v; li[i] = id; }
            v = tv; id = ti;
        }
    }
}
// trunc-hi / RNE-lo split of two fp32 -> packed bf16 pair words
__device__ __forceinline__ void split2(float x0, float x1, unsigned int& hp, unsigned int& lp) {
    union { float f; unsigned int u; } u0, u1;
    u0.f = x0; u1.f = x1;
    hp = (u0.u >> 16) | (u1.u & 0xffff0000u);
    const float r0 = x0 - bf2f((unsigned short)(u0.u >> 16));
    const float r1 = x1 - bf2f((unsigned short)(u1.u >> 16));
    lp = (unsigned int)f2bf(r0) | ((unsigned int)f2bf(r1) << 16);
}

// ---------------- Kernel 0a: fp32 -> bf16 (RNE) ----------------
__global__ __launch_bounds__(256)
void conv_bf16_kernel(const float* __restrict__ x, unsigned short* __restrict__ hi, const int n4)
{
    int i = blockIdx.x * 256 + threadIdx.x;
    const int stride = gridDim.x * 256;
    for (; i < n4; i += stride) {
        const float4 f = ((const float4*)x)[i];
        ushort4 h;
        h.x = f2bf(f.x); h.y = f2bf(f.y); h.z = f2bf(f.z); h.w = f2bf(f.w);
        ((ushort4*)hi)[i] = h;
    }
}

// ---------------- Kernel 0b: fp32 -> (hi, lo) bf16 split (weights) ----------------
__global__ __launch_bounds__(256)
void split_bf16_kernel(const float* __restrict__ x, unsigned short* __restrict__ hi,
                       unsigned short* __restrict__ lo, const int n4)
{
    int i = blockIdx.x * 256 + threadIdx.x;
    const int stride = gridDim.x * 256;
    for (; i < n4; i += stride) {
        const float4 f = ((const float4*)x)[i];
        ushort4 h, l;
        h.x = f2bf(f.x); l.x = f2bf(f.x - bf2f(h.x));
        h.y = f2bf(f.y); l.y = f2bf(f.y - bf2f(h.y));
        h.z = f2bf(f.z); l.z = f2bf(f.z - bf2f(h.z));
        h.w = f2bf(f.w); l.w = f2bf(f.w - bf2f(h.w));
        ((ushort4*)hi)[i] = h;
        ((ushort4*)lo)[i] = l;
    }
}

// ---------------- Kernel A: sims(bf16) = Qhi.Khi^T, 128x128 single-buffer (m97 structure) ----------------
// 4 waves as 2x2 (wave tile 64x64, acc 4x4). LDS 32KB: A[128][64]bf16 @0, B[128][64] @16KB.
// NO launch-bounds occupancy pin (r7 lesson: pinning min-waves clamped VGPRs -> 9GB scratch).
// Epilogue: [128][33] f32 C-tile, scalar stride-33 scans (bank-free, register-lean).
__global__ __launch_bounds__(256)
void sims_mfma_kernel(const unsigned short* __restrict__ Qhi, const unsigned short* __restrict__ Khi,
                      float* __restrict__ cand_val, int* __restrict__ cand_idx)
{
    __shared__ char smem[32768];
    const int tid  = threadIdx.x;
    const int lane = tid & 63;
    const int w    = tid >> 6;
    const int wr   = w >> 1, wc = w & 1;
    const int row0 = blockIdx.x * SBM;
    const int key0 = blockIdx.y * SBN;

    const f32x4 zero = {0.f, 0.f, 0.f, 0.f};
    f32x4 acc[4][4];
#pragma unroll
    for (int mi = 0; mi < 4; ++mi)
#pragma unroll
        for (int ni = 0; ni < 4; ++ni) acc[mi][ni] = zero;

    const int srow = lane >> 3;
    const int scol = (((lane & 7) ^ srow) << 4);      // pre-swizzled source byte col

#pragma unroll 1
    for (int step = 0; step < NSTEPS; ++step) {
        const int kbyte = step << 7;
        __syncthreads();                               // prev compute's LDS reads retired
#pragma unroll
        for (int i = 0; i < 8; ++i) {
            const int chunk = w + (i << 2);            // 0..31, wave-uniform
            const char* src;
            if (chunk < 16) {                          // A: rows 0..127
                const int r = (chunk << 3) + srow;
                src = (const char*)Qhi + (((size_t)(row0 + r)) << 11) + kbyte + scol;
            } else {                                   // B: keys 0..127
                const int r = ((chunk - 16) << 3) + srow;
                src = (const char*)Khi + (((size_t)(key0 + r)) << 11) + kbyte + scol;
            }
            gload16(src, smem + (chunk << 10));
        }
        __syncthreads();                               // staging landed (vmcnt drained)
#pragma unroll
        for (int kk = 0; kk < 2; ++kk) {
            const int cb = (kk << 6) + ((lane >> 4) << 4);
            bf16x8 af[4], bf[4];
#pragma unroll
            for (int mi = 0; mi < 4; ++mi) {
                const int r = wr * 64 + mi * 16 + (lane & 15);
                af[mi] = *(const bf16x8*)(smem + r * 128 + (cb ^ ((r & 7) << 4)));
            }
#pragma unroll
            for (int ni = 0; ni < 4; ++ni) {
                const int r = wc * 64 + ni * 16 + (lane & 15);
                bf[ni] = *(const bf16x8*)(smem + 16384 + r * 128 + (cb ^ ((r & 7) << 4)));
            }
#pragma unroll
            for (int mi = 0; mi < 4; ++mi)
#pragma unroll
                for (int ni = 0; ni < 4; ++ni)
                    acc[mi][ni] = __builtin_amdgcn_mfma_f32_16x16x32_bf16(af[mi], bf[ni], acc[mi][ni], 0, 0, 0);
        }
    }

    // ---- fused top-16 epilogue: 4 passes of 32 cols through LDS C tile [128][33] f32 ----
    float lv[16]; int li[16];
#pragma unroll
    for (int i = 0; i < 16; ++i) { lv[i] = -3.4e38f; li[i] = 0; }
    float* C_lds = (float*)smem;

#pragma unroll
    for (int q = 0; q < 4; ++q) {
        __syncthreads();
        if (wc == (q >> 1)) {                          // 2 waves own these 32 global cols
#pragma unroll
            for (int mi = 0; mi < 4; ++mi)
#pragma unroll
                for (int nn = 0; nn < 2; ++nn) {
                    const int ni = ((q & 1) << 1) + nn;
                    const int r  = wr * 64 + mi * 16 + ((lane >> 4) << 2);
                    const int c  = (nn << 4) + (lane & 15);
                    const f32x4 v = acc[mi][ni];
#pragma unroll
                    for (int j = 0; j < 4; ++j) C_lds[(r + j) * 33 + c] = v[j];
                }
        }
        __syncthreads();
        if (tid < 128) {                               // thread t scans row t; scalar, register-lean
            const int gbase = key0 + (q << 5);
#pragma unroll
            for (int cc = 0; cc < 32; ++cc)
                insN<16>(C_lds[tid * 33 + cc], gbase + cc, lv, li);
        }
    }
    if (tid < 128) {
        const size_t o = (((size_t)(row0 + tid)) * SNKB + blockIdx.y) * KSEL;
#pragma unroll
        for (int i = 0; i < 16; ++i) { cand_val[o + i] = lv[i]; cand_idx[o + i] = li[i]; }
    }
}

// ---------------- Kernel B: merge 256x16 candidates -> top-32 (bf16 scores) per row ----------------
__global__ __launch_bounds__(256)
void topk_merge_kernel(const float* __restrict__ cand_val, const int* __restrict__ cand_idx,
                       int* __restrict__ cand32)
{
    const int row  = blockIdx.x * 4 + (threadIdx.x >> 6);
    const int lane = threadIdx.x & 63;
    const size_t base = (size_t)row * CANDS_PER_ROW;
    float lv[NCAND]; int li[NCAND];
#pragma unroll
    for (int i = 0; i < NCAND; ++i) { lv[i] = -3.4e38f; li[i] = 0x7fffffff; }
#pragma unroll 1
    for (int m = 0; m < CANDS_PER_ROW / 64; ++m) {                // 64 per lane
        const int p = lane + (m << 6);
        insN<NCAND>(cand_val[base + p], cand_idx[base + p], lv, li);
    }
    int out = 0;
#pragma unroll 1
    for (int it = 0; it < NCAND; ++it) {
        float rv = lv[0]; int ridx = li[0];
#pragma unroll
        for (int off = 1; off < 64; off <<= 1) {
            const float ov = __shfl_xor(rv, off);
            const int   oi = __shfl_xor(ridx, off);
            if (ov > rv || (ov == rv && oi < ridx)) { rv = ov; ridx = oi; }
        }
        if (lane == it) out = ridx;
        if (li[0] == ridx) {
#pragma unroll
            for (int i = 0; i < NCAND - 1; ++i) { lv[i] = lv[i + 1]; li[i] = li[i + 1]; }
            lv[NCAND - 1] = -3.4e38f; li[NCAND - 1] = 0x7fffffff;
        }
    }
    if (lane < NCAND) cand32[(size_t)row * NCAND + lane] = out;
}

// ---------------- Kernel B2: exact fp32 rescore of 32 candidates -> final top-16 ----------------
__global__ __launch_bounds__(256)
void rescore_kernel(const float* __restrict__ Q, const float* __restrict__ K,
                    const int* __restrict__ cand32, int* __restrict__ topk)
{
    const int row  = blockIdx.x;
    const int wv   = threadIdx.x >> 6;
    const int lane = threadIdx.x & 63;
    __shared__ float sv[NCAND];
    __shared__ int   si[NCAND];
    if (threadIdx.x < NCAND) si[threadIdx.x] = cand32[(size_t)row * NCAND + threadIdx.x];
    float4 qv[4];
#pragma unroll
    for (int u = 0; u < 4; ++u)
        qv[u] = ((const float4*)(Q + (size_t)row * DDIM))[(u << 6) + lane];
    __syncthreads();
#pragma unroll 1
    for (int c = 0; c < 8; ++c) {
        const int slot = wv * 8 + c;
        const float* kr = K + (size_t)si[slot] * DDIM;
        float s = 0.f;
#pragma unroll
        for (int u = 0; u < 4; ++u) {
            const float4 kv = ((const float4*)kr)[(u << 6) + lane];
            s += kv.x * qv[u].x + kv.y * qv[u].y + kv.z * qv[u].z + kv.w * qv[u].w;
        }
#pragma unroll
        for (int off = 32; off >= 1; off >>= 1) s += __shfl_xor(s, off);
        if (lane == 0) sv[slot] = s;
    }
    __syncthreads();
    if (wv == 0) {
        float v = (lane < NCAND) ? sv[lane] : -3.4e38f;
        int  id = (lane < NCAND) ? si[lane] : 0x7fffffff;
        int out = 0;
#pragma unroll 1
        for (int it = 0; it < KSEL; ++it) {
            float rv = v; int ridx = id;
#pragma unroll
            for (int off = 1; off < 64; off <<= 1) {
                const float ov = __shfl_xor(rv, off);
                const int   oi = __shfl_xor(ridx, off);
                if (ov > rv || (ov == rv && oi < ridx)) { rv = ov; ridx = oi; }
            }
            if (lane == it) out = ridx;
            if (id == ridx) v = -3.4e38f;
        }
        if (lane < KSEL) topk[(size_t)row * KSEL + lane] = out;
    }
}

// ---------------- Kernel C: projections via split-bf16 MFMA; LO=1 3-term, LO=0 1-term (48KB LDS) ----------------
template <int LO>
__global__ __launch_bounds__(256)
void proj_split_kernel(const float* __restrict__ X, const unsigned short* __restrict__ Whi,
                       const unsigned short* __restrict__ Wlo, const float* __restrict__ bias,
                       void* __restrict__ outp, const int store_bf16)
{
    __shared__ char smem[LO ? 65536 : 49152];
    const int tid  = threadIdx.x;
    const int lane = tid & 63;
    const int w    = tid >> 6;
    const int wr   = w >> 1, wc = w & 1;
    const int row0 = blockIdx.x * 128;
    const int col0 = blockIdx.y * 128;

    const f32x4 zero = {0.f, 0.f, 0.f, 0.f};
    f32x4 acc[4][4];
#pragma unroll
    for (int mi = 0; mi < 4; ++mi)
#pragma unroll
        for (int ni = 0; ni < 4; ++ni) acc[mi][ni] = zero;

    const int srow = lane >> 3;
    const int scol = (((lane & 7) ^ srow) << 4);
    const int xr = tid >> 1, xh = tid & 1;

    for (int step = 0; step < 16; ++step) {
        const int kbyte = step << 7;
        const int k0    = step << 6;
        __syncthreads();
#pragma unroll
        for (int i = 0; i < (LO ? 8 : 4); ++i) {
            const int chunk = w + (i << 2);            // 0..31 (LO) or 0..15
            const int plane = chunk >> 4;
            const int r     = ((chunk & 15) << 3) + srow;
            const unsigned short* Wb = plane ? Wlo : Whi;
            const char* src = (const char*)Wb + (((size_t)(col0 + r)) << 11) + kbyte + scol;
            gload16(src, smem + 32768 + (chunk << 10));
        }
        {
            const float* Xp = X + (size_t)(row0 + xr) * DDIM + k0 + xh * 32;
            float4 xa[8];
#pragma unroll
            for (int i = 0; i < 8; ++i) xa[i] = ((const float4*)Xp)[i];
            const int xbase = xr * 128;
#pragma unroll
            for (int s4 = 0; s4 < 4; ++s4) {
                const float4 a = xa[2 * s4], b = xa[2 * s4 + 1];
                uint4 hw, lw;
                if (LO) {
                    split2(a.x, a.y, hw.x, lw.x);
                    split2(a.z, a.w, hw.y, lw.y);
                    split2(b.x, b.y, hw.z, lw.z);
                    split2(b.z, b.w, hw.w, lw.w);
                } else {
                    hw.x = (unsigned int)f2bf(a.x) | ((unsigned int)f2bf(a.y) << 16);
                    hw.y = (unsigned int)f2bf(a.z) | ((unsigned int)f2bf(a.w) << 16);
                    hw.z = (unsigned int)f2bf(b.x) | ((unsigned int)f2bf(b.y) << 16);
                    hw.w = (unsigned int)f2bf(b.z) | ((unsigned int)f2bf(b.w) << 16);
                }
                const int off = xbase + ((((xh << 2) + s4) ^ (xr & 7)) << 4);
                *(uint4*)(smem + off) = hw;
                if (LO) *(uint4*)(smem + 16384 + off) = lw;
            }
        }
        asm volatile("s_waitcnt vmcnt(0)" ::: "memory");
        __syncthreads();
#pragma unroll
        for (int kk = 0; kk < 2; ++kk) {
            const int cb = (kk << 6) + ((lane >> 4) << 4);
            bf16x8 ah[4], bh[4];
#pragma unroll
            for (int mi = 0; mi < 4; ++mi) {
                const int r = wr * 64 + mi * 16 + (lane & 15);
                ah[mi] = *(const bf16x8*)(smem + r * 128 + (cb ^ ((r & 7) << 4)));
            }
#pragma unroll
            for (int ni = 0; ni < 4; ++ni) {
                const int r = wc * 64 + ni * 16 + (lane & 15);
                bh[ni] = *(const bf16x8*)(smem + 32768 + r * 128 + (cb ^ ((r & 7) << 4)));
            }
#pragma unroll
            for (int mi = 0; mi < 4; ++mi)
#pragma unroll
                for (int ni = 0; ni < 4; ++ni)
                    acc[mi][ni] = __builtin_amdgcn_mfma_f32_16x16x32_bf16(ah[mi], bh[ni], acc[mi][ni], 0, 0, 0);
            if (LO) {
                bf16x8 al[4];
#pragma unroll
                for (int mi = 0; mi < 4; ++mi) {
                    const int r = wr * 64 + mi * 16 + (lane & 15);
                    al[mi] = *(const bf16x8*)(smem + 16384 + r * 128 + (cb ^ ((r & 7) << 4)));
                }
#pragma unroll
                for (int mi = 0; mi < 4; ++mi)
#pragma unroll
                    for (int ni = 0; ni < 4; ++ni)
                        acc[mi][ni] = __builtin_amdgcn_mfma_f32_16x16x32_bf16(al[mi], bh[ni], acc[mi][ni], 0, 0, 0);
                bf16x8 bl[4];
#pragma unroll
                for (int ni = 0; ni < 4; ++ni) {
                    const int r = wc * 64 + ni * 16 + (lane & 15);
                    bl[ni] = *(const bf16x8*)(smem + 49152 + r * 128 + (cb ^ ((r & 7) << 4)));
                }
#pragma unroll
                for (int mi = 0; mi < 4; ++mi)
#pragma unroll
                    for (int ni = 0; ni < 4; ++ni)
                        acc[mi][ni] = __builtin_amdgcn_mfma_f32_16x16x32_bf16(ah[mi], bl[ni], acc[mi][ni], 0, 0, 0);
            }
        }
    }

#pragma unroll
    for (int ni = 0; ni < 4; ++ni) {
        const int col = col0 + wc * 64 + ni * 16 + (lane & 15);
        const float bz = bias[col];
#pragma unroll
        for (int mi = 0; mi < 4; ++mi) {
            const int rbase = row0 + wr * 64 + mi * 16 + ((lane >> 4) << 2);
            const f32x4 v = acc[mi][ni];
#pragma unroll
            for (int j = 0; j < 4; ++j) {
                const float val = v[j] + bz;
                if (store_bf16)
                    ((unsigned short*)outp)[(size_t)(rbase + j) * DDIM + col] = f2bf(val);
                else
                    ((float*)outp)[(size_t)(rbase + j) * DDIM + col] = val;
            }
        }
    }
}

// ---------------- Kernel D: per-token 8-head attention over 16 retrieved slots ----------------
__global__ __launch_bounds__(256)
void attn_kernel(const float* __restrict__ Qp, const __hip_bfloat16* __restrict__ Kp,
                 const __hip_bfloat16* __restrict__ Vp, const int* __restrict__ topk,
                 float* __restrict__ attn_out)
{
    const int t = blockIdx.x;
    __shared__ int   idx_s[KSEL];
    __shared__ float sc_s[4][KSEL];
    if (threadIdx.x < KSEL) idx_s[threadIdx.x] = topk[(size_t)t * KSEL + threadIdx.x];
    __syncthreads();
    const int wv   = threadIdx.x >> 6;
    const int lane = threadIdx.x & 63;
    const int jj = lane >> 2, p = lane & 3;
    const float scale = 0.08838834764831845f;  // 1/sqrt(128)
    const unsigned short* Kpu = (const unsigned short*)Kp;
    const unsigned short* Vpu = (const unsigned short*)Vp;

#pragma unroll 1
    for (int hh = 0; hh < 2; ++hh) {
        const int h = wv * 2 + hh;
        const float* qh = Qp + (size_t)t * DDIM + h * HDIM + p * 32;
        const unsigned short* krow = Kpu + (size_t)idx_s[jj] * DDIM + h * HDIM + p * 32;
        float s = 0.f;
#pragma unroll
        for (int u = 0; u < 32; u += 8) {
            uint4  kv = *(const uint4*)(krow + u);
            float4 qa = *(const float4*)(qh + u);
            float4 qb = *(const float4*)(qh + u + 4);
            const unsigned short* kk = (const unsigned short*)&kv;
            s += bf2f(kk[0]) * qa.x + bf2f(kk[1]) * qa.y + bf2f(kk[2]) * qa.z + bf2f(kk[3]) * qa.w
               + bf2f(kk[4]) * qb.x + bf2f(kk[5]) * qb.y + bf2f(kk[6]) * qb.z + bf2f(kk[7]) * qb.w;
        }
        s += __shfl_xor(s, 1);
        s += __shfl_xor(s, 2);
        if (p == 0) sc_s[wv][jj] = s * scale;
        __syncthreads();
        float mx = -__builtin_inff();
#pragma unroll
        for (int n = 0; n < KSEL; ++n) mx = fmaxf(mx, sc_s[wv][n]);
        float wj[KSEL]; float wsum = 0.f;
#pragma unroll
        for (int n = 0; n < KSEL; ++n) { wj[n] = __expf(sc_s[wv][n] - mx); wsum += wj[n]; }
        const float inv = 1.f / wsum;
        const int d = lane * 2;
        float o0 = 0.f, o1 = 0.f;
#pragma unroll
        for (int n = 0; n < KSEL; ++n) {
            const unsigned int vv = *(const unsigned int*)(Vpu + (size_t)idx_s[n] * DDIM + h * HDIM + d);
            const float w = wj[n] * inv;
            o0 += w * bf2f((unsigned short)(vv & 0xffffu));
            o1 += w * bf2f((unsigned short)(vv >> 16));
        }
        *(float2*)(attn_out + (size_t)t * DDIM + h * HDIM + d) = make_float2(o0, o1);
        __syncthreads();
    }
}

extern "C" void kernel_launch(void* const* d_in, const int* in_sizes, int n_in,
                              void* d_out, int out_size, void* d_ws, size_t ws_size,
                              hipStream_t stream)
{
    const float* queries = (const float*)d_in[0];
    const float* mkeys   = (const float*)d_in[1];
    const float* mvals   = (const float*)d_in[2];
    const float* ipw     = (const float*)d_in[3];
    const float* ipb     = (const float*)d_in[4];
    const float* opw     = (const float*)d_in[5];
    const float* opb     = (const float*)d_in[6];

    char* ws = (char*)d_ws;
    size_t off = 0;
    auto alloc = [&](size_t bytes) -> char* {
        char* p = ws + off;
        off += (bytes + 255) & ~(size_t)255;
        return p;
    };
    unsigned short* Khi  = (unsigned short*)alloc((size_t)MKEYS * DDIM * 2);    // 67.1 MB
    unsigned short* Qhi  = (unsigned short*)alloc((size_t)NROWS * DDIM * 2);    // 8.4 MB
    unsigned short* IPhi = (unsigned short*)alloc((size_t)3 * DDIM * DDIM * 2); // 6.3 MB
    unsigned short* IPlo = (unsigned short*)alloc((size_t)3 * DDIM * DDIM * 2); // 6.3 MB
    unsigned short* OPhi = (unsigned short*)alloc((size_t)DDIM * DDIM * 2);     // 2.1 MB
    unsigned short* OPlo = (unsigned short*)alloc((size_t)DDIM * DDIM * 2);     // 2.1 MB
    float* cand_val = (float*)alloc((size_t)NROWS * CANDS_PER_ROW * 4);         // 67.1 MB
    int*   cand_idx = (int*)  alloc((size_t)NROWS * CANDS_PER_ROW * 4);         // 67.1 MB
    int*   cand32   = (int*)  alloc((size_t)NROWS * NCAND * 4);                 // 0.52 MB
    int*   topk     = (int*)  alloc((size_t)NROWS * KSEL * 4);                  // 0.26 MB
    // stream-ordered aliases (total ws ~227 MB):
    float* Qp       = (float*)cand_val;                          // cand_val dead after merge
    float* attn_out = (float*)cand_val + (size_t)NROWS * DDIM;   // second 16.8 MB of cand_val
    __hip_bfloat16* Kp = (__hip_bfloat16*)Khi;                   // Khi dead after sims
    __hip_bfloat16* Vp = (__hip_bfloat16*)cand_idx;              // cand_idx dead after merge

    // 0) converts (sims operands, hi-only) + weight splits
    conv_bf16_kernel<<<2048, 256, 0, stream>>>(queries, Qhi, NROWS * DDIM / 4);
    conv_bf16_kernel<<<2048, 256, 0, stream>>>(mkeys, Khi, MKEYS * DDIM / 4);
    split_bf16_kernel<<<1024, 256, 0, stream>>>(ipw, IPhi, IPlo, 3 * DDIM * DDIM / 4);
    split_bf16_kernel<<<512,  256, 0, stream>>>(opw, OPhi, OPlo, DDIM * DDIM / 4);
    // 1) bf16 similarity GEMM + per-keyblock top-16
    sims_mfma_kernel<<<dim3(NROWS / SBM, MKEYS / SBN), 256, 0, stream>>>(Qhi, Khi, cand_val, cand_idx);
    // 2) merge to top-32 candidates (bf16 scores)
    topk_merge_kernel<<<NROWS / 4, 256, 0, stream>>>(cand_val, cand_idx, cand32);
    // 3) exact fp32 rescore -> final top-16
    rescore_kernel<<<NROWS, 256, 0, stream>>>(queries, mkeys, cand32, topk);
    // 4) projections: q (3-term, f32 out), memory bank K/V (1-term, bf16 out)
    proj_split_kernel<1><<<dim3(NROWS / 128, 8), 256, 0, stream>>>(queries, IPhi, IPlo, ipb, Qp, 0);
    proj_split_kernel<0><<<dim3(MKEYS / 128, 8), 256, 0, stream>>>(mkeys, IPhi + (size_t)DDIM * DDIM,
                                                                   IPlo + (size_t)DDIM * DDIM, ipb + DDIM, Kp, 1);
    proj_split_kernel<0><<<dim3(MKEYS / 128, 8), 256, 0, stream>>>(mvals, IPhi + 2 * (size_t)DDIM * DDIM,
                                                                   IPlo + 2 * (size_t)DDIM * DDIM, ipb + 2 * DDIM, Vp, 1);
    // 5) gather + attention
    attn_kernel<<<NROWS, 256, 0, stream>>>(Qp, Kp, Vp, topk, attn_out);
    // 6) output projection (3-term) -> d_out (f32)
    proj_split_kernel<1><<<dim3(NROWS / 128, 8), 256, 0, stream>>>(attn_out, OPhi, OPlo, opb, d_out, 0);
}

// Round 9
// 1308.343 us; speedup vs baseline: 1.9163x; 1.2118x over previous
//
#include <hip/hip_runtime.h>
#include <hip/hip_bf16.h>

#define NROWS 4096    // B*S
#define DDIM  1024
#define MKEYS 32768
#define HDIM  128
#define KSEL  16
#define NCAND 32      // rescored candidates per row
#define BTOP  8       // per-keyblock kept candidates (top-8; P[miss] ~1e-8)

// ---- sims MFMA GEMM geometry: m97-style 128x128 tile, 4 waves, 32KB LDS ----
#define SBM 128
#define SBN 128
#define SNKB (MKEYS / SBN)            // 256 key blocks
#define CANDS_PER_ROW (SNKB * BTOP)   // 2048
#define NSTEPS 16                     // K = 1024 bf16, BK = 64

typedef short bf16x8 __attribute__((ext_vector_type(8)));
typedef float f32x4  __attribute__((ext_vector_type(4)));

__device__ __forceinline__ float bf2f(unsigned short u) {
    union { unsigned int i; float f; } x; x.i = ((unsigned int)u) << 16; return x.f;
}
__device__ __forceinline__ unsigned short f2bf(float f) {
    union { float f; unsigned int u; } v; v.f = f;
    unsigned int r = (v.u + 0x7fffu + ((v.u >> 16) & 1u)) >> 16;   // RNE
    return (unsigned short)r;
}
__device__ __forceinline__ void gload16(const void* g, const void* l) {
    __builtin_amdgcn_global_load_lds((const __attribute__((address_space(1))) unsigned int*)g,
                                     (__attribute__((address_space(3))) unsigned int*)l, 16, 0, 0);
}
// sorted-descending top-N insertion, fully static indexing (no scratch)
template <int N>
__device__ __forceinline__ void insN(float v, int id, float* lv, int* li) {
    if (v > lv[N - 1]) {
#pragma unroll
        for (int i = 0; i < N; ++i) {
            const bool gt = v > lv[i];
            const float tv = gt ? lv[i] : v;
            const int   ti = gt ? li[i] : id;
            if (gt) { lv[i] = v; li[i] = id; }
            v = tv; id = ti;
        }
    }
}
// trunc-hi / RNE-lo split of two fp32 -> packed bf16 pair words
__device__ __forceinline__ void split2(float x0, float x1, unsigned int& hp, unsigned int& lp) {
    union { float f; unsigned int u; } u0, u1;
    u0.f = x0; u1.f = x1;
    hp = (u0.u >> 16) | (u1.u & 0xffff0000u);
    const float r0 = x0 - bf2f((unsigned short)(u0.u >> 16));
    const float r1 = x1 - bf2f((unsigned short)(u1.u >> 16));
    lp = (unsigned int)f2bf(r0) | ((unsigned int)f2bf(r1) << 16);
}

// ---------------- Kernel 0a: fp32 -> bf16 (RNE) ----------------
__global__ __launch_bounds__(256)
void conv_bf16_kernel(const float* __restrict__ x, unsigned short* __restrict__ hi, const int n4)
{
    int i = blockIdx.x * 256 + threadIdx.x;
    const int stride = gridDim.x * 256;
    for (; i < n4; i += stride) {
        const float4 f = ((const float4*)x)[i];
        ushort4 h;
        h.x = f2bf(f.x); h.y = f2bf(f.y); h.z = f2bf(f.z); h.w = f2bf(f.w);
        ((ushort4*)hi)[i] = h;
    }
}

// ---------------- Kernel 0b: fp32 -> (hi, lo) bf16 split (weights) ----------------
__global__ __launch_bounds__(256)
void split_bf16_kernel(const float* __restrict__ x, unsigned short* __restrict__ hi,
                       unsigned short* __restrict__ lo, const int n4)
{
    int i = blockIdx.x * 256 + threadIdx.x;
    const int stride = gridDim.x * 256;
    for (; i < n4; i += stride) {
        const float4 f = ((const float4*)x)[i];
        ushort4 h, l;
        h.x = f2bf(f.x); l.x = f2bf(f.x - bf2f(h.x));
        h.y = f2bf(f.y); l.y = f2bf(f.y - bf2f(h.y));
        h.z = f2bf(f.z); l.z = f2bf(f.z - bf2f(h.z));
        h.w = f2bf(f.w); l.w = f2bf(f.w - bf2f(h.w));
        ((ushort4*)hi)[i] = h;
        ((ushort4*)lo)[i] = l;
    }
}

// ---------------- Kernel A: sims(bf16) = Qhi.Khi^T, 128x128 single-buffer (m97 structure) ----------------
// 4 waves as 2x2 (wave tile 64x64, acc 4x4). LDS 32KB: A[128][64]bf16 @0, B[128][64] @16KB.
// Epilogue: [128][33] f32 C-tile, scalar stride-33 scans, per-block TOP-8 (r8 lesson: the
// 16-deep sorted-insert cascade was 60% VALUBusy; top-8 cuts insertion work ~3x).
__global__ __launch_bounds__(256)
void sims_mfma_kernel(const unsigned short* __restrict__ Qhi, const unsigned short* __restrict__ Khi,
                      float* __restrict__ cand_val, int* __restrict__ cand_idx)
{
    __shared__ char smem[32768];
    const int tid  = threadIdx.x;
    const int lane = tid & 63;
    const int w    = tid >> 6;
    const int wr   = w >> 1, wc = w & 1;
    const int row0 = blockIdx.x * SBM;
    const int key0 = blockIdx.y * SBN;

    const f32x4 zero = {0.f, 0.f, 0.f, 0.f};
    f32x4 acc[4][4];
#pragma unroll
    for (int mi = 0; mi < 4; ++mi)
#pragma unroll
        for (int ni = 0; ni < 4; ++ni) acc[mi][ni] = zero;

    const int srow = lane >> 3;
    const int scol = (((lane & 7) ^ srow) << 4);      // pre-swizzled source byte col

#pragma unroll 1
    for (int step = 0; step < NSTEPS; ++step) {
        const int kbyte = step << 7;
        __syncthreads();                               // prev compute's LDS reads retired
#pragma unroll
        for (int i = 0; i < 8; ++i) {
            const int chunk = w + (i << 2);            // 0..31, wave-uniform
            const char* src;
            if (chunk < 16) {                          // A: rows 0..127
                const int r = (chunk << 3) + srow;
                src = (const char*)Qhi + (((size_t)(row0 + r)) << 11) + kbyte + scol;
            } else {                                   // B: keys 0..127
                const int r = ((chunk - 16) << 3) + srow;
                src = (const char*)Khi + (((size_t)(key0 + r)) << 11) + kbyte + scol;
            }
            gload16(src, smem + (chunk << 10));
        }
        __syncthreads();                               // staging landed (vmcnt drained)
#pragma unroll
        for (int kk = 0; kk < 2; ++kk) {
            const int cb = (kk << 6) + ((lane >> 4) << 4);
            bf16x8 af[4], bf[4];
#pragma unroll
            for (int mi = 0; mi < 4; ++mi) {
                const int r = wr * 64 + mi * 16 + (lane & 15);
                af[mi] = *(const bf16x8*)(smem + r * 128 + (cb ^ ((r & 7) << 4)));
            }
#pragma unroll
            for (int ni = 0; ni < 4; ++ni) {
                const int r = wc * 64 + ni * 16 + (lane & 15);
                bf[ni] = *(const bf16x8*)(smem + 16384 + r * 128 + (cb ^ ((r & 7) << 4)));
            }
#pragma unroll
            for (int mi = 0; mi < 4; ++mi)
#pragma unroll
                for (int ni = 0; ni < 4; ++ni)
                    acc[mi][ni] = __builtin_amdgcn_mfma_f32_16x16x32_bf16(af[mi], bf[ni], acc[mi][ni], 0, 0, 0);
        }
    }

    // ---- fused top-8 epilogue: 4 passes of 32 cols through LDS C tile [128][33] f32 ----
    float lv[BTOP]; int li[BTOP];
#pragma unroll
    for (int i = 0; i < BTOP; ++i) { lv[i] = -3.4e38f; li[i] = 0; }
    float* C_lds = (float*)smem;

#pragma unroll
    for (int q = 0; q < 4; ++q) {
        __syncthreads();
        if (wc == (q >> 1)) {                          // 2 waves own these 32 global cols
#pragma unroll
            for (int mi = 0; mi < 4; ++mi)
#pragma unroll
                for (int nn = 0; nn < 2; ++nn) {
                    const int ni = ((q & 1) << 1) + nn;
                    const int r  = wr * 64 + mi * 16 + ((lane >> 4) << 2);
                    const int c  = (nn << 4) + (lane & 15);
                    const f32x4 v = acc[mi][ni];
#pragma unroll
                    for (int j = 0; j < 4; ++j) C_lds[(r + j) * 33 + c] = v[j];
                }
        }
        __syncthreads();
        if (tid < 128) {                               // thread t scans row t; scalar, register-lean
            const int gbase = key0 + (q << 5);
#pragma unroll
            for (int cc = 0; cc < 32; ++cc)
                insN<BTOP>(C_lds[tid * 33 + cc], gbase + cc, lv, li);
        }
    }
    if (tid < 128) {
        const size_t o = (((size_t)(row0 + tid)) * SNKB + blockIdx.y) * BTOP;
#pragma unroll
        for (int i = 0; i < BTOP; ++i) { cand_val[o + i] = lv[i]; cand_idx[o + i] = li[i]; }
    }
}

// ---------------- Kernel B: merge 256x8 candidates -> top-32 (bf16 scores) per row ----------------
__global__ __launch_bounds__(256)
void topk_merge_kernel(const float* __restrict__ cand_val, const int* __restrict__ cand_idx,
                       int* __restrict__ cand32)
{
    const int row  = blockIdx.x * 4 + (threadIdx.x >> 6);
    const int lane = threadIdx.x & 63;
    const size_t base = (size_t)row * CANDS_PER_ROW;
    float lv[NCAND]; int li[NCAND];
#pragma unroll
    for (int i = 0; i < NCAND; ++i) { lv[i] = -3.4e38f; li[i] = 0x7fffffff; }
#pragma unroll 1
    for (int m = 0; m < CANDS_PER_ROW / 64; ++m) {                // 32 per lane
        const int p = lane + (m << 6);
        insN<NCAND>(cand_val[base + p], cand_idx[base + p], lv, li);
    }
    int out = 0;
#pragma unroll 1
    for (int it = 0; it < NCAND; ++it) {
        float rv = lv[0]; int ridx = li[0];
#pragma unroll
        for (int off = 1; off < 64; off <<= 1) {
            const float ov = __shfl_xor(rv, off);
            const int   oi = __shfl_xor(ridx, off);
            if (ov > rv || (ov == rv && oi < ridx)) { rv = ov; ridx = oi; }
        }
        if (lane == it) out = ridx;
        if (li[0] == ridx) {
#pragma unroll
            for (int i = 0; i < NCAND - 1; ++i) { lv[i] = lv[i + 1]; li[i] = li[i + 1]; }
            lv[NCAND - 1] = -3.4e38f; li[NCAND - 1] = 0x7fffffff;
        }
    }
    if (lane < NCAND) cand32[(size_t)row * NCAND + lane] = out;
}

// ---------------- Kernel B2: exact fp32 rescore of 32 candidates -> final top-16 ----------------
__global__ __launch_bounds__(256)
void rescore_kernel(const float* __restrict__ Q, const float* __restrict__ K,
                    const int* __restrict__ cand32, int* __restrict__ topk)
{
    const int row  = blockIdx.x;
    const int wv   = threadIdx.x >> 6;
    const int lane = threadIdx.x & 63;
    __shared__ float sv[NCAND];
    __shared__ int   si[NCAND];
    if (threadIdx.x < NCAND) si[threadIdx.x] = cand32[(size_t)row * NCAND + threadIdx.x];
    float4 qv[4];
#pragma unroll
    for (int u = 0; u < 4; ++u)
        qv[u] = ((const float4*)(Q + (size_t)row * DDIM))[(u << 6) + lane];
    __syncthreads();
#pragma unroll 1
    for (int c = 0; c < 8; ++c) {
        const int slot = wv * 8 + c;
        const float* kr = K + (size_t)si[slot] * DDIM;
        float s = 0.f;
#pragma unroll
        for (int u = 0; u < 4; ++u) {
            const float4 kv = ((const float4*)kr)[(u << 6) + lane];
            s += kv.x * qv[u].x + kv.y * qv[u].y + kv.z * qv[u].z + kv.w * qv[u].w;
        }
#pragma unroll
        for (int off = 32; off >= 1; off >>= 1) s += __shfl_xor(s, off);
        if (lane == 0) sv[slot] = s;
    }
    __syncthreads();
    if (wv == 0) {
        float v = (lane < NCAND) ? sv[lane] : -3.4e38f;
        int  id = (lane < NCAND) ? si[lane] : 0x7fffffff;
        int out = 0;
#pragma unroll 1
        for (int it = 0; it < KSEL; ++it) {
            float rv = v; int ridx = id;
#pragma unroll
            for (int off = 1; off < 64; off <<= 1) {
                const float ov = __shfl_xor(rv, off);
                const int   oi = __shfl_xor(ridx, off);
                if (ov > rv || (ov == rv && oi < ridx)) { rv = ov; ridx = oi; }
            }
            if (lane == it) out = ridx;
            if (id == ridx) v = -3.4e38f;
        }
        if (lane < KSEL) topk[(size_t)row * KSEL + lane] = out;
    }
}

// ---------------- Kernel C: projections via split-bf16 MFMA; LO=1 3-term (64KB), LO=0 1-term (32KB) ----------------
template <int LO>
__global__ __launch_bounds__(256)
void proj_split_kernel(const float* __restrict__ X, const unsigned short* __restrict__ Whi,
                       const unsigned short* __restrict__ Wlo, const float* __restrict__ bias,
                       void* __restrict__ outp, const int store_bf16)
{
    constexpr int WOFF = LO ? 32768 : 16384;           // W-plane base (no dead hole at LO=0)
    __shared__ char smem[LO ? 65536 : 32768];
    const int tid  = threadIdx.x;
    const int lane = tid & 63;
    const int w    = tid >> 6;
    const int wr   = w >> 1, wc = w & 1;
    const int row0 = blockIdx.x * 128;
    const int col0 = blockIdx.y * 128;

    const f32x4 zero = {0.f, 0.f, 0.f, 0.f};
    f32x4 acc[4][4];
#pragma unroll
    for (int mi = 0; mi < 4; ++mi)
#pragma unroll
        for (int ni = 0; ni < 4; ++ni) acc[mi][ni] = zero;

    const int srow = lane >> 3;
    const int scol = (((lane & 7) ^ srow) << 4);
    const int xr = tid >> 1, xh = tid & 1;

    for (int step = 0; step < 16; ++step) {
        const int kbyte = step << 7;
        const int k0    = step << 6;
        __syncthreads();
#pragma unroll
        for (int i = 0; i < (LO ? 8 : 4); ++i) {
            const int chunk = w + (i << 2);            // 0..31 (LO) or 0..15
            const int plane = chunk >> 4;
            const int r     = ((chunk & 15) << 3) + srow;
            const unsigned short* Wb = plane ? Wlo : Whi;
            const char* src = (const char*)Wb + (((size_t)(col0 + r)) << 11) + kbyte + scol;
            gload16(src, smem + WOFF + (chunk << 10));
        }
        {
            const float* Xp = X + (size_t)(row0 + xr) * DDIM + k0 + xh * 32;
            float4 xa[8];
#pragma unroll
            for (int i = 0; i < 8; ++i) xa[i] = ((const float4*)Xp)[i];
            const int xbase = xr * 128;
#pragma unroll
            for (int s4 = 0; s4 < 4; ++s4) {
                const float4 a = xa[2 * s4], b = xa[2 * s4 + 1];
                uint4 hw, lw;
                if (LO) {
                    split2(a.x, a.y, hw.x, lw.x);
                    split2(a.z, a.w, hw.y, lw.y);
                    split2(b.x, b.y, hw.z, lw.z);
                    split2(b.z, b.w, hw.w, lw.w);
                } else {
                    hw.x = (unsigned int)f2bf(a.x) | ((unsigned int)f2bf(a.y) << 16);
                    hw.y = (unsigned int)f2bf(a.z) | ((unsigned int)f2bf(a.w) << 16);
                    hw.z = (unsigned int)f2bf(b.x) | ((unsigned int)f2bf(b.y) << 16);
                    hw.w = (unsigned int)f2bf(b.z) | ((unsigned int)f2bf(b.w) << 16);
                }
                const int off = xbase + ((((xh << 2) + s4) ^ (xr & 7)) << 4);
                *(uint4*)(smem + off) = hw;
                if (LO) *(uint4*)(smem + 16384 + off) = lw;
            }
        }
        asm volatile("s_waitcnt vmcnt(0)" ::: "memory");
        __syncthreads();
#pragma unroll
        for (int kk = 0; kk < 2; ++kk) {
            const int cb = (kk << 6) + ((lane >> 4) << 4);
            bf16x8 ah[4], bh[4];
#pragma unroll
            for (int mi = 0; mi < 4; ++mi) {
                const int r = wr * 64 + mi * 16 + (lane & 15);
                ah[mi] = *(const bf16x8*)(smem + r * 128 + (cb ^ ((r & 7) << 4)));
            }
#pragma unroll
            for (int ni = 0; ni < 4; ++ni) {
                const int r = wc * 64 + ni * 16 + (lane & 15);
                bh[ni] = *(const bf16x8*)(smem + WOFF + r * 128 + (cb ^ ((r & 7) << 4)));
            }
#pragma unroll
            for (int mi = 0; mi < 4; ++mi)
#pragma unroll
                for (int ni = 0; ni < 4; ++ni)
                    acc[mi][ni] = __builtin_amdgcn_mfma_f32_16x16x32_bf16(ah[mi], bh[ni], acc[mi][ni], 0, 0, 0);
            if (LO) {
                bf16x8 al[4];
#pragma unroll
                for (int mi = 0; mi < 4; ++mi) {
                    const int r = wr * 64 + mi * 16 + (lane & 15);
                    al[mi] = *(const bf16x8*)(smem + 16384 + r * 128 + (cb ^ ((r & 7) << 4)));
                }
#pragma unroll
                for (int mi = 0; mi < 4; ++mi)
#pragma unroll
                    for (int ni = 0; ni < 4; ++ni)
                        acc[mi][ni] = __builtin_amdgcn_mfma_f32_16x16x32_bf16(al[mi], bh[ni], acc[mi][ni], 0, 0, 0);
                bf16x8 bl[4];
#pragma unroll
                for (int ni = 0; ni < 4; ++ni) {
                    const int r = wc * 64 + ni * 16 + (lane & 15);
                    bl[ni] = *(const bf16x8*)(smem + WOFF + 16384 + r * 128 + (cb ^ ((r & 7) << 4)));
                }
#pragma unroll
                for (int mi = 0; mi < 4; ++mi)
#pragma unroll
                    for (int ni = 0; ni < 4; ++ni)
                        acc[mi][ni] = __builtin_amdgcn_mfma_f32_16x16x32_bf16(ah[mi], bl[ni], acc[mi][ni], 0, 0, 0);
            }
        }
    }

#pragma unroll
    for (int ni = 0; ni < 4; ++ni) {
        const int col = col0 + wc * 64 + ni * 16 + (lane & 15);
        const float bz = bias[col];
#pragma unroll
        for (int mi = 0; mi < 4; ++mi) {
            const int rbase = row0 + wr * 64 + mi * 16 + ((lane >> 4) << 2);
            const f32x4 v = acc[mi][ni];
#pragma unroll
            for (int j = 0; j < 4; ++j) {
                const float val = v[j] + bz;
                if (store_bf16)
                    ((unsigned short*)outp)[(size_t)(rbase + j) * DDIM + col] = f2bf(val);
                else
                    ((float*)outp)[(size_t)(rbase + j) * DDIM + col] = val;
            }
        }
    }
}

// ---------------- Kernel D: per-token 8-head attention over 16 retrieved slots ----------------
__global__ __launch_bounds__(256)
void attn_kernel(const float* __restrict__ Qp, const __hip_bfloat16* __restrict__ Kp,
                 const __hip_bfloat16* __restrict__ Vp, const int* __restrict__ topk,
                 float* __restrict__ attn_out)
{
    const int t = blockIdx.x;
    __shared__ int   idx_s[KSEL];
    __shared__ float sc_s[4][KSEL];
    if (threadIdx.x < KSEL) idx_s[threadIdx.x] = topk[(size_t)t * KSEL + threadIdx.x];
    __syncthreads();
    const int wv   = threadIdx.x >> 6;
    const int lane = threadIdx.x & 63;
    const int jj = lane >> 2, p = lane & 3;
    const float scale = 0.08838834764831845f;  // 1/sqrt(128)
    const unsigned short* Kpu = (const unsigned short*)Kp;
    const unsigned short* Vpu = (const unsigned short*)Vp;

#pragma unroll 1
    for (int hh = 0; hh < 2; ++hh) {
        const int h = wv * 2 + hh;
        const float* qh = Qp + (size_t)t * DDIM + h * HDIM + p * 32;
        const unsigned short* krow = Kpu + (size_t)idx_s[jj] * DDIM + h * HDIM + p * 32;
        float s = 0.f;
#pragma unroll
        for (int u = 0; u < 32; u += 8) {
            uint4  kv = *(const uint4*)(krow + u);
            float4 qa = *(const float4*)(qh + u);
            float4 qb = *(const float4*)(qh + u + 4);
            const unsigned short* kk = (const unsigned short*)&kv;
            s += bf2f(kk[0]) * qa.x + bf2f(kk[1]) * qa.y + bf2f(kk[2]) * qa.z + bf2f(kk[3]) * qa.w
               + bf2f(kk[4]) * qb.x + bf2f(kk[5]) * qb.y + bf2f(kk[6]) * qb.z + bf2f(kk[7]) * qb.w;
        }
        s += __shfl_xor(s, 1);
        s += __shfl_xor(s, 2);
        if (p == 0) sc_s[wv][jj] = s * scale;
        __syncthreads();
        float mx = -__builtin_inff();
#pragma unroll
        for (int n = 0; n < KSEL; ++n) mx = fmaxf(mx, sc_s[wv][n]);
        float wj[KSEL]; float wsum = 0.f;
#pragma unroll
        for (int n = 0; n < KSEL; ++n) { wj[n] = __expf(sc_s[wv][n] - mx); wsum += wj[n]; }
        const float inv = 1.f / wsum;
        const int d = lane * 2;
        float o0 = 0.f, o1 = 0.f;
#pragma unroll
        for (int n = 0; n < KSEL; ++n) {
            const unsigned int vv = *(const unsigned int*)(Vpu + (size_t)idx_s[n] * DDIM + h * HDIM + d);
            const float w = wj[n] * inv;
            o0 += w * bf2f((unsigned short)(vv & 0xffffu));
            o1 += w * bf2f((unsigned short)(vv >> 16));
        }
        *(float2*)(attn_out + (size_t)t * DDIM + h * HDIM + d) = make_float2(o0, o1);
        __syncthreads();
    }
}

extern "C" void kernel_launch(void* const* d_in, const int* in_sizes, int n_in,
                              void* d_out, int out_size, void* d_ws, size_t ws_size,
                              hipStream_t stream)
{
    const float* queries = (const float*)d_in[0];
    const float* mkeys   = (const float*)d_in[1];
    const float* mvals   = (const float*)d_in[2];
    const float* ipw     = (const float*)d_in[3];
    const float* ipb     = (const float*)d_in[4];
    const float* opw     = (const float*)d_in[5];
    const float* opb     = (const float*)d_in[6];

    char* ws = (char*)d_ws;
    size_t off = 0;
    auto alloc = [&](size_t bytes) -> char* {
        char* p = ws + off;
        off += (bytes + 255) & ~(size_t)255;
        return p;
    };
    unsigned short* Khi  = (unsigned short*)alloc((size_t)MKEYS * DDIM * 2);    // 67.1 MB
    unsigned short* Qhi  = (unsigned short*)alloc((size_t)NROWS * DDIM * 2);    // 8.4 MB
    unsigned short* IPhi = (unsigned short*)alloc((size_t)3 * DDIM * DDIM * 2); // 6.3 MB
    unsigned short* IPlo = (unsigned short*)alloc((size_t)3 * DDIM * DDIM * 2); // 6.3 MB
    unsigned short* OPhi = (unsigned short*)alloc((size_t)DDIM * DDIM * 2);     // 2.1 MB
    unsigned short* OPlo = (unsigned short*)alloc((size_t)DDIM * DDIM * 2);     // 2.1 MB
    float* cand_val = (float*)alloc((size_t)NROWS * CANDS_PER_ROW * 4);         // 33.5 MB
    int*   cand_idx = (int*)  alloc((size_t)NROWS * CANDS_PER_ROW * 4);         // 33.5 MB
    int*   cand32   = (int*)  alloc((size_t)NROWS * NCAND * 4);                 // 0.52 MB
    int*   topk     = (int*)  alloc((size_t)NROWS * KSEL * 4);                  // 0.26 MB
    float* Qp       = (float*)alloc((size_t)NROWS * DDIM * 4);                  // 16.8 MB
    float* attn_out = (float*)alloc((size_t)NROWS * DDIM * 4);                  // 16.8 MB
    // stream-ordered aliases (total ws ~194 MB):
    __hip_bfloat16* Kp = (__hip_bfloat16*)Khi;                   // Khi dead after sims+rescore
    __hip_bfloat16* Vp = (__hip_bfloat16*)cand_val;              // cand arrays dead after merge

    // 0) converts (sims operands, hi-only) + weight splits
    conv_bf16_kernel<<<2048, 256, 0, stream>>>(queries, Qhi, NROWS * DDIM / 4);
    conv_bf16_kernel<<<2048, 256, 0, stream>>>(mkeys, Khi, MKEYS * DDIM / 4);
    split_bf16_kernel<<<1024, 256, 0, stream>>>(ipw, IPhi, IPlo, 3 * DDIM * DDIM / 4);
    split_bf16_kernel<<<512,  256, 0, stream>>>(opw, OPhi, OPlo, DDIM * DDIM / 4);
    // 1) bf16 similarity GEMM + per-keyblock top-8
    sims_mfma_kernel<<<dim3(NROWS / SBM, MKEYS / SBN), 256, 0, stream>>>(Qhi, Khi, cand_val, cand_idx);
    // 2) merge to top-32 candidates (bf16 scores)
    topk_merge_kernel<<<NROWS / 4, 256, 0, stream>>>(cand_val, cand_idx, cand32);
    // 3) exact fp32 rescore -> final top-16
    rescore_kernel<<<NROWS, 256, 0, stream>>>(queries, mkeys, cand32, topk);
    // 4) projections: q (3-term, f32 out), memory bank K/V (1-term, bf16 out)
    proj_split_kernel<1><<<dim3(NROWS / 128, 8), 256, 0, stream>>>(queries, IPhi, IPlo, ipb, Qp, 0);
    proj_split_kernel<0><<<dim3(MKEYS / 128, 8), 256, 0, stream>>>(mkeys, IPhi + (size_t)DDIM * DDIM,
                                                                   IPlo + (size_t)DDIM * DDIM, ipb + DDIM, Kp, 1);
    proj_split_kernel<0><<<dim3(MKEYS / 128, 8), 256, 0, stream>>>(mvals, IPhi + 2 * (size_t)DDIM * DDIM,
                                                                   IPlo + 2 * (size_t)DDIM * DDIM, ipb + 2 * DDIM, Vp, 1);
    // 5) gather + attention
    attn_kernel<<<NROWS, 256, 0, stream>>>(Qp, Kp, Vp, topk, attn_out);
    // 6) output projection (3-term) -> d_out (f32)
    proj_split_kernel<1><<<dim3(NROWS / 128, 8), 256, 0, stream>>>(attn_out, OPhi, OPlo, opb, d_out, 0);
}

// Round 10
// 1136.968 us; speedup vs baseline: 2.2051x; 1.1507x over previous
//
#include <hip/hip_runtime.h>
#include <hip/hip_bf16.h>

#define NROWS 4096    // B*S
#define DDIM  1024
#define MKEYS 32768
#define HDIM  128
#define KSEL  16
#define NCAND 32      // rescored candidates per row
#define BTOP  8       // per-keyblock kept candidates (top-8; P[miss] ~1e-8)

// ---- sims MFMA GEMM geometry: m97-style 128x128 tile, 4 waves, 32KB LDS ----
#define SBM 128
#define SBN 128
#define SNKB (MKEYS / SBN)            // 256 key blocks
#define CANDS_PER_ROW (SNKB * BTOP)   // 2048
#define NSTEPS 16                     // K = 1024 bf16, BK = 64

typedef short bf16x8 __attribute__((ext_vector_type(8)));
typedef float f32x4  __attribute__((ext_vector_type(4)));

__device__ __forceinline__ float bf2f(unsigned short u) {
    union { unsigned int i; float f; } x; x.i = ((unsigned int)u) << 16; return x.f;
}
__device__ __forceinline__ unsigned short f2bf(float f) {
    union { float f; unsigned int u; } v; v.f = f;
    unsigned int r = (v.u + 0x7fffu + ((v.u >> 16) & 1u)) >> 16;   // RNE
    return (unsigned short)r;
}
__device__ __forceinline__ void gload16(const void* g, const void* l) {
    __builtin_amdgcn_global_load_lds((const __attribute__((address_space(1))) unsigned int*)g,
                                     (__attribute__((address_space(3))) unsigned int*)l, 16, 0, 0);
}
// sorted-descending top-N insertion, fully static indexing (no scratch)
template <int N>
__device__ __forceinline__ void insN(float v, int id, float* lv, int* li) {
    if (v > lv[N - 1]) {
#pragma unroll
        for (int i = 0; i < N; ++i) {
            const bool gt = v > lv[i];
            const float tv = gt ? lv[i] : v;
            const int   ti = gt ? li[i] : id;
            if (gt) { lv[i] = v; li[i] = id; }
            v = tv; id = ti;
        }
    }
}
// trunc-hi / RNE-lo split of two fp32 -> packed bf16 pair words
__device__ __forceinline__ void split2(float x0, float x1, unsigned int& hp, unsigned int& lp) {
    union { float f; unsigned int u; } u0, u1;
    u0.f = x0; u1.f = x1;
    hp = (u0.u >> 16) | (u1.u & 0xffff0000u);
    const float r0 = x0 - bf2f((unsigned short)(u0.u >> 16));
    const float r1 = x1 - bf2f((unsigned short)(u1.u >> 16));
    lp = (unsigned int)f2bf(r0) | ((unsigned int)f2bf(r1) << 16);
}

// ---------------- Kernel 0a: fp32 -> bf16 (RNE) ----------------
__global__ __launch_bounds__(256)
void conv_bf16_kernel(const float* __restrict__ x, unsigned short* __restrict__ hi, const int n4)
{
    int i = blockIdx.x * 256 + threadIdx.x;
    const int stride = gridDim.x * 256;
    for (; i < n4; i += stride) {
        const float4 f = ((const float4*)x)[i];
        ushort4 h;
        h.x = f2bf(f.x); h.y = f2bf(f.y); h.z = f2bf(f.z); h.w = f2bf(f.w);
        ((ushort4*)hi)[i] = h;
    }
}

// ---------------- Kernel 0b: fp32 -> (hi, lo) bf16 split (weights) ----------------
__global__ __launch_bounds__(256)
void split_bf16_kernel(const float* __restrict__ x, unsigned short* __restrict__ hi,
                       unsigned short* __restrict__ lo, const int n4)
{
    int i = blockIdx.x * 256 + threadIdx.x;
    const int stride = gridDim.x * 256;
    for (; i < n4; i += stride) {
        const float4 f = ((const float4*)x)[i];
        ushort4 h, l;
        h.x = f2bf(f.x); l.x = f2bf(f.x - bf2f(h.x));
        h.y = f2bf(f.y); l.y = f2bf(f.y - bf2f(h.y));
        h.z = f2bf(f.z); l.z = f2bf(f.z - bf2f(h.z));
        h.w = f2bf(f.w); l.w = f2bf(f.w - bf2f(h.w));
        ((ushort4*)hi)[i] = h;
        ((ushort4*)lo)[i] = l;
    }
}

// ---------------- Kernel A: sims(bf16) = Qhi.Khi^T, 128x128 single-buffer (m97 structure) ----------------
// 4 waves as 2x2 (wave tile 64x64, acc 4x4). LDS 32KB: A[128][64]bf16 @0, B[128][64] @16KB.
// Epilogue (r10): ALL 256 threads scan — thread t and t+128 split each row's 32 cols/pass
// (16 each, 64 total per thread), then merge the two top-8 lists via LDS (exact).
__global__ __launch_bounds__(256)
void sims_mfma_kernel(const unsigned short* __restrict__ Qhi, const unsigned short* __restrict__ Khi,
                      float* __restrict__ cand_val, int* __restrict__ cand_idx)
{
    __shared__ char smem[32768];
    const int tid  = threadIdx.x;
    const int lane = tid & 63;
    const int w    = tid >> 6;
    const int wr   = w >> 1, wc = w & 1;
    const int row0 = blockIdx.x * SBM;
    const int key0 = blockIdx.y * SBN;

    const f32x4 zero = {0.f, 0.f, 0.f, 0.f};
    f32x4 acc[4][4];
#pragma unroll
    for (int mi = 0; mi < 4; ++mi)
#pragma unroll
        for (int ni = 0; ni < 4; ++ni) acc[mi][ni] = zero;

    const int srow = lane >> 3;
    const int scol = (((lane & 7) ^ srow) << 4);      // pre-swizzled source byte col

#pragma unroll 1
    for (int step = 0; step < NSTEPS; ++step) {
        const int kbyte = step << 7;
        __syncthreads();                               // prev compute's LDS reads retired
#pragma unroll
        for (int i = 0; i < 8; ++i) {
            const int chunk = w + (i << 2);            // 0..31, wave-uniform
            const char* src;
            if (chunk < 16) {                          // A: rows 0..127
                const int r = (chunk << 3) + srow;
                src = (const char*)Qhi + (((size_t)(row0 + r)) << 11) + kbyte + scol;
            } else {                                   // B: keys 0..127
                const int r = ((chunk - 16) << 3) + srow;
                src = (const char*)Khi + (((size_t)(key0 + r)) << 11) + kbyte + scol;
            }
            gload16(src, smem + (chunk << 10));
        }
        __syncthreads();                               // staging landed (vmcnt drained)
#pragma unroll
        for (int kk = 0; kk < 2; ++kk) {
            const int cb = (kk << 6) + ((lane >> 4) << 4);
            bf16x8 af[4], bf[4];
#pragma unroll
            for (int mi = 0; mi < 4; ++mi) {
                const int r = wr * 64 + mi * 16 + (lane & 15);
                af[mi] = *(const bf16x8*)(smem + r * 128 + (cb ^ ((r & 7) << 4)));
            }
#pragma unroll
            for (int ni = 0; ni < 4; ++ni) {
                const int r = wc * 64 + ni * 16 + (lane & 15);
                bf[ni] = *(const bf16x8*)(smem + 16384 + r * 128 + (cb ^ ((r & 7) << 4)));
            }
#pragma unroll
            for (int mi = 0; mi < 4; ++mi)
#pragma unroll
                for (int ni = 0; ni < 4; ++ni)
                    acc[mi][ni] = __builtin_amdgcn_mfma_f32_16x16x32_bf16(af[mi], bf[ni], acc[mi][ni], 0, 0, 0);
        }
    }

    // ---- fused top-8 epilogue: 4 passes of 32 cols through LDS C tile [128][33] f32 ----
    float lv[BTOP]; int li[BTOP];
#pragma unroll
    for (int i = 0; i < BTOP; ++i) { lv[i] = -3.4e38f; li[i] = 0; }
    float* C_lds = (float*)smem;
    const int rowt = tid & 127;
    const int half = tid >> 7;

#pragma unroll
    for (int q = 0; q < 4; ++q) {
        __syncthreads();
        if (wc == (q >> 1)) {                          // 2 waves own these 32 global cols
#pragma unroll
            for (int mi = 0; mi < 4; ++mi)
#pragma unroll
                for (int nn = 0; nn < 2; ++nn) {
                    const int ni = ((q & 1) << 1) + nn;
                    const int r  = wr * 64 + mi * 16 + ((lane >> 4) << 2);
                    const int c  = (nn << 4) + (lane & 15);
                    const f32x4 v = acc[mi][ni];
#pragma unroll
                    for (int j = 0; j < 4; ++j) C_lds[(r + j) * 33 + c] = v[j];
                }
        }
        __syncthreads();
        // all 256 threads: thread scans 16 cols of its row-half
        const int gbase = key0 + (q << 5) + (half << 4);
#pragma unroll
        for (int cc = 0; cc < 16; ++cc)
            insN<BTOP>(C_lds[rowt * 33 + (half << 4) + cc], gbase + cc, lv, li);
    }
    // merge the two half-lists per row (exact: top8(A∪B) = top8(top8 A ∪ top8 B))
    __syncthreads();
    float* mv = (float*)smem;                          // [128][8] vals
    int*   mx = (int*)(smem + 4096);                   // [128][8] idxs
    if (half == 1) {
#pragma unroll
        for (int i = 0; i < BTOP; ++i) { mv[rowt * 8 + i] = lv[i]; mx[rowt * 8 + i] = li[i]; }
    }
    __syncthreads();
    if (half == 0) {
#pragma unroll
        for (int i = 0; i < BTOP; ++i)
            insN<BTOP>(mv[rowt * 8 + i], mx[rowt * 8 + i], lv, li);
        const size_t o = (((size_t)(row0 + rowt)) * SNKB + blockIdx.y) * BTOP;
#pragma unroll
        for (int i = 0; i < BTOP; ++i) { cand_val[o + i] = lv[i]; cand_idx[o + i] = li[i]; }
    }
}

// ---------------- Kernel B: merge 256x8 candidates -> top-32 (bf16 scores) per row ----------------
__global__ __launch_bounds__(256)
void topk_merge_kernel(const float* __restrict__ cand_val, const int* __restrict__ cand_idx,
                       int* __restrict__ cand32)
{
    const int row  = blockIdx.x * 4 + (threadIdx.x >> 6);
    const int lane = threadIdx.x & 63;
    const size_t base = (size_t)row * CANDS_PER_ROW;
    float lv[NCAND]; int li[NCAND];
#pragma unroll
    for (int i = 0; i < NCAND; ++i) { lv[i] = -3.4e38f; li[i] = 0x7fffffff; }
#pragma unroll 1
    for (int m = 0; m < CANDS_PER_ROW / 64; ++m) {                // 32 per lane
        const int p = lane + (m << 6);
        insN<NCAND>(cand_val[base + p], cand_idx[base + p], lv, li);
    }
    int out = 0;
#pragma unroll 1
    for (int it = 0; it < NCAND; ++it) {
        float rv = lv[0]; int ridx = li[0];
#pragma unroll
        for (int off = 1; off < 64; off <<= 1) {
            const float ov = __shfl_xor(rv, off);
            const int   oi = __shfl_xor(ridx, off);
            if (ov > rv || (ov == rv && oi < ridx)) { rv = ov; ridx = oi; }
        }
        if (lane == it) out = ridx;
        if (li[0] == ridx) {
#pragma unroll
            for (int i = 0; i < NCAND - 1; ++i) { lv[i] = lv[i + 1]; li[i] = li[i + 1]; }
            lv[NCAND - 1] = -3.4e38f; li[NCAND - 1] = 0x7fffffff;
        }
    }
    if (lane < NCAND) cand32[(size_t)row * NCAND + lane] = out;
}

// ---------------- Kernel B2: exact fp32 rescore of 32 candidates -> final top-16 ----------------
__global__ __launch_bounds__(256)
void rescore_kernel(const float* __restrict__ Q, const float* __restrict__ K,
                    const int* __restrict__ cand32, int* __restrict__ topk)
{
    const int row  = blockIdx.x;
    const int wv   = threadIdx.x >> 6;
    const int lane = threadIdx.x & 63;
    __shared__ float sv[NCAND];
    __shared__ int   si[NCAND];
    if (threadIdx.x < NCAND) si[threadIdx.x] = cand32[(size_t)row * NCAND + threadIdx.x];
    float4 qv[4];
#pragma unroll
    for (int u = 0; u < 4; ++u)
        qv[u] = ((const float4*)(Q + (size_t)row * DDIM))[(u << 6) + lane];
    __syncthreads();
#pragma unroll 1
    for (int c = 0; c < 8; ++c) {
        const int slot = wv * 8 + c;
        const float* kr = K + (size_t)si[slot] * DDIM;
        float s = 0.f;
#pragma unroll
        for (int u = 0; u < 4; ++u) {
            const float4 kv = ((const float4*)kr)[(u << 6) + lane];
            s += kv.x * qv[u].x + kv.y * qv[u].y + kv.z * qv[u].z + kv.w * qv[u].w;
        }
#pragma unroll
        for (int off = 32; off >= 1; off >>= 1) s += __shfl_xor(s, off);
        if (lane == 0) sv[slot] = s;
    }
    __syncthreads();
    if (wv == 0) {
        float v = (lane < NCAND) ? sv[lane] : -3.4e38f;
        int  id = (lane < NCAND) ? si[lane] : 0x7fffffff;
        int out = 0;
#pragma unroll 1
        for (int it = 0; it < KSEL; ++it) {
            float rv = v; int ridx = id;
#pragma unroll
            for (int off = 1; off < 64; off <<= 1) {
                const float ov = __shfl_xor(rv, off);
                const int   oi = __shfl_xor(ridx, off);
                if (ov > rv || (ov == rv && oi < ridx)) { rv = ov; ridx = oi; }
            }
            if (lane == it) out = ridx;
            if (id == ridx) v = -3.4e38f;
        }
        if (lane < KSEL) topk[(size_t)row * KSEL + lane] = out;
    }
}

// ---------------- Kernel C1: bf16 x bf16 GEMM + bias -> bf16 (K projection; pure gload_lds) ----------------
__global__ __launch_bounds__(256)
void gemm_bb_kernel(const unsigned short* __restrict__ Xb, const unsigned short* __restrict__ Whi,
                    const float* __restrict__ bias, unsigned short* __restrict__ outp)
{
    __shared__ char smem[32768];
    const int tid  = threadIdx.x;
    const int lane = tid & 63;
    const int w    = tid >> 6;
    const int wr   = w >> 1, wc = w & 1;
    const int row0 = blockIdx.x * 128;
    const int col0 = blockIdx.y * 128;

    const f32x4 zero = {0.f, 0.f, 0.f, 0.f};
    f32x4 acc[4][4];
#pragma unroll
    for (int mi = 0; mi < 4; ++mi)
#pragma unroll
        for (int ni = 0; ni < 4; ++ni) acc[mi][ni] = zero;

    const int srow = lane >> 3;
    const int scol = (((lane & 7) ^ srow) << 4);

#pragma unroll 1
    for (int step = 0; step < 16; ++step) {
        const int kbyte = step << 7;
        __syncthreads();
#pragma unroll
        for (int i = 0; i < 8; ++i) {
            const int chunk = w + (i << 2);            // 0..31
            const char* src;
            if (chunk < 16) {                          // X rows
                const int r = (chunk << 3) + srow;
                src = (const char*)Xb + (((size_t)(row0 + r)) << 11) + kbyte + scol;
            } else {                                   // W rows (output cols)
                const int r = ((chunk - 16) << 3) + srow;
                src = (const char*)Whi + (((size_t)(col0 + r)) << 11) + kbyte + scol;
            }
            gload16(src, smem + (chunk << 10));
        }
        __syncthreads();
#pragma unroll
        for (int kk = 0; kk < 2; ++kk) {
            const int cb = (kk << 6) + ((lane >> 4) << 4);
            bf16x8 af[4], bf[4];
#pragma unroll
            for (int mi = 0; mi < 4; ++mi) {
                const int r = wr * 64 + mi * 16 + (lane & 15);
                af[mi] = *(const bf16x8*)(smem + r * 128 + (cb ^ ((r & 7) << 4)));
            }
#pragma unroll
            for (int ni = 0; ni < 4; ++ni) {
                const int r = wc * 64 + ni * 16 + (lane & 15);
                bf[ni] = *(const bf16x8*)(smem + 16384 + r * 128 + (cb ^ ((r & 7) << 4)));
            }
#pragma unroll
            for (int mi = 0; mi < 4; ++mi)
#pragma unroll
                for (int ni = 0; ni < 4; ++ni)
                    acc[mi][ni] = __builtin_amdgcn_mfma_f32_16x16x32_bf16(af[mi], bf[ni], acc[mi][ni], 0, 0, 0);
        }
    }

#pragma unroll
    for (int ni = 0; ni < 4; ++ni) {
        const int col = col0 + wc * 64 + ni * 16 + (lane & 15);
        const float bz = bias[col];
#pragma unroll
        for (int mi = 0; mi < 4; ++mi) {
            const int rbase = row0 + wr * 64 + mi * 16 + ((lane >> 4) << 2);
            const f32x4 v = acc[mi][ni];
#pragma unroll
            for (int j = 0; j < 4; ++j)
                outp[(size_t)(rbase + j) * DDIM + col] = f2bf(v[j] + bz);
        }
    }
}

// ---------------- Kernel C: projections via split-bf16 MFMA; LO=1 3-term (64KB), LO=0 1-term (32KB) ----------------
template <int LO>
__global__ __launch_bounds__(256)
void proj_split_kernel(const float* __restrict__ X, const unsigned short* __restrict__ Whi,
                       const unsigned short* __restrict__ Wlo, const float* __restrict__ bias,
                       void* __restrict__ outp, const int store_bf16)
{
    constexpr int WOFF = LO ? 32768 : 16384;           // W-plane base (no dead hole at LO=0)
    __shared__ char smem[LO ? 65536 : 32768];
    const int tid  = threadIdx.x;
    const int lane = tid & 63;
    const int w    = tid >> 6;
    const int wr   = w >> 1, wc = w & 1;
    const int row0 = blockIdx.x * 128;
    const int col0 = blockIdx.y * 128;

    const f32x4 zero = {0.f, 0.f, 0.f, 0.f};
    f32x4 acc[4][4];
#pragma unroll
    for (int mi = 0; mi < 4; ++mi)
#pragma unroll
        for (int ni = 0; ni < 4; ++ni) acc[mi][ni] = zero;

    const int srow = lane >> 3;
    const int scol = (((lane & 7) ^ srow) << 4);
    const int xr = tid >> 1, xh = tid & 1;

    for (int step = 0; step < 16; ++step) {
        const int kbyte = step << 7;
        const int k0    = step << 6;
        __syncthreads();
#pragma unroll
        for (int i = 0; i < (LO ? 8 : 4); ++i) {
            const int chunk = w + (i << 2);            // 0..31 (LO) or 0..15
            const int plane = chunk >> 4;
            const int r     = ((chunk & 15) << 3) + srow;
            const unsigned short* Wb = plane ? Wlo : Whi;
            const char* src = (const char*)Wb + (((size_t)(col0 + r)) << 11) + kbyte + scol;
            gload16(src, smem + WOFF + (chunk << 10));
        }
        {
            const float* Xp = X + (size_t)(row0 + xr) * DDIM + k0 + xh * 32;
            float4 xa[8];
#pragma unroll
            for (int i = 0; i < 8; ++i) xa[i] = ((const float4*)Xp)[i];
            const int xbase = xr * 128;
#pragma unroll
            for (int s4 = 0; s4 < 4; ++s4) {
                const float4 a = xa[2 * s4], b = xa[2 * s4 + 1];
                uint4 hw, lw;
                if (LO) {
                    split2(a.x, a.y, hw.x, lw.x);
                    split2(a.z, a.w, hw.y, lw.y);
                    split2(b.x, b.y, hw.z, lw.z);
                    split2(b.z, b.w, hw.w, lw.w);
                } else {
                    hw.x = (unsigned int)f2bf(a.x) | ((unsigned int)f2bf(a.y) << 16);
                    hw.y = (unsigned int)f2bf(a.z) | ((unsigned int)f2bf(a.w) << 16);
                    hw.z = (unsigned int)f2bf(b.x) | ((unsigned int)f2bf(b.y) << 16);
                    hw.w = (unsigned int)f2bf(b.z) | ((unsigned int)f2bf(b.w) << 16);
                }
                const int off = xbase + ((((xh << 2) + s4) ^ (xr & 7)) << 4);
                *(uint4*)(smem + off) = hw;
                if (LO) *(uint4*)(smem + 16384 + off) = lw;
            }
        }
        asm volatile("s_waitcnt vmcnt(0)" ::: "memory");
        __syncthreads();
#pragma unroll
        for (int kk = 0; kk < 2; ++kk) {
            const int cb = (kk << 6) + ((lane >> 4) << 4);
            bf16x8 ah[4], bh[4];
#pragma unroll
            for (int mi = 0; mi < 4; ++mi) {
                const int r = wr * 64 + mi * 16 + (lane & 15);
                ah[mi] = *(const bf16x8*)(smem + r * 128 + (cb ^ ((r & 7) << 4)));
            }
#pragma unroll
            for (int ni = 0; ni < 4; ++ni) {
                const int r = wc * 64 + ni * 16 + (lane & 15);
                bh[ni] = *(const bf16x8*)(smem + WOFF + r * 128 + (cb ^ ((r & 7) << 4)));
            }
#pragma unroll
            for (int mi = 0; mi < 4; ++mi)
#pragma unroll
                for (int ni = 0; ni < 4; ++ni)
                    acc[mi][ni] = __builtin_amdgcn_mfma_f32_16x16x32_bf16(ah[mi], bh[ni], acc[mi][ni], 0, 0, 0);
            if (LO) {
                bf16x8 al[4];
#pragma unroll
                for (int mi = 0; mi < 4; ++mi) {
                    const int r = wr * 64 + mi * 16 + (lane & 15);
                    al[mi] = *(const bf16x8*)(smem + 16384 + r * 128 + (cb ^ ((r & 7) << 4)));
                }
#pragma unroll
                for (int mi = 0; mi < 4; ++mi)
#pragma unroll
                    for (int ni = 0; ni < 4; ++ni)
                        acc[mi][ni] = __builtin_amdgcn_mfma_f32_16x16x32_bf16(al[mi], bh[ni], acc[mi][ni], 0, 0, 0);
                bf16x8 bl[4];
#pragma unroll
                for (int ni = 0; ni < 4; ++ni) {
                    const int r = wc * 64 + ni * 16 + (lane & 15);
                    bl[ni] = *(const bf16x8*)(smem + WOFF + 16384 + r * 128 + (cb ^ ((r & 7) << 4)));
                }
#pragma unroll
                for (int mi = 0; mi < 4; ++mi)
#pragma unroll
                    for (int ni = 0; ni < 4; ++ni)
                        acc[mi][ni] = __builtin_amdgcn_mfma_f32_16x16x32_bf16(ah[mi], bl[ni], acc[mi][ni], 0, 0, 0);
            }
        }
    }

#pragma unroll
    for (int ni = 0; ni < 4; ++ni) {
        const int col = col0 + wc * 64 + ni * 16 + (lane & 15);
        const float bz = bias[col];
#pragma unroll
        for (int mi = 0; mi < 4; ++mi) {
            const int rbase = row0 + wr * 64 + mi * 16 + ((lane >> 4) << 2);
            const f32x4 v = acc[mi][ni];
#pragma unroll
            for (int j = 0; j < 4; ++j) {
                const float val = v[j] + bz;
                if (store_bf16)
                    ((unsigned short*)outp)[(size_t)(rbase + j) * DDIM + col] = f2bf(val);
                else
                    ((float*)outp)[(size_t)(rbase + j) * DDIM + col] = val;
            }
        }
    }
}

// ---------------- Kernel D: per-token 8-head attention over 16 retrieved slots ----------------
__global__ __launch_bounds__(256)
void attn_kernel(const float* __restrict__ Qp, const __hip_bfloat16* __restrict__ Kp,
                 const __hip_bfloat16* __restrict__ Vp, const int* __restrict__ topk,
                 float* __restrict__ attn_out)
{
    const int t = blockIdx.x;
    __shared__ int   idx_s[KSEL];
    __shared__ float sc_s[4][KSEL];
    if (threadIdx.x < KSEL) idx_s[threadIdx.x] = topk[(size_t)t * KSEL + threadIdx.x];
    __syncthreads();
    const int wv   = threadIdx.x >> 6;
    const int lane = threadIdx.x & 63;
    const int jj = lane >> 2, p = lane & 3;
    const float scale = 0.08838834764831845f;  // 1/sqrt(128)
    const unsigned short* Kpu = (const unsigned short*)Kp;
    const unsigned short* Vpu = (const unsigned short*)Vp;

#pragma unroll 1
    for (int hh = 0; hh < 2; ++hh) {
        const int h = wv * 2 + hh;
        const float* qh = Qp + (size_t)t * DDIM + h * HDIM + p * 32;
        const unsigned short* krow = Kpu + (size_t)idx_s[jj] * DDIM + h * HDIM + p * 32;
        float s = 0.f;
#pragma unroll
        for (int u = 0; u < 32; u += 8) {
            uint4  kv = *(const uint4*)(krow + u);
            float4 qa = *(const float4*)(qh + u);
            float4 qb = *(const float4*)(qh + u + 4);
            const unsigned short* kk = (const unsigned short*)&kv;
            s += bf2f(kk[0]) * qa.x + bf2f(kk[1]) * qa.y + bf2f(kk[2]) * qa.z + bf2f(kk[3]) * qa.w
               + bf2f(kk[4]) * qb.x + bf2f(kk[5]) * qb.y + bf2f(kk[6]) * qb.z + bf2f(kk[7]) * qb.w;
        }
        s += __shfl_xor(s, 1);
        s += __shfl_xor(s, 2);
        if (p == 0) sc_s[wv][jj] = s * scale;
        __syncthreads();
        float mx = -__builtin_inff();
#pragma unroll
        for (int n = 0; n < KSEL; ++n) mx = fmaxf(mx, sc_s[wv][n]);
        float wj[KSEL]; float wsum = 0.f;
#pragma unroll
        for (int n = 0; n < KSEL; ++n) { wj[n] = __expf(sc_s[wv][n] - mx); wsum += wj[n]; }
        const float inv = 1.f / wsum;
        const int d = lane * 2;
        float o0 = 0.f, o1 = 0.f;
#pragma unroll
        for (int n = 0; n < KSEL; ++n) {
            const unsigned int vv = *(const unsigned int*)(Vpu + (size_t)idx_s[n] * DDIM + h * HDIM + d);
            const float w = wj[n] * inv;
            o0 += w * bf2f((unsigned short)(vv & 0xffffu));
            o1 += w * bf2f((unsigned short)(vv >> 16));
        }
        *(float2*)(attn_out + (size_t)t * DDIM + h * HDIM + d) = make_float2(o0, o1);
        __syncthreads();
    }
}

extern "C" void kernel_launch(void* const* d_in, const int* in_sizes, int n_in,
                              void* d_out, int out_size, void* d_ws, size_t ws_size,
                              hipStream_t stream)
{
    const float* queries = (const float*)d_in[0];
    const float* mkeys   = (const float*)d_in[1];
    const float* mvals   = (const float*)d_in[2];
    const float* ipw     = (const float*)d_in[3];
    const float* ipb     = (const float*)d_in[4];
    const float* opw     = (const float*)d_in[5];
    const float* opb     = (const float*)d_in[6];

    char* ws = (char*)d_ws;
    size_t off = 0;
    auto alloc = [&](size_t bytes) -> char* {
        char* p = ws + off;
        off += (bytes + 255) & ~(size_t)255;
        return p;
    };
    unsigned short* Khi  = (unsigned short*)alloc((size_t)MKEYS * DDIM * 2);    // 67.1 MB
    unsigned short* Qhi  = (unsigned short*)alloc((size_t)NROWS * DDIM * 2);    // 8.4 MB
    unsigned short* IPhi = (unsigned short*)alloc((size_t)3 * DDIM * DDIM * 2); // 6.3 MB
    unsigned short* IPlo = (unsigned short*)alloc((size_t)3 * DDIM * DDIM * 2); // 6.3 MB
    unsigned short* OPhi = (unsigned short*)alloc((size_t)DDIM * DDIM * 2);     // 2.1 MB
    unsigned short* OPlo = (unsigned short*)alloc((size_t)DDIM * DDIM * 2);     // 2.1 MB
    float* cand_val = (float*)alloc((size_t)NROWS * CANDS_PER_ROW * 4);         // 33.5 MB
    int*   cand_idx = (int*)  alloc((size_t)NROWS * CANDS_PER_ROW * 4);         // 33.5 MB (contiguous after cand_val)
    int*   cand32   = (int*)  alloc((size_t)NROWS * NCAND * 4);                 // 0.52 MB
    int*   topk     = (int*)  alloc((size_t)NROWS * KSEL * 4);                  // 0.26 MB
    float* Qp       = (float*)alloc((size_t)NROWS * DDIM * 4);                  // 16.8 MB
    float* attn_out = (float*)alloc((size_t)NROWS * DDIM * 4);                  // 16.8 MB
    // stream-ordered aliases (total ws ~194 MB):
    __hip_bfloat16* Kp = (__hip_bfloat16*)cand_val;   // cand_val+cand_idx = exactly 67.1 MB, dead after merge
    __hip_bfloat16* Vp = (__hip_bfloat16*)Khi;        // Khi dead after K-proj (runs before V-proj)

    // 0) converts (sims operands, hi-only) + weight splits
    conv_bf16_kernel<<<2048, 256, 0, stream>>>(queries, Qhi, NROWS * DDIM / 4);
    conv_bf16_kernel<<<2048, 256, 0, stream>>>(mkeys, Khi, MKEYS * DDIM / 4);
    split_bf16_kernel<<<1024, 256, 0, stream>>>(ipw, IPhi, IPlo, 3 * DDIM * DDIM / 4);
    split_bf16_kernel<<<512,  256, 0, stream>>>(opw, OPhi, OPlo, DDIM * DDIM / 4);
    // 1) bf16 similarity GEMM + per-keyblock top-8
    sims_mfma_kernel<<<dim3(NROWS / SBM, MKEYS / SBN), 256, 0, stream>>>(Qhi, Khi, cand_val, cand_idx);
    // 2) merge to top-32 candidates (bf16 scores)
    topk_merge_kernel<<<NROWS / 4, 256, 0, stream>>>(cand_val, cand_idx, cand32);
    // 3) exact fp32 rescore -> final top-16
    rescore_kernel<<<NROWS, 256, 0, stream>>>(queries, mkeys, cand32, topk);
    // 4) projections: q (3-term, f32 out), K (bf16xbf16 reusing Khi), V (1-term reg-staged)
    proj_split_kernel<1><<<dim3(NROWS / 128, 8), 256, 0, stream>>>(queries, IPhi, IPlo, ipb, Qp, 0);
    gemm_bb_kernel<<<dim3(MKEYS / 128, 8), 256, 0, stream>>>(Khi, IPhi + (size_t)DDIM * DDIM,
                                                             ipb + DDIM, (unsigned short*)Kp);
    proj_split_kernel<0><<<dim3(MKEYS / 128, 8), 256, 0, stream>>>(mvals, IPhi + 2 * (size_t)DDIM * DDIM,
                                                                   IPlo + 2 * (size_t)DDIM * DDIM, ipb + 2 * DDIM, Vp, 1);
    // 5) gather + attention
    attn_kernel<<<NROWS, 256, 0, stream>>>(Qp, Kp, Vp, topk, attn_out);
    // 6) output projection (3-term) -> d_out (f32)
    proj_split_kernel<1><<<dim3(NROWS / 128, 8), 256, 0, stream>>>(attn_out, OPhi, OPlo, opb, d_out, 0);
}

// Round 11
// 1044.071 us; speedup vs baseline: 2.4013x; 1.0890x over previous
//
#include <hip/hip_runtime.h>
#include <hip/hip_bf16.h>

#define NROWS 4096    // B*S
#define DDIM  1024
#define MKEYS 32768
#define HDIM  128
#define KSEL  16
#define NCAND 24      // rescored candidates per row (gap v16->v24 >> bf16 err)
#define BTOP  6       // per-keyblock kept candidates (P[miss] ~8e-6)

// ---- sims MFMA GEMM geometry: m97-style 128x128 tile, 4 waves, 32KB LDS ----
#define SBM 128
#define SBN 128
#define SNKB (MKEYS / SBN)            // 256 key blocks
#define CANDS_PER_ROW (SNKB * BTOP)   // 1536
#define CANDS_ALLOC   2048            // allocation stride (keeps Kp alias = 67MB region)
#define NSTEPS 16                     // K = 1024 bf16, BK = 64

typedef short bf16x8 __attribute__((ext_vector_type(8)));
typedef float f32x4  __attribute__((ext_vector_type(4)));

__device__ __forceinline__ float bf2f(unsigned short u) {
    union { unsigned int i; float f; } x; x.i = ((unsigned int)u) << 16; return x.f;
}
__device__ __forceinline__ unsigned short f2bf(float f) {
    union { float f; unsigned int u; } v; v.f = f;
    unsigned int r = (v.u + 0x7fffu + ((v.u >> 16) & 1u)) >> 16;   // RNE
    return (unsigned short)r;
}
__device__ __forceinline__ void gload16(const void* g, const void* l) {
    __builtin_amdgcn_global_load_lds((const __attribute__((address_space(1))) unsigned int*)g,
                                     (__attribute__((address_space(3))) unsigned int*)l, 16, 0, 0);
}
// sorted-descending top-N insertion, fully static indexing (no scratch)
template <int N>
__device__ __forceinline__ void insN(float v, int id, float* lv, int* li) {
    if (v > lv[N - 1]) {
#pragma unroll
        for (int i = 0; i < N; ++i) {
            const bool gt = v > lv[i];
            const float tv = gt ? lv[i] : v;
            const int   ti = gt ? li[i] : id;
            if (gt) { lv[i] = v; li[i] = id; }
            v = tv; id = ti;
        }
    }
}
// trunc-hi / RNE-lo split of two fp32 -> packed bf16 pair words
__device__ __forceinline__ void split2(float x0, float x1, unsigned int& hp, unsigned int& lp) {
    union { float f; unsigned int u; } u0, u1;
    u0.f = x0; u1.f = x1;
    hp = (u0.u >> 16) | (u1.u & 0xffff0000u);
    const float r0 = x0 - bf2f((unsigned short)(u0.u >> 16));
    const float r1 = x1 - bf2f((unsigned short)(u1.u >> 16));
    lp = (unsigned int)f2bf(r0) | ((unsigned int)f2bf(r1) << 16);
}

// ---------------- Kernel 0a: fp32 -> bf16 (RNE) ----------------
__global__ __launch_bounds__(256)
void conv_bf16_kernel(const float* __restrict__ x, unsigned short* __restrict__ hi, const int n4)
{
    int i = blockIdx.x * 256 + threadIdx.x;
    const int stride = gridDim.x * 256;
    for (; i < n4; i += stride) {
        const float4 f = ((const float4*)x)[i];
        ushort4 h;
        h.x = f2bf(f.x); h.y = f2bf(f.y); h.z = f2bf(f.z); h.w = f2bf(f.w);
        ((ushort4*)hi)[i] = h;
    }
}

// ---------------- Kernel 0b: fp32 -> (hi, lo) bf16 split (weights) ----------------
__global__ __launch_bounds__(256)
void split_bf16_kernel(const float* __restrict__ x, unsigned short* __restrict__ hi,
                       unsigned short* __restrict__ lo, const int n4)
{
    int i = blockIdx.x * 256 + threadIdx.x;
    const int stride = gridDim.x * 256;
    for (; i < n4; i += stride) {
        const float4 f = ((const float4*)x)[i];
        ushort4 h, l;
        h.x = f2bf(f.x); l.x = f2bf(f.x - bf2f(h.x));
        h.y = f2bf(f.y); l.y = f2bf(f.y - bf2f(h.y));
        h.z = f2bf(f.z); l.z = f2bf(f.z - bf2f(h.z));
        h.w = f2bf(f.w); l.w = f2bf(f.w - bf2f(h.w));
        ((ushort4*)hi)[i] = h;
        ((ushort4*)lo)[i] = l;
    }
}

// ---------------- Kernel A: sims(bf16) = Qhi.Khi^T, 128x128 single-buffer (m97 structure) ----------------
// 4 waves as 2x2 (wave tile 64x64, acc 4x4). LDS 32KB: A[128][64]bf16 @0, B[128][64] @16KB.
// Epilogue: ALL 256 threads scan (2 threads/row, 64 vals each), per-block TOP-6;
// half-lists merged via stride-9 LDS (odd stride -> conflict-free).
__global__ __launch_bounds__(256)
void sims_mfma_kernel(const unsigned short* __restrict__ Qhi, const unsigned short* __restrict__ Khi,
                      float* __restrict__ cand_val, int* __restrict__ cand_idx)
{
    __shared__ char smem[32768];
    const int tid  = threadIdx.x;
    const int lane = tid & 63;
    const int w    = tid >> 6;
    const int wr   = w >> 1, wc = w & 1;
    const int row0 = blockIdx.x * SBM;
    const int key0 = blockIdx.y * SBN;

    const f32x4 zero = {0.f, 0.f, 0.f, 0.f};
    f32x4 acc[4][4];
#pragma unroll
    for (int mi = 0; mi < 4; ++mi)
#pragma unroll
        for (int ni = 0; ni < 4; ++ni) acc[mi][ni] = zero;

    const int srow = lane >> 3;
    const int scol = (((lane & 7) ^ srow) << 4);      // pre-swizzled source byte col

#pragma unroll 1
    for (int step = 0; step < NSTEPS; ++step) {
        const int kbyte = step << 7;
        __syncthreads();                               // prev compute's LDS reads retired
#pragma unroll
        for (int i = 0; i < 8; ++i) {
            const int chunk = w + (i << 2);            // 0..31, wave-uniform
            const char* src;
            if (chunk < 16) {                          // A: rows 0..127
                const int r = (chunk << 3) + srow;
                src = (const char*)Qhi + (((size_t)(row0 + r)) << 11) + kbyte + scol;
            } else {                                   // B: keys 0..127
                const int r = ((chunk - 16) << 3) + srow;
                src = (const char*)Khi + (((size_t)(key0 + r)) << 11) + kbyte + scol;
            }
            gload16(src, smem + (chunk << 10));
        }
        __syncthreads();                               // staging landed (vmcnt drained)
#pragma unroll
        for (int kk = 0; kk < 2; ++kk) {
            const int cb = (kk << 6) + ((lane >> 4) << 4);
            bf16x8 af[4], bf[4];
#pragma unroll
            for (int mi = 0; mi < 4; ++mi) {
                const int r = wr * 64 + mi * 16 + (lane & 15);
                af[mi] = *(const bf16x8*)(smem + r * 128 + (cb ^ ((r & 7) << 4)));
            }
#pragma unroll
            for (int ni = 0; ni < 4; ++ni) {
                const int r = wc * 64 + ni * 16 + (lane & 15);
                bf[ni] = *(const bf16x8*)(smem + 16384 + r * 128 + (cb ^ ((r & 7) << 4)));
            }
#pragma unroll
            for (int mi = 0; mi < 4; ++mi)
#pragma unroll
                for (int ni = 0; ni < 4; ++ni)
                    acc[mi][ni] = __builtin_amdgcn_mfma_f32_16x16x32_bf16(af[mi], bf[ni], acc[mi][ni], 0, 0, 0);
        }
    }

    // ---- fused top-6 epilogue: 4 passes of 32 cols through LDS C tile [128][33] f32 ----
    float lv[BTOP]; int li[BTOP];
#pragma unroll
    for (int i = 0; i < BTOP; ++i) { lv[i] = -3.4e38f; li[i] = 0; }
    float* C_lds = (float*)smem;
    const int rowt = tid & 127;
    const int half = tid >> 7;

#pragma unroll
    for (int q = 0; q < 4; ++q) {
        __syncthreads();
        if (wc == (q >> 1)) {                          // 2 waves own these 32 global cols
#pragma unroll
            for (int mi = 0; mi < 4; ++mi)
#pragma unroll
                for (int nn = 0; nn < 2; ++nn) {
                    const int ni = ((q & 1) << 1) + nn;
                    const int r  = wr * 64 + mi * 16 + ((lane >> 4) << 2);
                    const int c  = (nn << 4) + (lane & 15);
                    const f32x4 v = acc[mi][ni];
#pragma unroll
                    for (int j = 0; j < 4; ++j) C_lds[(r + j) * 33 + c] = v[j];
                }
        }
        __syncthreads();
        // all 256 threads: thread scans 16 cols of its row-half
        const int gbase = key0 + (q << 5) + (half << 4);
#pragma unroll
        for (int cc = 0; cc < 16; ++cc)
            insN<BTOP>(C_lds[rowt * 33 + (half << 4) + cc], gbase + cc, lv, li);
    }
    // merge the two half-lists per row (exact; stride 9 -> odd -> conflict-free)
    __syncthreads();
    float* mv = (float*)smem;                          // [128][9] vals
    int*   mx = (int*)(smem + 128 * 9 * 4);            // [128][9] idxs
    if (half == 1) {
#pragma unroll
        for (int i = 0; i < BTOP; ++i) { mv[rowt * 9 + i] = lv[i]; mx[rowt * 9 + i] = li[i]; }
    }
    __syncthreads();
    if (half == 0) {
#pragma unroll
        for (int i = 0; i < BTOP; ++i)
            insN<BTOP>(mv[rowt * 9 + i], mx[rowt * 9 + i], lv, li);
        const size_t o = (((size_t)(row0 + rowt)) * SNKB + blockIdx.y) * BTOP;
#pragma unroll
        for (int i = 0; i < BTOP; ++i) { cand_val[o + i] = lv[i]; cand_idx[o + i] = li[i]; }
    }
}

// ---------------- Kernel B: merge 256x6 candidates -> top-24 (bf16 scores) per row ----------------
// 24 cands/lane = capacity 24 -> per-lane list is lossless.
__global__ __launch_bounds__(256)
void topk_merge_kernel(const float* __restrict__ cand_val, const int* __restrict__ cand_idx,
                       int* __restrict__ cand32)
{
    const int row  = blockIdx.x * 4 + (threadIdx.x >> 6);
    const int lane = threadIdx.x & 63;
    const size_t base = (size_t)row * CANDS_PER_ROW;
    float lv[NCAND]; int li[NCAND];
#pragma unroll
    for (int i = 0; i < NCAND; ++i) { lv[i] = -3.4e38f; li[i] = 0x7fffffff; }
#pragma unroll 1
    for (int m = 0; m < CANDS_PER_ROW / 64; ++m) {                // 24 per lane
        const int p = lane + (m << 6);
        insN<NCAND>(cand_val[base + p], cand_idx[base + p], lv, li);
    }
    int out = 0;
#pragma unroll 1
    for (int it = 0; it < NCAND; ++it) {
        float rv = lv[0]; int ridx = li[0];
#pragma unroll
        for (int off = 1; off < 64; off <<= 1) {
            const float ov = __shfl_xor(rv, off);
            const int   oi = __shfl_xor(ridx, off);
            if (ov > rv || (ov == rv && oi < ridx)) { rv = ov; ridx = oi; }
        }
        if (lane == it) out = ridx;
        if (li[0] == ridx) {
#pragma unroll
            for (int i = 0; i < NCAND - 1; ++i) { lv[i] = lv[i + 1]; li[i] = li[i + 1]; }
            lv[NCAND - 1] = -3.4e38f; li[NCAND - 1] = 0x7fffffff;
        }
    }
    if (lane < NCAND) cand32[(size_t)row * NCAND + lane] = out;
}

// ---------------- Kernel B2: exact fp32 rescore of 24 candidates -> final top-16 ----------------
__global__ __launch_bounds__(256)
void rescore_kernel(const float* __restrict__ Q, const float* __restrict__ K,
                    const int* __restrict__ cand32, int* __restrict__ topk)
{
    const int row  = blockIdx.x;
    const int wv   = threadIdx.x >> 6;
    const int lane = threadIdx.x & 63;
    __shared__ float sv[NCAND];
    __shared__ int   si[NCAND];
    if (threadIdx.x < NCAND) si[threadIdx.x] = cand32[(size_t)row * NCAND + threadIdx.x];
    float4 qv[4];
#pragma unroll
    for (int u = 0; u < 4; ++u)
        qv[u] = ((const float4*)(Q + (size_t)row * DDIM))[(u << 6) + lane];
    __syncthreads();
#pragma unroll 1
    for (int c = 0; c < NCAND / 4; ++c) {              // 6 cands per wave
        const int slot = wv * (NCAND / 4) + c;
        const float* kr = K + (size_t)si[slot] * DDIM;
        float s = 0.f;
#pragma unroll
        for (int u = 0; u < 4; ++u) {
            const float4 kv = ((const float4*)kr)[(u << 6) + lane];
            s += kv.x * qv[u].x + kv.y * qv[u].y + kv.z * qv[u].z + kv.w * qv[u].w;
        }
#pragma unroll
        for (int off = 32; off >= 1; off >>= 1) s += __shfl_xor(s, off);
        if (lane == 0) sv[slot] = s;
    }
    __syncthreads();
    if (wv == 0) {
        float v = (lane < NCAND) ? sv[lane] : -3.4e38f;
        int  id = (lane < NCAND) ? si[lane] : 0x7fffffff;
        int out = 0;
#pragma unroll 1
        for (int it = 0; it < KSEL; ++it) {
            float rv = v; int ridx = id;
#pragma unroll
            for (int off = 1; off < 64; off <<= 1) {
                const float ov = __shfl_xor(rv, off);
                const int   oi = __shfl_xor(ridx, off);
                if (ov > rv || (ov == rv && oi < ridx)) { rv = ov; ridx = oi; }
            }
            if (lane == it) out = ridx;
            if (id == ridx) v = -3.4e38f;
        }
        if (lane < KSEL) topk[(size_t)row * KSEL + lane] = out;
    }
}

// ---------------- Kernel C1: bf16 x bf16 GEMM + bias -> bf16 (K projection; pure gload_lds) ----------------
__global__ __launch_bounds__(256)
void gemm_bb_kernel(const unsigned short* __restrict__ Xb, const unsigned short* __restrict__ Whi,
                    const float* __restrict__ bias, unsigned short* __restrict__ outp)
{
    __shared__ char smem[32768];
    const int tid  = threadIdx.x;
    const int lane = tid & 63;
    const int w    = tid >> 6;
    const int wr   = w >> 1, wc = w & 1;
    const int row0 = blockIdx.x * 128;
    const int col0 = blockIdx.y * 128;

    const f32x4 zero = {0.f, 0.f, 0.f, 0.f};
    f32x4 acc[4][4];
#pragma unroll
    for (int mi = 0; mi < 4; ++mi)
#pragma unroll
        for (int ni = 0; ni < 4; ++ni) acc[mi][ni] = zero;

    const int srow = lane >> 3;
    const int scol = (((lane & 7) ^ srow) << 4);

#pragma unroll 1
    for (int step = 0; step < 16; ++step) {
        const int kbyte = step << 7;
        __syncthreads();
#pragma unroll
        for (int i = 0; i < 8; ++i) {
            const int chunk = w + (i << 2);            // 0..31
            const char* src;
            if (chunk < 16) {                          // X rows
                const int r = (chunk << 3) + srow;
                src = (const char*)Xb + (((size_t)(row0 + r)) << 11) + kbyte + scol;
            } else {                                   // W rows (output cols)
                const int r = ((chunk - 16) << 3) + srow;
                src = (const char*)Whi + (((size_t)(col0 + r)) << 11) + kbyte + scol;
            }
            gload16(src, smem + (chunk << 10));
        }
        __syncthreads();
#pragma unroll
        for (int kk = 0; kk < 2; ++kk) {
            const int cb = (kk << 6) + ((lane >> 4) << 4);
            bf16x8 af[4], bf[4];
#pragma unroll
            for (int mi = 0; mi < 4; ++mi) {
                const int r = wr * 64 + mi * 16 + (lane & 15);
                af[mi] = *(const bf16x8*)(smem + r * 128 + (cb ^ ((r & 7) << 4)));
            }
#pragma unroll
            for (int ni = 0; ni < 4; ++ni) {
                const int r = wc * 64 + ni * 16 + (lane & 15);
                bf[ni] = *(const bf16x8*)(smem + 16384 + r * 128 + (cb ^ ((r & 7) << 4)));
            }
#pragma unroll
            for (int mi = 0; mi < 4; ++mi)
#pragma unroll
                for (int ni = 0; ni < 4; ++ni)
                    acc[mi][ni] = __builtin_amdgcn_mfma_f32_16x16x32_bf16(af[mi], bf[ni], acc[mi][ni], 0, 0, 0);
        }
    }

#pragma unroll
    for (int ni = 0; ni < 4; ++ni) {
        const int col = col0 + wc * 64 + ni * 16 + (lane & 15);
        const float bz = bias[col];
#pragma unroll
        for (int mi = 0; mi < 4; ++mi) {
            const int rbase = row0 + wr * 64 + mi * 16 + ((lane >> 4) << 2);
            const f32x4 v = acc[mi][ni];
#pragma unroll
            for (int j = 0; j < 4; ++j)
                outp[(size_t)(rbase + j) * DDIM + col] = f2bf(v[j] + bz);
        }
    }
}

// ---------------- Kernel C: projections via split-bf16 MFMA; LO=1 3-term (64KB), LO=0 1-term (32KB) ----------------
template <int LO>
__global__ __launch_bounds__(256)
void proj_split_kernel(const float* __restrict__ X, const unsigned short* __restrict__ Whi,
                       const unsigned short* __restrict__ Wlo, const float* __restrict__ bias,
                       void* __restrict__ outp, const int store_bf16)
{
    constexpr int WOFF = LO ? 32768 : 16384;           // W-plane base (no dead hole at LO=0)
    __shared__ char smem[LO ? 65536 : 32768];
    const int tid  = threadIdx.x;
    const int lane = tid & 63;
    const int w    = tid >> 6;
    const int wr   = w >> 1, wc = w & 1;
    const int row0 = blockIdx.x * 128;
    const int col0 = blockIdx.y * 128;

    const f32x4 zero = {0.f, 0.f, 0.f, 0.f};
    f32x4 acc[4][4];
#pragma unroll
    for (int mi = 0; mi < 4; ++mi)
#pragma unroll
        for (int ni = 0; ni < 4; ++ni) acc[mi][ni] = zero;

    const int srow = lane >> 3;
    const int scol = (((lane & 7) ^ srow) << 4);
    const int xr = tid >> 1, xh = tid & 1;

    for (int step = 0; step < 16; ++step) {
        const int kbyte = step << 7;
        const int k0    = step << 6;
        __syncthreads();
#pragma unroll
        for (int i = 0; i < (LO ? 8 : 4); ++i) {
            const int chunk = w + (i << 2);            // 0..31 (LO) or 0..15
            const int plane = chunk >> 4;
            const int r     = ((chunk & 15) << 3) + srow;
            const unsigned short* Wb = plane ? Wlo : Whi;
            const char* src = (const char*)Wb + (((size_t)(col0 + r)) << 11) + kbyte + scol;
            gload16(src, smem + WOFF + (chunk << 10));
        }
        {
            const float* Xp = X + (size_t)(row0 + xr) * DDIM + k0 + xh * 32;
            float4 xa[8];
#pragma unroll
            for (int i = 0; i < 8; ++i) xa[i] = ((const float4*)Xp)[i];
            const int xbase = xr * 128;
#pragma unroll
            for (int s4 = 0; s4 < 4; ++s4) {
                const float4 a = xa[2 * s4], b = xa[2 * s4 + 1];
                uint4 hw, lw;
                if (LO) {
                    split2(a.x, a.y, hw.x, lw.x);
                    split2(a.z, a.w, hw.y, lw.y);
                    split2(b.x, b.y, hw.z, lw.z);
                    split2(b.z, b.w, hw.w, lw.w);
                } else {
                    hw.x = (unsigned int)f2bf(a.x) | ((unsigned int)f2bf(a.y) << 16);
                    hw.y = (unsigned int)f2bf(a.z) | ((unsigned int)f2bf(a.w) << 16);
                    hw.z = (unsigned int)f2bf(b.x) | ((unsigned int)f2bf(b.y) << 16);
                    hw.w = (unsigned int)f2bf(b.z) | ((unsigned int)f2bf(b.w) << 16);
                }
                const int off = xbase + ((((xh << 2) + s4) ^ (xr & 7)) << 4);
                *(uint4*)(smem + off) = hw;
                if (LO) *(uint4*)(smem + 16384 + off) = lw;
            }
        }
        asm volatile("s_waitcnt vmcnt(0)" ::: "memory");
        __syncthreads();
#pragma unroll
        for (int kk = 0; kk < 2; ++kk) {
            const int cb = (kk << 6) + ((lane >> 4) << 4);
            bf16x8 ah[4], bh[4];
#pragma unroll
            for (int mi = 0; mi < 4; ++mi) {
                const int r = wr * 64 + mi * 16 + (lane & 15);
                ah[mi] = *(const bf16x8*)(smem + r * 128 + (cb ^ ((r & 7) << 4)));
            }
#pragma unroll
            for (int ni = 0; ni < 4; ++ni) {
                const int r = wc * 64 + ni * 16 + (lane & 15);
                bh[ni] = *(const bf16x8*)(smem + WOFF + r * 128 + (cb ^ ((r & 7) << 4)));
            }
#pragma unroll
            for (int mi = 0; mi < 4; ++mi)
#pragma unroll
                for (int ni = 0; ni < 4; ++ni)
                    acc[mi][ni] = __builtin_amdgcn_mfma_f32_16x16x32_bf16(ah[mi], bh[ni], acc[mi][ni], 0, 0, 0);
            if (LO) {
                bf16x8 al[4];
#pragma unroll
                for (int mi = 0; mi < 4; ++mi) {
                    const int r = wr * 64 + mi * 16 + (lane & 15);
                    al[mi] = *(const bf16x8*)(smem + 16384 + r * 128 + (cb ^ ((r & 7) << 4)));
                }
#pragma unroll
                for (int mi = 0; mi < 4; ++mi)
#pragma unroll
                    for (int ni = 0; ni < 4; ++ni)
                        acc[mi][ni] = __builtin_amdgcn_mfma_f32_16x16x32_bf16(al[mi], bh[ni], acc[mi][ni], 0, 0, 0);
                bf16x8 bl[4];
#pragma unroll
                for (int ni = 0; ni < 4; ++ni) {
                    const int r = wc * 64 + ni * 16 + (lane & 15);
                    bl[ni] = *(const bf16x8*)(smem + WOFF + 16384 + r * 128 + (cb ^ ((r & 7) << 4)));
                }
#pragma unroll
                for (int mi = 0; mi < 4; ++mi)
#pragma unroll
                    for (int ni = 0; ni < 4; ++ni)
                        acc[mi][ni] = __builtin_amdgcn_mfma_f32_16x16x32_bf16(ah[mi], bl[ni], acc[mi][ni], 0, 0, 0);
            }
        }
    }

#pragma unroll
    for (int ni = 0; ni < 4; ++ni) {
        const int col = col0 + wc * 64 + ni * 16 + (lane & 15);
        const float bz = bias[col];
#pragma unroll
        for (int mi = 0; mi < 4; ++mi) {
            const int rbase = row0 + wr * 64 + mi * 16 + ((lane >> 4) << 2);
            const f32x4 v = acc[mi][ni];
#pragma unroll
            for (int j = 0; j < 4; ++j) {
                const float val = v[j] + bz;
                if (store_bf16)
                    ((unsigned short*)outp)[(size_t)(rbase + j) * DDIM + col] = f2bf(val);
                else
                    ((float*)outp)[(size_t)(rbase + j) * DDIM + col] = val;
            }
        }
    }
}

// ---------------- Kernel D: per-token 8-head attention over 16 retrieved slots ----------------
__global__ __launch_bounds__(256)
void attn_kernel(const float* __restrict__ Qp, const __hip_bfloat16* __restrict__ Kp,
                 const __hip_bfloat16* __restrict__ Vp, const int* __restrict__ topk,
                 float* __restrict__ attn_out)
{
    const int t = blockIdx.x;
    __shared__ int   idx_s[KSEL];
    __shared__ float sc_s[4][KSEL];
    if (threadIdx.x < KSEL) idx_s[threadIdx.x] = topk[(size_t)t * KSEL + threadIdx.x];
    __syncthreads();
    const int wv   = threadIdx.x >> 6;
    const int lane = threadIdx.x & 63;
    const int jj = lane >> 2, p = lane & 3;
    const float scale = 0.08838834764831845f;  // 1/sqrt(128)
    const unsigned short* Kpu = (const unsigned short*)Kp;
    const unsigned short* Vpu = (const unsigned short*)Vp;

#pragma unroll 1
    for (int hh = 0; hh < 2; ++hh) {
        const int h = wv * 2 + hh;
        const float* qh = Qp + (size_t)t * DDIM + h * HDIM + p * 32;
        const unsigned short* krow = Kpu + (size_t)idx_s[jj] * DDIM + h * HDIM + p * 32;
        float s = 0.f;
#pragma unroll
        for (int u = 0; u < 32; u += 8) {
            uint4  kv = *(const uint4*)(krow + u);
            float4 qa = *(const float4*)(qh + u);
            float4 qb = *(const float4*)(qh + u + 4);
            const unsigned short* kk = (const unsigned short*)&kv;
            s += bf2f(kk[0]) * qa.x + bf2f(kk[1]) * qa.y + bf2f(kk[2]) * qa.z + bf2f(kk[3]) * qa.w
               + bf2f(kk[4]) * qb.x + bf2f(kk[5]) * qb.y + bf2f(kk[6]) * qb.z + bf2f(kk[7]) * qb.w;
        }
        s += __shfl_xor(s, 1);
        s += __shfl_xor(s, 2);
        if (p == 0) sc_s[wv][jj] = s * scale;
        __syncthreads();
        float mx = -__builtin_inff();
#pragma unroll
        for (int n = 0; n < KSEL; ++n) mx = fmaxf(mx, sc_s[wv][n]);
        float wj[KSEL]; float wsum = 0.f;
#pragma unroll
        for (int n = 0; n < KSEL; ++n) { wj[n] = __expf(sc_s[wv][n] - mx); wsum += wj[n]; }
        const float inv = 1.f / wsum;
        const int d = lane * 2;
        float o0 = 0.f, o1 = 0.f;
#pragma unroll
        for (int n = 0; n < KSEL; ++n) {
            const unsigned int vv = *(const unsigned int*)(Vpu + (size_t)idx_s[n] * DDIM + h * HDIM + d);
            const float w = wj[n] * inv;
            o0 += w * bf2f((unsigned short)(vv & 0xffffu));
            o1 += w * bf2f((unsigned short)(vv >> 16));
        }
        *(float2*)(attn_out + (size_t)t * DDIM + h * HDIM + d) = make_float2(o0, o1);
        __syncthreads();
    }
}

extern "C" void kernel_launch(void* const* d_in, const int* in_sizes, int n_in,
                              void* d_out, int out_size, void* d_ws, size_t ws_size,
                              hipStream_t stream)
{
    const float* queries = (const float*)d_in[0];
    const float* mkeys   = (const float*)d_in[1];
    const float* mvals   = (const float*)d_in[2];
    const float* ipw     = (const float*)d_in[3];
    const float* ipb     = (const float*)d_in[4];
    const float* opw     = (const float*)d_in[5];
    const float* opb     = (const float*)d_in[6];

    char* ws = (char*)d_ws;
    size_t off = 0;
    auto alloc = [&](size_t bytes) -> char* {
        char* p = ws + off;
        off += (bytes + 255) & ~(size_t)255;
        return p;
    };
    unsigned short* Khi  = (unsigned short*)alloc((size_t)MKEYS * DDIM * 2);    // 67.1 MB
    unsigned short* Qhi  = (unsigned short*)alloc((size_t)NROWS * DDIM * 2);    // 8.4 MB
    unsigned short* IPhi = (unsigned short*)alloc((size_t)3 * DDIM * DDIM * 2); // 6.3 MB
    unsigned short* IPlo = (unsigned short*)alloc((size_t)3 * DDIM * DDIM * 2); // 6.3 MB
    unsigned short* OPhi = (unsigned short*)alloc((size_t)DDIM * DDIM * 2);     // 2.1 MB
    unsigned short* OPlo = (unsigned short*)alloc((size_t)DDIM * DDIM * 2);     // 2.1 MB
    float* cand_val = (float*)alloc((size_t)NROWS * CANDS_ALLOC * 4);           // 33.5 MB (alloc stride)
    int*   cand_idx = (int*)  alloc((size_t)NROWS * CANDS_ALLOC * 4);           // 33.5 MB (contiguous)
    int*   cand32   = (int*)  alloc((size_t)NROWS * NCAND * 4);                 // 0.39 MB
    int*   topk     = (int*)  alloc((size_t)NROWS * KSEL * 4);                  // 0.26 MB
    float* Qp       = (float*)alloc((size_t)NROWS * DDIM * 4);                  // 16.8 MB
    float* attn_out = (float*)alloc((size_t)NROWS * DDIM * 4);                  // 16.8 MB
    // stream-ordered aliases (total ws ~194 MB):
    __hip_bfloat16* Kp = (__hip_bfloat16*)cand_val;   // cand_val+cand_idx = 67.1 MB, dead after merge
    __hip_bfloat16* Vp = (__hip_bfloat16*)Khi;        // Khi dead after K-proj (runs before V-proj)

    // 0) converts (sims operands, hi-only) + weight splits
    conv_bf16_kernel<<<2048, 256, 0, stream>>>(queries, Qhi, NROWS * DDIM / 4);
    conv_bf16_kernel<<<2048, 256, 0, stream>>>(mkeys, Khi, MKEYS * DDIM / 4);
    split_bf16_kernel<<<1024, 256, 0, stream>>>(ipw, IPhi, IPlo, 3 * DDIM * DDIM / 4);
    split_bf16_kernel<<<512,  256, 0, stream>>>(opw, OPhi, OPlo, DDIM * DDIM / 4);
    // 1) bf16 similarity GEMM + per-keyblock top-6
    sims_mfma_kernel<<<dim3(NROWS / SBM, MKEYS / SBN), 256, 0, stream>>>(Qhi, Khi, cand_val, cand_idx);
    // 2) merge to top-24 candidates (bf16 scores; per-lane lossless)
    topk_merge_kernel<<<NROWS / 4, 256, 0, stream>>>(cand_val, cand_idx, cand32);
    // 3) exact fp32 rescore -> final top-16
    rescore_kernel<<<NROWS, 256, 0, stream>>>(queries, mkeys, cand32, topk);
    // 4) projections: q (3-term, f32 out), K (bf16xbf16 reusing Khi), V (1-term reg-staged)
    proj_split_kernel<1><<<dim3(NROWS / 128, 8), 256, 0, stream>>>(queries, IPhi, IPlo, ipb, Qp, 0);
    gemm_bb_kernel<<<dim3(MKEYS / 128, 8), 256, 0, stream>>>(Khi, IPhi + (size_t)DDIM * DDIM,
                                                             ipb + DDIM, (unsigned short*)Kp);
    proj_split_kernel<0><<<dim3(MKEYS / 128, 8), 256, 0, stream>>>(mvals, IPhi + 2 * (size_t)DDIM * DDIM,
                                                                   IPlo + 2 * (size_t)DDIM * DDIM, ipb + 2 * DDIM, Vp, 1);
    // 5) gather + attention
    attn_kernel<<<NROWS, 256, 0, stream>>>(Qp, Kp, Vp, topk, attn_out);
    // 6) output projection (3-term) -> d_out (f32)
    proj_split_kernel<1><<<dim3(NROWS / 128, 8), 256, 0, stream>>>(attn_out, OPhi, OPlo, opb, d_out, 0);
}

// Round 12
// 886.064 us; speedup vs baseline: 2.8295x; 1.1783x over previous
//
#include <hip/hip_runtime.h>
#include <hip/hip_bf16.h>

#define NROWS 4096    // B*S
#define DDIM  1024
#define MKEYS 32768
#define HDIM  128
#define KSEL  16
#define NCAND 24      // rescored candidates per row
#define BTOP  6       // per-keyblock kept candidates

// ---- sims MFMA GEMM geometry: m97-style 128x128 tile, 4 waves, 32KB LDS ----
#define SBM 128
#define SBN 128
#define SNKB (MKEYS / SBN)            // 256 key blocks
#define CANDS_PER_ROW (SNKB * BTOP)   // 1536
#define CANDS_ALLOC   2048            // allocation stride (cand region = 67.1MB = Vhi alias)
#define NSTEPS 16                     // K = 1024 bf16, BK = 64

typedef short bf16x8 __attribute__((ext_vector_type(8)));
typedef float f32x4  __attribute__((ext_vector_type(4)));

__device__ __forceinline__ float bf2f(unsigned short u) {
    union { unsigned int i; float f; } x; x.i = ((unsigned int)u) << 16; return x.f;
}
__device__ __forceinline__ unsigned short f2bf(float f) {
    union { float f; unsigned int u; } v; v.f = f;
    unsigned int r = (v.u + 0x7fffu + ((v.u >> 16) & 1u)) >> 16;   // RNE
    return (unsigned short)r;
}
__device__ __forceinline__ void gload16(const void* g, const void* l) {
    __builtin_amdgcn_global_load_lds((const __attribute__((address_space(1))) unsigned int*)g,
                                     (__attribute__((address_space(3))) unsigned int*)l, 16, 0, 0);
}
template <int N>
__device__ __forceinline__ void insN(float v, int id, float* lv, int* li) {
    if (v > lv[N - 1]) {
#pragma unroll
        for (int i = 0; i < N; ++i) {
            const bool gt = v > lv[i];
            const float tv = gt ? lv[i] : v;
            const int   ti = gt ? li[i] : id;
            if (gt) { lv[i] = v; li[i] = id; }
            v = tv; id = ti;
        }
    }
}
__device__ __forceinline__ void split2(float x0, float x1, unsigned int& hp, unsigned int& lp) {
    union { float f; unsigned int u; } u0, u1;
    u0.f = x0; u1.f = x1;
    hp = (u0.u >> 16) | (u1.u & 0xffff0000u);
    const float r0 = x0 - bf2f((unsigned short)(u0.u >> 16));
    const float r1 = x1 - bf2f((unsigned short)(u1.u >> 16));
    lp = (unsigned int)f2bf(r0) | ((unsigned int)f2bf(r1) << 16);
}

// ---------------- fp32 -> bf16 (RNE) ----------------
__global__ __launch_bounds__(256)
void conv_bf16_kernel(const float* __restrict__ x, unsigned short* __restrict__ hi, const int n4)
{
    int i = blockIdx.x * 256 + threadIdx.x;
    const int stride = gridDim.x * 256;
    for (; i < n4; i += stride) {
        const float4 f = ((const float4*)x)[i];
        ushort4 h;
        h.x = f2bf(f.x); h.y = f2bf(f.y); h.z = f2bf(f.z); h.w = f2bf(f.w);
        ((ushort4*)hi)[i] = h;
    }
}

// ---------------- fp32 -> (hi, lo) bf16 split (weights) ----------------
__global__ __launch_bounds__(256)
void split_bf16_kernel(const float* __restrict__ x, unsigned short* __restrict__ hi,
                       unsigned short* __restrict__ lo, const int n4)
{
    int i = blockIdx.x * 256 + threadIdx.x;
    const int stride = gridDim.x * 256;
    for (; i < n4; i += stride) {
        const float4 f = ((const float4*)x)[i];
        ushort4 h, l;
        h.x = f2bf(f.x); l.x = f2bf(f.x - bf2f(h.x));
        h.y = f2bf(f.y); l.y = f2bf(f.y - bf2f(h.y));
        h.z = f2bf(f.z); l.z = f2bf(f.z - bf2f(h.z));
        h.w = f2bf(f.w); l.w = f2bf(f.w - bf2f(h.w));
        ((ushort4*)hi)[i] = h;
        ((ushort4*)lo)[i] = l;
    }
}

// ---------------- wkT[h][j][c] = bf16(ipw[1024 + h*128 + c][j]) ----------------
__global__ __launch_bounds__(256)
void wk_transpose_kernel(const float* __restrict__ ipw, unsigned short* __restrict__ wkT)
{
    const int tt   = blockIdx.x * 256 + threadIdx.x;   // 512 blocks -> 1M elems / 8
    const int base = tt << 3;
    const int h    = base >> 17;
    const int rem  = base & 131071;
    const int j    = rem >> 7;
    const int c0   = rem & 127;                        // multiple of 8
    const float* src = ipw + ((size_t)(1024 + h * 128 + c0)) * 1024 + j;
    ushort4 o0, o1;
    o0.x = f2bf(src[0]);        o0.y = f2bf(src[1024]);
    o0.z = f2bf(src[2 * 1024]); o0.w = f2bf(src[3 * 1024]);
    o1.x = f2bf(src[4 * 1024]); o1.y = f2bf(src[5 * 1024]);
    o1.z = f2bf(src[6 * 1024]); o1.w = f2bf(src[7 * 1024]);
    *(ushort4*)(wkT + base)     = o0;
    *(ushort4*)(wkT + base + 4) = o1;
}

// ---------------- Kernel A: sims(bf16) = Qhi.Khi^T, 128x128 (unchanged r11) ----------------
__global__ __launch_bounds__(256)
void sims_mfma_kernel(const unsigned short* __restrict__ Qhi, const unsigned short* __restrict__ Khi,
                      float* __restrict__ cand_val, int* __restrict__ cand_idx)
{
    __shared__ char smem[32768];
    const int tid  = threadIdx.x;
    const int lane = tid & 63;
    const int w    = tid >> 6;
    const int wr   = w >> 1, wc = w & 1;
    const int row0 = blockIdx.x * SBM;
    const int key0 = blockIdx.y * SBN;

    const f32x4 zero = {0.f, 0.f, 0.f, 0.f};
    f32x4 acc[4][4];
#pragma unroll
    for (int mi = 0; mi < 4; ++mi)
#pragma unroll
        for (int ni = 0; ni < 4; ++ni) acc[mi][ni] = zero;

    const int srow = lane >> 3;
    const int scol = (((lane & 7) ^ srow) << 4);

#pragma unroll 1
    for (int step = 0; step < NSTEPS; ++step) {
        const int kbyte = step << 7;
        __syncthreads();
#pragma unroll
        for (int i = 0; i < 8; ++i) {
            const int chunk = w + (i << 2);
            const char* src;
            if (chunk < 16) {
                const int r = (chunk << 3) + srow;
                src = (const char*)Qhi + (((size_t)(row0 + r)) << 11) + kbyte + scol;
            } else {
                const int r = ((chunk - 16) << 3) + srow;
                src = (const char*)Khi + (((size_t)(key0 + r)) << 11) + kbyte + scol;
            }
            gload16(src, smem + (chunk << 10));
        }
        __syncthreads();
#pragma unroll
        for (int kk = 0; kk < 2; ++kk) {
            const int cb = (kk << 6) + ((lane >> 4) << 4);
            bf16x8 af[4], bf[4];
#pragma unroll
            for (int mi = 0; mi < 4; ++mi) {
                const int r = wr * 64 + mi * 16 + (lane & 15);
                af[mi] = *(const bf16x8*)(smem + r * 128 + (cb ^ ((r & 7) << 4)));
            }
#pragma unroll
            for (int ni = 0; ni < 4; ++ni) {
                const int r = wc * 64 + ni * 16 + (lane & 15);
                bf[ni] = *(const bf16x8*)(smem + 16384 + r * 128 + (cb ^ ((r & 7) << 4)));
            }
#pragma unroll
            for (int mi = 0; mi < 4; ++mi)
#pragma unroll
                for (int ni = 0; ni < 4; ++ni)
                    acc[mi][ni] = __builtin_amdgcn_mfma_f32_16x16x32_bf16(af[mi], bf[ni], acc[mi][ni], 0, 0, 0);
        }
    }

    float lv[BTOP]; int li[BTOP];
#pragma unroll
    for (int i = 0; i < BTOP; ++i) { lv[i] = -3.4e38f; li[i] = 0; }
    float* C_lds = (float*)smem;
    const int rowt = tid & 127;
    const int half = tid >> 7;

#pragma unroll
    for (int q = 0; q < 4; ++q) {
        __syncthreads();
        if (wc == (q >> 1)) {
#pragma unroll
            for (int mi = 0; mi < 4; ++mi)
#pragma unroll
                for (int nn = 0; nn < 2; ++nn) {
                    const int ni = ((q & 1) << 1) + nn;
                    const int r  = wr * 64 + mi * 16 + ((lane >> 4) << 2);
                    const int c  = (nn << 4) + (lane & 15);
                    const f32x4 v = acc[mi][ni];
#pragma unroll
                    for (int j = 0; j < 4; ++j) C_lds[(r + j) * 33 + c] = v[j];
                }
        }
        __syncthreads();
        const int gbase = key0 + (q << 5) + (half << 4);
#pragma unroll
        for (int cc = 0; cc < 16; ++cc)
            insN<BTOP>(C_lds[rowt * 33 + (half << 4) + cc], gbase + cc, lv, li);
    }
    __syncthreads();
    float* mv = (float*)smem;
    int*   mx = (int*)(smem + 128 * 9 * 4);
    if (half == 1) {
#pragma unroll
        for (int i = 0; i < BTOP; ++i) { mv[rowt * 9 + i] = lv[i]; mx[rowt * 9 + i] = li[i]; }
    }
    __syncthreads();
    if (half == 0) {
#pragma unroll
        for (int i = 0; i < BTOP; ++i)
            insN<BTOP>(mv[rowt * 9 + i], mx[rowt * 9 + i], lv, li);
        const size_t o = (((size_t)(row0 + rowt)) * SNKB + blockIdx.y) * BTOP;
#pragma unroll
        for (int i = 0; i < BTOP; ++i) { cand_val[o + i] = lv[i]; cand_idx[o + i] = li[i]; }
    }
}

// ---------------- Kernel B: merge -> top-24 per row (unchanged r11) ----------------
__global__ __launch_bounds__(256)
void topk_merge_kernel(const float* __restrict__ cand_val, const int* __restrict__ cand_idx,
                       int* __restrict__ cand32)
{
    const int row  = blockIdx.x * 4 + (threadIdx.x >> 6);
    const int lane = threadIdx.x & 63;
    const size_t base = (size_t)row * CANDS_PER_ROW;
    float lv[NCAND]; int li[NCAND];
#pragma unroll
    for (int i = 0; i < NCAND; ++i) { lv[i] = -3.4e38f; li[i] = 0x7fffffff; }
#pragma unroll 1
    for (int m = 0; m < CANDS_PER_ROW / 64; ++m) {
        const int p = lane + (m << 6);
        insN<NCAND>(cand_val[base + p], cand_idx[base + p], lv, li);
    }
    int out = 0;
#pragma unroll 1
    for (int it = 0; it < NCAND; ++it) {
        float rv = lv[0]; int ridx = li[0];
#pragma unroll
        for (int off = 1; off < 64; off <<= 1) {
            const float ov = __shfl_xor(rv, off);
            const int   oi = __shfl_xor(ridx, off);
            if (ov > rv || (ov == rv && oi < ridx)) { rv = ov; ridx = oi; }
        }
        if (lane == it) out = ridx;
        if (li[0] == ridx) {
#pragma unroll
            for (int i = 0; i < NCAND - 1; ++i) { lv[i] = lv[i + 1]; li[i] = li[i + 1]; }
            lv[NCAND - 1] = -3.4e38f; li[NCAND - 1] = 0x7fffffff;
        }
    }
    if (lane < NCAND) cand32[(size_t)row * NCAND + lane] = out;
}

// ---------------- Kernel B2: exact fp32 rescore -> final top-16 (unchanged r11) ----------------
__global__ __launch_bounds__(256)
void rescore_kernel(const float* __restrict__ Q, const float* __restrict__ K,
                    const int* __restrict__ cand32, int* __restrict__ topk)
{
    const int row  = blockIdx.x;
    const int wv   = threadIdx.x >> 6;
    const int lane = threadIdx.x & 63;
    __shared__ float sv[NCAND];
    __shared__ int   si[NCAND];
    if (threadIdx.x < NCAND) si[threadIdx.x] = cand32[(size_t)row * NCAND + threadIdx.x];
    float4 qv[4];
#pragma unroll
    for (int u = 0; u < 4; ++u)
        qv[u] = ((const float4*)(Q + (size_t)row * DDIM))[(u << 6) + lane];
    __syncthreads();
#pragma unroll 1
    for (int c = 0; c < NCAND / 4; ++c) {
        const int slot = wv * (NCAND / 4) + c;
        const float* kr = K + (size_t)si[slot] * DDIM;
        float s = 0.f;
#pragma unroll
        for (int u = 0; u < 4; ++u) {
            const float4 kv = ((const float4*)kr)[(u << 6) + lane];
            s += kv.x * qv[u].x + kv.y * qv[u].y + kv.z * qv[u].z + kv.w * qv[u].w;
        }
#pragma unroll
        for (int off = 32; off >= 1; off >>= 1) s += __shfl_xor(s, off);
        if (lane == 0) sv[slot] = s;
    }
    __syncthreads();
    if (wv == 0) {
        float v = (lane < NCAND) ? sv[lane] : -3.4e38f;
        int  id = (lane < NCAND) ? si[lane] : 0x7fffffff;
        int out = 0;
#pragma unroll 1
        for (int it = 0; it < KSEL; ++it) {
            float rv = v; int ridx = id;
#pragma unroll
            for (int off = 1; off < 64; off <<= 1) {
                const float ov = __shfl_xor(rv, off);
                const int   oi = __shfl_xor(ridx, off);
                if (ov > rv || (ov == rv && oi < ridx)) { rv = ov; ridx = oi; }
            }
            if (lane == it) out = ridx;
            if (id == ridx) v = -3.4e38f;
        }
        if (lane < KSEL) topk[(size_t)row * KSEL + lane] = out;
    }
}

// ---------------- Kernel C: X(fp32) x W projections (LO=1 3-term / LO=0 1-term) ----------------
template <int LO>
__global__ __launch_bounds__(256)
void proj_split_kernel(const float* __restrict__ X, const unsigned short* __restrict__ Whi,
                       const unsigned short* __restrict__ Wlo, const float* __restrict__ bias,
                       void* __restrict__ outp, const int store_bf16)
{
    constexpr int WOFF = LO ? 32768 : 16384;
    __shared__ char smem[LO ? 65536 : 32768];
    const int tid  = threadIdx.x;
    const int lane = tid & 63;
    const int w    = tid >> 6;
    const int wr   = w >> 1, wc = w & 1;
    const int row0 = blockIdx.x * 128;
    const int col0 = blockIdx.y * 128;

    const f32x4 zero = {0.f, 0.f, 0.f, 0.f};
    f32x4 acc[4][4];
#pragma unroll
    for (int mi = 0; mi < 4; ++mi)
#pragma unroll
        for (int ni = 0; ni < 4; ++ni) acc[mi][ni] = zero;

    const int srow = lane >> 3;
    const int scol = (((lane & 7) ^ srow) << 4);
    const int xr = tid >> 1, xh = tid & 1;

    for (int step = 0; step < 16; ++step) {
        const int kbyte = step << 7;
        const int k0    = step << 6;
        __syncthreads();
#pragma unroll
        for (int i = 0; i < (LO ? 8 : 4); ++i) {
            const int chunk = w + (i << 2);
            const int plane = chunk >> 4;
            const int r     = ((chunk & 15) << 3) + srow;
            const unsigned short* Wb = plane ? Wlo : Whi;
            const char* src = (const char*)Wb + (((size_t)(col0 + r)) << 11) + kbyte + scol;
            gload16(src, smem + WOFF + (chunk << 10));
        }
        {
            const float* Xp = X + (size_t)(row0 + xr) * DDIM + k0 + xh * 32;
            float4 xa[8];
#pragma unroll
            for (int i = 0; i < 8; ++i) xa[i] = ((const float4*)Xp)[i];
            const int xbase = xr * 128;
#pragma unroll
            for (int s4 = 0; s4 < 4; ++s4) {
                const float4 a = xa[2 * s4], b = xa[2 * s4 + 1];
                uint4 hw, lw;
                if (LO) {
                    split2(a.x, a.y, hw.x, lw.x);
                    split2(a.z, a.w, hw.y, lw.y);
                    split2(b.x, b.y, hw.z, lw.z);
                    split2(b.z, b.w, hw.w, lw.w);
                } else {
                    hw.x = (unsigned int)f2bf(a.x) | ((unsigned int)f2bf(a.y) << 16);
                    hw.y = (unsigned int)f2bf(a.z) | ((unsigned int)f2bf(a.w) << 16);
                    hw.z = (unsigned int)f2bf(b.x) | ((unsigned int)f2bf(b.y) << 16);
                    hw.w = (unsigned int)f2bf(b.z) | ((unsigned int)f2bf(b.w) << 16);
                }
                const int off = xbase + ((((xh << 2) + s4) ^ (xr & 7)) << 4);
                *(uint4*)(smem + off) = hw;
                if (LO) *(uint4*)(smem + 16384 + off) = lw;
            }
        }
        asm volatile("s_waitcnt vmcnt(0)" ::: "memory");
        __syncthreads();
#pragma unroll
        for (int kk = 0; kk < 2; ++kk) {
            const int cb = (kk << 6) + ((lane >> 4) << 4);
            bf16x8 ah[4], bh[4];
#pragma unroll
            for (int mi = 0; mi < 4; ++mi) {
                const int r = wr * 64 + mi * 16 + (lane & 15);
                ah[mi] = *(const bf16x8*)(smem + r * 128 + (cb ^ ((r & 7) << 4)));
            }
#pragma unroll
            for (int ni = 0; ni < 4; ++ni) {
                const int r = wc * 64 + ni * 16 + (lane & 15);
                bh[ni] = *(const bf16x8*)(smem + WOFF + r * 128 + (cb ^ ((r & 7) << 4)));
            }
#pragma unroll
            for (int mi = 0; mi < 4; ++mi)
#pragma unroll
                for (int ni = 0; ni < 4; ++ni)
                    acc[mi][ni] = __builtin_amdgcn_mfma_f32_16x16x32_bf16(ah[mi], bh[ni], acc[mi][ni], 0, 0, 0);
            if (LO) {
                bf16x8 al[4];
#pragma unroll
                for (int mi = 0; mi < 4; ++mi) {
                    const int r = wr * 64 + mi * 16 + (lane & 15);
                    al[mi] = *(const bf16x8*)(smem + 16384 + r * 128 + (cb ^ ((r & 7) << 4)));
                }
#pragma unroll
                for (int mi = 0; mi < 4; ++mi)
#pragma unroll
                    for (int ni = 0; ni < 4; ++ni)
                        acc[mi][ni] = __builtin_amdgcn_mfma_f32_16x16x32_bf16(al[mi], bh[ni], acc[mi][ni], 0, 0, 0);
                bf16x8 bl[4];
#pragma unroll
                for (int ni = 0; ni < 4; ++ni) {
                    const int r = wc * 64 + ni * 16 + (lane & 15);
                    bl[ni] = *(const bf16x8*)(smem + WOFF + 16384 + r * 128 + (cb ^ ((r & 7) << 4)));
                }
#pragma unroll
                for (int mi = 0; mi < 4; ++mi)
#pragma unroll
                    for (int ni = 0; ni < 4; ++ni)
                        acc[mi][ni] = __builtin_amdgcn_mfma_f32_16x16x32_bf16(ah[mi], bl[ni], acc[mi][ni], 0, 0, 0);
            }
        }
    }

#pragma unroll
    for (int ni = 0; ni < 4; ++ni) {
        const int col = col0 + wc * 64 + ni * 16 + (lane & 15);
        const float bz = bias[col];
#pragma unroll
        for (int mi = 0; mi < 4; ++mi) {
            const int rbase = row0 + wr * 64 + mi * 16 + ((lane >> 4) << 2);
            const f32x4 v = acc[mi][ni];
#pragma unroll
            for (int j = 0; j < 4; ++j) {
                const float val = v[j] + bz;
                if (store_bf16)
                    ((unsigned short*)outp)[(size_t)(rbase + j) * DDIM + col] = f2bf(val);
                else
                    ((float*)outp)[(size_t)(rbase + j) * DDIM + col] = val;
            }
        }
    }
}

// ---------------- Kernel U: u[t, h*1024+j] = sum_c Qpb[t, h*128+c] * wkT[h][j][c]  (K=128) ----------------
__global__ __launch_bounds__(256)
void ugemm_kernel(const unsigned short* __restrict__ Qpb, const unsigned short* __restrict__ wkT,
                  unsigned short* __restrict__ u)
{
    __shared__ char smem[32768];
    const int tid  = threadIdx.x;
    const int lane = tid & 63;
    const int w    = tid >> 6;
    const int wr   = w >> 1, wc = w & 1;
    const int row0 = blockIdx.x * 128;      // tokens
    const int j0   = blockIdx.y * 128;      // u cols
    const int h    = blockIdx.z;

    const f32x4 zero = {0.f, 0.f, 0.f, 0.f};
    f32x4 acc[4][4];
#pragma unroll
    for (int mi = 0; mi < 4; ++mi)
#pragma unroll
        for (int ni = 0; ni < 4; ++ni) acc[mi][ni] = zero;

    const int srow = lane >> 3;
    const int scol = (((lane & 7) ^ srow) << 4);

#pragma unroll 1
    for (int step = 0; step < 2; ++step) {
        const int kbyte = step << 7;
        __syncthreads();
#pragma unroll
        for (int i = 0; i < 8; ++i) {
            const int chunk = w + (i << 2);
            const char* src;
            if (chunk < 16) {               // A: Qpb rows, head-slice c
                const int r = (chunk << 3) + srow;
                src = (const char*)Qpb + (((size_t)(row0 + r)) << 11) + h * 256 + kbyte + scol;
            } else {                        // B: wkT rows j (256B each)
                const int r = ((chunk - 16) << 3) + srow;
                src = (const char*)wkT + ((size_t)h << 18) + (((size_t)(j0 + r)) << 8) + kbyte + scol;
            }
            gload16(src, smem + (chunk << 10));
        }
        __syncthreads();
#pragma unroll
        for (int kk = 0; kk < 2; ++kk) {
            const int cb = (kk << 6) + ((lane >> 4) << 4);
            bf16x8 af[4], bf[4];
#pragma unroll
            for (int mi = 0; mi < 4; ++mi) {
                const int r = wr * 64 + mi * 16 + (lane & 15);
                af[mi] = *(const bf16x8*)(smem + r * 128 + (cb ^ ((r & 7) << 4)));
            }
#pragma unroll
            for (int ni = 0; ni < 4; ++ni) {
                const int r = wc * 64 + ni * 16 + (lane & 15);
                bf[ni] = *(const bf16x8*)(smem + 16384 + r * 128 + (cb ^ ((r & 7) << 4)));
            }
#pragma unroll
            for (int mi = 0; mi < 4; ++mi)
#pragma unroll
                for (int ni = 0; ni < 4; ++ni)
                    acc[mi][ni] = __builtin_amdgcn_mfma_f32_16x16x32_bf16(af[mi], bf[ni], acc[mi][ni], 0, 0, 0);
        }
    }

#pragma unroll
    for (int ni = 0; ni < 4; ++ni) {
        const int col = j0 + wc * 64 + ni * 16 + (lane & 15);
#pragma unroll
        for (int mi = 0; mi < 4; ++mi) {
            const int rbase = row0 + wr * 64 + mi * 16 + ((lane >> 4) << 2);
            const f32x4 v = acc[mi][ni];
#pragma unroll
            for (int j = 0; j < 4; ++j)
                u[(size_t)(rbase + j) * 8192 + h * 1024 + col] = f2bf(v[j]);   // no bias (softmax-invariant)
        }
    }
}

// ---------------- Kernel D2: scores from u . raw-K, softmax, z = attn @ raw-V (z overwrites u) ----------------
__global__ __launch_bounds__(256)
void attn2_kernel(const unsigned short* __restrict__ Khi, const unsigned short* __restrict__ Vhi,
                  unsigned short* __restrict__ uz, const int* __restrict__ topk)
{
    __shared__ char smem[66112];                 // K 32KB @0 (src-swizzled), V 32KB @32768, idx@65536, sc@65600
    int*   idx_s = (int*)(smem + 65536);
    float* sc_s  = (float*)(smem + 65600);       // [8][16]
    const int t   = blockIdx.x;
    const int tid = threadIdx.x;
    if (tid < KSEL) idx_s[tid] = topk[(size_t)t * KSEL + tid];
    __syncthreads();
#pragma unroll
    for (int i = 0; i < 8; ++i) {
        const int s   = tid + (i << 8);
        const int row = s >> 7, col = s & 127;
        const size_t kb = ((size_t)idx_s[row]) << 11;
        gload16((const char*)Khi + kb + ((col ^ (row & 7)) << 4), smem + (s << 4));
        gload16((const char*)Vhi + kb + (col << 4),               smem + 32768 + (s << 4));
    }
    __syncthreads();                             // staging landed
    // scores: pair (h,k) handled by 2 threads (sub halves of 1024 dims)
    {
        const int p = tid >> 1, sub = tid & 1;
        const int h = p >> 4, k = p & 15;
        const unsigned short* urow = uz + (size_t)t * 8192 + h * 1024 + sub * 512;
        float s = 0.f;
#pragma unroll 8
        for (int j = 0; j < 64; ++j) {
            const uint4 uw = *(const uint4*)(urow + (j << 3));
            const uint4 kw = *(const uint4*)(smem + (k << 11) + ((((sub << 6) + j) ^ (k & 7)) << 4));
            s += bf2f((unsigned short)(uw.x & 0xffffu)) * bf2f((unsigned short)(kw.x & 0xffffu))
               + bf2f((unsigned short)(uw.x >> 16))     * bf2f((unsigned short)(kw.x >> 16))
               + bf2f((unsigned short)(uw.y & 0xffffu)) * bf2f((unsigned short)(kw.y & 0xffffu))
               + bf2f((unsigned short)(uw.y >> 16))     * bf2f((unsigned short)(kw.y >> 16))
               + bf2f((unsigned short)(uw.z & 0xffffu)) * bf2f((unsigned short)(kw.z & 0xffffu))
               + bf2f((unsigned short)(uw.z >> 16))     * bf2f((unsigned short)(kw.z >> 16))
               + bf2f((unsigned short)(uw.w & 0xffffu)) * bf2f((unsigned short)(kw.w & 0xffffu))
               + bf2f((unsigned short)(uw.w >> 16))     * bf2f((unsigned short)(kw.w >> 16));
        }
        s += __shfl_xor(s, 1);
        if (sub == 0) sc_s[h * 16 + k] = s;
    }
    __syncthreads();                             // all u reads complete; sc ready -> safe to overwrite uz
    // softmax (redundant per 32-thread head group) + z
    const int h  = tid >> 5;
    const int dp = tid & 31;
    const float scale = 0.08838834764831845f;    // 1/sqrt(128)
    float mxv = -3.4e38f;
#pragma unroll
    for (int n = 0; n < KSEL; ++n) mxv = fmaxf(mxv, sc_s[h * 16 + n]);
    float wgt[KSEL]; float wsum = 0.f;
#pragma unroll
    for (int n = 0; n < KSEL; ++n) { wgt[n] = __expf((sc_s[h * 16 + n] - mxv) * scale); wsum += wgt[n]; }
    const float inv = 1.f / wsum;
#pragma unroll
    for (int n = 0; n < KSEL; ++n) wgt[n] *= inv;
#pragma unroll 1
    for (int j = 0; j < 16; ++j) {
        float z0 = 0.f, z1 = 0.f;
#pragma unroll
        for (int k = 0; k < 16; ++k) {
            const unsigned int vv = *(const unsigned int*)(smem + 32768 + (k << 11) + (j << 7) + (dp << 2));
            z0 += wgt[k] * bf2f((unsigned short)(vv & 0xffffu));
            z1 += wgt[k] * bf2f((unsigned short)(vv >> 16));
        }
        *(unsigned int*)((char*)uz + (size_t)t * 16384 + (h << 11) + (j << 7) + (dp << 2)) =
            (unsigned int)f2bf(z0) | ((unsigned int)f2bf(z1) << 16);
    }
}

// ---------------- Kernel Z: attn_out[t, h*128+c] = sum_d z[t,h,d]*Wv_h[c,d] + bv ----------------
__global__ __launch_bounds__(256)
void zout_kernel(const unsigned short* __restrict__ z, const unsigned short* __restrict__ IPhi,
                 const float* __restrict__ ipb, float* __restrict__ attn_out)
{
    __shared__ char smem[32768];
    const int tid  = threadIdx.x;
    const int lane = tid & 63;
    const int w    = tid >> 6;
    const int wr   = w >> 1, wc = w & 1;
    const int row0 = blockIdx.x * 128;
    const int h    = blockIdx.y;

    const f32x4 zero = {0.f, 0.f, 0.f, 0.f};
    f32x4 acc[4][4];
#pragma unroll
    for (int mi = 0; mi < 4; ++mi)
#pragma unroll
        for (int ni = 0; ni < 4; ++ni) acc[mi][ni] = zero;

    const int srow = lane >> 3;
    const int scol = (((lane & 7) ^ srow) << 4);

#pragma unroll 1
    for (int step = 0; step < 16; ++step) {
        const int kbyte = step << 7;
        __syncthreads();
#pragma unroll
        for (int i = 0; i < 8; ++i) {
            const int chunk = w + (i << 2);
            const char* src;
            if (chunk < 16) {               // A: z rows (stride 16KB), head slice
                const int r = (chunk << 3) + srow;
                src = (const char*)z + (((size_t)(row0 + r)) << 14) + (h << 11) + kbyte + scol;
            } else {                        // B: Wv rows = ipw-space rows 2048 + h*128 + r
                const int r = ((chunk - 16) << 3) + srow;
                src = (const char*)IPhi + (((size_t)(2048 + h * 128 + r)) << 11) + kbyte + scol;
            }
            gload16(src, smem + (chunk << 10));
        }
        __syncthreads();
#pragma unroll
        for (int kk = 0; kk < 2; ++kk) {
            const int cb = (kk << 6) + ((lane >> 4) << 4);
            bf16x8 af[4], bf[4];
#pragma unroll
            for (int mi = 0; mi < 4; ++mi) {
                const int r = wr * 64 + mi * 16 + (lane & 15);
                af[mi] = *(const bf16x8*)(smem + r * 128 + (cb ^ ((r & 7) << 4)));
            }
#pragma unroll
            for (int ni = 0; ni < 4; ++ni) {
                const int r = wc * 64 + ni * 16 + (lane & 15);
                bf[ni] = *(const bf16x8*)(smem + 16384 + r * 128 + (cb ^ ((r & 7) << 4)));
            }
#pragma unroll
            for (int mi = 0; mi < 4; ++mi)
#pragma unroll
                for (int ni = 0; ni < 4; ++ni)
                    acc[mi][ni] = __builtin_amdgcn_mfma_f32_16x16x32_bf16(af[mi], bf[ni], acc[mi][ni], 0, 0, 0);
        }
    }

#pragma unroll
    for (int ni = 0; ni < 4; ++ni) {
        const int cl = wc * 64 + ni * 16 + (lane & 15);        // 0..127 within head
        const float bz = ipb[2048 + h * 128 + cl];
#pragma unroll
        for (int mi = 0; mi < 4; ++mi) {
            const int rbase = row0 + wr * 64 + mi * 16 + ((lane >> 4) << 2);
            const f32x4 v = acc[mi][ni];
#pragma unroll
            for (int j = 0; j < 4; ++j)
                attn_out[(size_t)(rbase + j) * 1024 + h * 128 + cl] = v[j] + bz;
        }
    }
}

extern "C" void kernel_launch(void* const* d_in, const int* in_sizes, int n_in,
                              void* d_out, int out_size, void* d_ws, size_t ws_size,
                              hipStream_t stream)
{
    const float* queries = (const float*)d_in[0];
    const float* mkeys   = (const float*)d_in[1];
    const float* mvals   = (const float*)d_in[2];
    const float* ipw     = (const float*)d_in[3];
    const float* ipb     = (const float*)d_in[4];
    const float* opw     = (const float*)d_in[5];
    const float* opb     = (const float*)d_in[6];

    char* ws = (char*)d_ws;
    size_t off = 0;
    auto alloc = [&](size_t bytes) -> char* {
        char* p = ws + off;
        off += (bytes + 255) & ~(size_t)255;
        return p;
    };
    unsigned short* Khi  = (unsigned short*)alloc((size_t)MKEYS * DDIM * 2);    // 67.1 MB
    unsigned short* Qhi  = (unsigned short*)alloc((size_t)NROWS * DDIM * 2);    // 8.4 MB
    unsigned short* IPhi = (unsigned short*)alloc((size_t)3 * DDIM * DDIM * 2); // 6.3 MB
    unsigned short* IPlo = (unsigned short*)alloc((size_t)3 * DDIM * DDIM * 2); // 6.3 MB
    unsigned short* OPhi = (unsigned short*)alloc((size_t)DDIM * DDIM * 2);     // 2.1 MB
    unsigned short* OPlo = (unsigned short*)alloc((size_t)DDIM * DDIM * 2);     // 2.1 MB
    unsigned short* wkT  = (unsigned short*)alloc((size_t)DDIM * DDIM * 2);     // 2.1 MB
    float* cand_val = (float*)alloc((size_t)NROWS * CANDS_ALLOC * 4);           // 33.55 MB
    int*   cand_idx = (int*)  alloc((size_t)NROWS * CANDS_ALLOC * 4);           // 33.55 MB (contiguous)
    int*   cand32   = (int*)  alloc((size_t)NROWS * NCAND * 4);                 // 0.39 MB
    int*   topk     = (int*)  alloc((size_t)NROWS * KSEL * 4);                  // 0.26 MB
    unsigned short* u = (unsigned short*)alloc((size_t)NROWS * 8 * DDIM * 2);   // 67.1 MB (z in-place)
    // aliases (total ~229 MB <= 235 proven):
    unsigned short* Qpb = (unsigned short*)Qhi;       // Qhi dead after sims
    unsigned short* Vhi = (unsigned short*)cand_val;  // cand region (67.1MB) dead after merge
    float* attn_out     = (float*)Khi;                // Khi dead after attn2; zout runs after

    // 0) converts + weight splits + Wk transpose
    conv_bf16_kernel<<<2048, 256, 0, stream>>>(queries, Qhi, NROWS * DDIM / 4);
    conv_bf16_kernel<<<2048, 256, 0, stream>>>(mkeys, Khi, MKEYS * DDIM / 4);
    split_bf16_kernel<<<1024, 256, 0, stream>>>(ipw, IPhi, IPlo, 3 * DDIM * DDIM / 4);
    split_bf16_kernel<<<512,  256, 0, stream>>>(opw, OPhi, OPlo, DDIM * DDIM / 4);
    wk_transpose_kernel<<<512, 256, 0, stream>>>(ipw, wkT);
    // 1) bf16 similarity GEMM + per-keyblock top-6
    sims_mfma_kernel<<<dim3(NROWS / SBM, MKEYS / SBN), 256, 0, stream>>>(Qhi, Khi, cand_val, cand_idx);
    // 2) merge to top-24 candidates
    topk_merge_kernel<<<NROWS / 4, 256, 0, stream>>>(cand_val, cand_idx, cand32);
    // 2b) raw values -> bf16 (into dead cand region)
    conv_bf16_kernel<<<2048, 256, 0, stream>>>(mvals, Vhi, MKEYS * DDIM / 4);
    // 3) exact fp32 rescore -> final top-16
    rescore_kernel<<<NROWS, 256, 0, stream>>>(queries, mkeys, cand32, topk);
    // 4) q projection (3-term, bf16 out into Qhi region)
    proj_split_kernel<1><<<dim3(NROWS / 128, 8), 256, 0, stream>>>(queries, IPhi, IPlo, ipb, Qpb, 1);
    // 5) u = Qpb @ wkT per head (K=128)
    ugemm_kernel<<<dim3(NROWS / 128, 8, 8), 256, 0, stream>>>(Qpb, wkT, u);
    // 6) scores/softmax/z over raw K,V (z overwrites u)
    attn2_kernel<<<NROWS, 256, 0, stream>>>(Khi, Vhi, u, topk);
    // 7) attn_out = z @ Wv^T + bv (into Khi region)
    zout_kernel<<<dim3(NROWS / 128, 8), 256, 0, stream>>>(u, IPhi, ipb, attn_out);
    // 8) output projection (3-term) -> d_out (f32)
    proj_split_kernel<1><<<dim3(NROWS / 128, 8), 256, 0, stream>>>(attn_out, OPhi, OPlo, opb, d_out, 0);
}

// Round 13
// 845.038 us; speedup vs baseline: 2.9669x; 1.0485x over previous
//
#include <hip/hip_runtime.h>
#include <hip/hip_bf16.h>

#define NROWS 4096    // B*S
#define DDIM  1024
#define MKEYS 32768
#define HDIM  128
#define KSEL  16
#define NCAND 20      // rescored candidates per row (gap v16->v20 = 16 sigma of bf16 err)
#define BTOP  6       // per-keyblock kept candidates

// ---- sims MFMA GEMM geometry: m97-style 128x128 tile, 4 waves, 32KB LDS ----
#define SBM 128
#define SBN 128
#define SNKB (MKEYS / SBN)            // 256 key blocks
#define CANDS_PER_ROW (SNKB * BTOP)   // 1536
#define CANDS_ALLOC   2048            // allocation stride (cand region = 67.1MB = Vhi alias)
#define NSTEPS 16                     // K = 1024 bf16, BK = 64

typedef short bf16x8 __attribute__((ext_vector_type(8)));
typedef float f32x4  __attribute__((ext_vector_type(4)));

__device__ __forceinline__ float bf2f(unsigned short u) {
    union { unsigned int i; float f; } x; x.i = ((unsigned int)u) << 16; return x.f;
}
__device__ __forceinline__ unsigned short f2bf(float f) {
    union { float f; unsigned int u; } v; v.f = f;
    unsigned int r = (v.u + 0x7fffu + ((v.u >> 16) & 1u)) >> 16;   // RNE
    return (unsigned short)r;
}
__device__ __forceinline__ void gload16(const void* g, const void* l) {
    __builtin_amdgcn_global_load_lds((const __attribute__((address_space(1))) unsigned int*)g,
                                     (__attribute__((address_space(3))) unsigned int*)l, 16, 0, 0);
}
template <int N>
__device__ __forceinline__ void insN(float v, int id, float* lv, int* li) {
    if (v > lv[N - 1]) {
#pragma unroll
        for (int i = 0; i < N; ++i) {
            const bool gt = v > lv[i];
            const float tv = gt ? lv[i] : v;
            const int   ti = gt ? li[i] : id;
            if (gt) { lv[i] = v; li[i] = id; }
            v = tv; id = ti;
        }
    }
}
__device__ __forceinline__ void split2(float x0, float x1, unsigned int& hp, unsigned int& lp) {
    union { float f; unsigned int u; } u0, u1;
    u0.f = x0; u1.f = x1;
    hp = (u0.u >> 16) | (u1.u & 0xffff0000u);
    const float r0 = x0 - bf2f((unsigned short)(u0.u >> 16));
    const float r1 = x1 - bf2f((unsigned short)(u1.u >> 16));
    lp = (unsigned int)f2bf(r0) | ((unsigned int)f2bf(r1) << 16);
}

// ---------------- fp32 -> bf16 (RNE) ----------------
__global__ __launch_bounds__(256)
void conv_bf16_kernel(const float* __restrict__ x, unsigned short* __restrict__ hi, const int n4)
{
    int i = blockIdx.x * 256 + threadIdx.x;
    const int stride = gridDim.x * 256;
    for (; i < n4; i += stride) {
        const float4 f = ((const float4*)x)[i];
        ushort4 h;
        h.x = f2bf(f.x); h.y = f2bf(f.y); h.z = f2bf(f.z); h.w = f2bf(f.w);
        ((ushort4*)hi)[i] = h;
    }
}

// ---------------- fp32 -> (hi, lo) bf16 split (out-proj weights only) ----------------
__global__ __launch_bounds__(256)
void split_bf16_kernel(const float* __restrict__ x, unsigned short* __restrict__ hi,
                       unsigned short* __restrict__ lo, const int n4)
{
    int i = blockIdx.x * 256 + threadIdx.x;
    const int stride = gridDim.x * 256;
    for (; i < n4; i += stride) {
        const float4 f = ((const float4*)x)[i];
        ushort4 h, l;
        h.x = f2bf(f.x); l.x = f2bf(f.x - bf2f(h.x));
        h.y = f2bf(f.y); l.y = f2bf(f.y - bf2f(h.y));
        h.z = f2bf(f.z); l.z = f2bf(f.z - bf2f(h.z));
        h.w = f2bf(f.w); l.w = f2bf(f.w - bf2f(h.w));
        ((ushort4*)hi)[i] = h;
        ((ushort4*)lo)[i] = l;
    }
}

// ---------------- wkT[h][j][c] = bf16(ipw[1024 + h*128 + c][j]) ----------------
__global__ __launch_bounds__(256)
void wk_transpose_kernel(const float* __restrict__ ipw, unsigned short* __restrict__ wkT)
{
    const int tt   = blockIdx.x * 256 + threadIdx.x;
    const int base = tt << 3;
    const int h    = base >> 17;
    const int rem  = base & 131071;
    const int j    = rem >> 7;
    const int c0   = rem & 127;
    const float* src = ipw + ((size_t)(1024 + h * 128 + c0)) * 1024 + j;
    ushort4 o0, o1;
    o0.x = f2bf(src[0]);        o0.y = f2bf(src[1024]);
    o0.z = f2bf(src[2 * 1024]); o0.w = f2bf(src[3 * 1024]);
    o1.x = f2bf(src[4 * 1024]); o1.y = f2bf(src[5 * 1024]);
    o1.z = f2bf(src[6 * 1024]); o1.w = f2bf(src[7 * 1024]);
    *(ushort4*)(wkT + base)     = o0;
    *(ushort4*)(wkT + base + 4) = o1;
}

// ---------------- Kernel A: sims(bf16) = Qhi.Khi^T, 128x128 (unchanged) ----------------
__global__ __launch_bounds__(256)
void sims_mfma_kernel(const unsigned short* __restrict__ Qhi, const unsigned short* __restrict__ Khi,
                      float* __restrict__ cand_val, int* __restrict__ cand_idx)
{
    __shared__ char smem[32768];
    const int tid  = threadIdx.x;
    const int lane = tid & 63;
    const int w    = tid >> 6;
    const int wr   = w >> 1, wc = w & 1;
    const int row0 = blockIdx.x * SBM;
    const int key0 = blockIdx.y * SBN;

    const f32x4 zero = {0.f, 0.f, 0.f, 0.f};
    f32x4 acc[4][4];
#pragma unroll
    for (int mi = 0; mi < 4; ++mi)
#pragma unroll
        for (int ni = 0; ni < 4; ++ni) acc[mi][ni] = zero;

    const int srow = lane >> 3;
    const int scol = (((lane & 7) ^ srow) << 4);

#pragma unroll 1
    for (int step = 0; step < NSTEPS; ++step) {
        const int kbyte = step << 7;
        __syncthreads();
#pragma unroll
        for (int i = 0; i < 8; ++i) {
            const int chunk = w + (i << 2);
            const char* src;
            if (chunk < 16) {
                const int r = (chunk << 3) + srow;
                src = (const char*)Qhi + (((size_t)(row0 + r)) << 11) + kbyte + scol;
            } else {
                const int r = ((chunk - 16) << 3) + srow;
                src = (const char*)Khi + (((size_t)(key0 + r)) << 11) + kbyte + scol;
            }
            gload16(src, smem + (chunk << 10));
        }
        __syncthreads();
#pragma unroll
        for (int kk = 0; kk < 2; ++kk) {
            const int cb = (kk << 6) + ((lane >> 4) << 4);
            bf16x8 af[4], bf[4];
#pragma unroll
            for (int mi = 0; mi < 4; ++mi) {
                const int r = wr * 64 + mi * 16 + (lane & 15);
                af[mi] = *(const bf16x8*)(smem + r * 128 + (cb ^ ((r & 7) << 4)));
            }
#pragma unroll
            for (int ni = 0; ni < 4; ++ni) {
                const int r = wc * 64 + ni * 16 + (lane & 15);
                bf[ni] = *(const bf16x8*)(smem + 16384 + r * 128 + (cb ^ ((r & 7) << 4)));
            }
#pragma unroll
            for (int mi = 0; mi < 4; ++mi)
#pragma unroll
                for (int ni = 0; ni < 4; ++ni)
                    acc[mi][ni] = __builtin_amdgcn_mfma_f32_16x16x32_bf16(af[mi], bf[ni], acc[mi][ni], 0, 0, 0);
        }
    }

    float lv[BTOP]; int li[BTOP];
#pragma unroll
    for (int i = 0; i < BTOP; ++i) { lv[i] = -3.4e38f; li[i] = 0; }
    float* C_lds = (float*)smem;
    const int rowt = tid & 127;
    const int half = tid >> 7;

#pragma unroll
    for (int q = 0; q < 4; ++q) {
        __syncthreads();
        if (wc == (q >> 1)) {
#pragma unroll
            for (int mi = 0; mi < 4; ++mi)
#pragma unroll
                for (int nn = 0; nn < 2; ++nn) {
                    const int ni = ((q & 1) << 1) + nn;
                    const int r  = wr * 64 + mi * 16 + ((lane >> 4) << 2);
                    const int c  = (nn << 4) + (lane & 15);
                    const f32x4 v = acc[mi][ni];
#pragma unroll
                    for (int j = 0; j < 4; ++j) C_lds[(r + j) * 33 + c] = v[j];
                }
        }
        __syncthreads();
        const int gbase = key0 + (q << 5) + (half << 4);
#pragma unroll
        for (int cc = 0; cc < 16; ++cc)
            insN<BTOP>(C_lds[rowt * 33 + (half << 4) + cc], gbase + cc, lv, li);
    }
    __syncthreads();
    float* mv = (float*)smem;
    int*   mx = (int*)(smem + 128 * 9 * 4);
    if (half == 1) {
#pragma unroll
        for (int i = 0; i < BTOP; ++i) { mv[rowt * 9 + i] = lv[i]; mx[rowt * 9 + i] = li[i]; }
    }
    __syncthreads();
    if (half == 0) {
#pragma unroll
        for (int i = 0; i < BTOP; ++i)
            insN<BTOP>(mv[rowt * 9 + i], mx[rowt * 9 + i], lv, li);
        const size_t o = (((size_t)(row0 + rowt)) * SNKB + blockIdx.y) * BTOP;
#pragma unroll
        for (int i = 0; i < BTOP; ++i) { cand_val[o + i] = lv[i]; cand_idx[o + i] = li[i]; }
    }
}

// ---------------- Kernel B: merge -> top-20 per row (per-lane 20-deep over 24 vals: lossless) ----------------
__global__ __launch_bounds__(256)
void topk_merge_kernel(const float* __restrict__ cand_val, const int* __restrict__ cand_idx,
                       int* __restrict__ cand32)
{
    const int row  = blockIdx.x * 4 + (threadIdx.x >> 6);
    const int lane = threadIdx.x & 63;
    const size_t base = (size_t)row * CANDS_PER_ROW;
    float lv[NCAND]; int li[NCAND];
#pragma unroll
    for (int i = 0; i < NCAND; ++i) { lv[i] = -3.4e38f; li[i] = 0x7fffffff; }
#pragma unroll 1
    for (int m = 0; m < CANDS_PER_ROW / 64; ++m) {
        const int p = lane + (m << 6);
        insN<NCAND>(cand_val[base + p], cand_idx[base + p], lv, li);
    }
    int out = 0;
#pragma unroll 1
    for (int it = 0; it < NCAND; ++it) {
        float rv = lv[0]; int ridx = li[0];
#pragma unroll
        for (int off = 1; off < 64; off <<= 1) {
            const float ov = __shfl_xor(rv, off);
            const int   oi = __shfl_xor(ridx, off);
            if (ov > rv || (ov == rv && oi < ridx)) { rv = ov; ridx = oi; }
        }
        if (lane == it) out = ridx;
        if (li[0] == ridx) {
#pragma unroll
            for (int i = 0; i < NCAND - 1; ++i) { lv[i] = lv[i + 1]; li[i] = li[i + 1]; }
            lv[NCAND - 1] = -3.4e38f; li[NCAND - 1] = 0x7fffffff;
        }
    }
    if (lane < NCAND) cand32[(size_t)row * NCAND + lane] = out;
}

// ---------------- Kernel B2: exact fp32 rescore of 20 candidates -> final top-16 ----------------
__global__ __launch_bounds__(256)
void rescore_kernel(const float* __restrict__ Q, const float* __restrict__ K,
                    const int* __restrict__ cand32, int* __restrict__ topk)
{
    const int row  = blockIdx.x;
    const int wv   = threadIdx.x >> 6;
    const int lane = threadIdx.x & 63;
    __shared__ float sv[NCAND];
    __shared__ int   si[NCAND];
    if (threadIdx.x < NCAND) si[threadIdx.x] = cand32[(size_t)row * NCAND + threadIdx.x];
    float4 qv[4];
#pragma unroll
    for (int u = 0; u < 4; ++u)
        qv[u] = ((const float4*)(Q + (size_t)row * DDIM))[(u << 6) + lane];
    __syncthreads();
#pragma unroll 1
    for (int c = 0; c < NCAND / 4; ++c) {              // 5 cands per wave
        const int slot = wv * (NCAND / 4) + c;
        const float* kr = K + (size_t)si[slot] * DDIM;
        float s = 0.f;
#pragma unroll
        for (int u = 0; u < 4; ++u) {
            const float4 kv = ((const float4*)kr)[(u << 6) + lane];
            s += kv.x * qv[u].x + kv.y * qv[u].y + kv.z * qv[u].z + kv.w * qv[u].w;
        }
#pragma unroll
        for (int off = 32; off >= 1; off >>= 1) s += __shfl_xor(s, off);
        if (lane == 0) sv[slot] = s;
    }
    __syncthreads();
    if (wv == 0) {
        float v = (lane < NCAND) ? sv[lane] : -3.4e38f;
        int  id = (lane < NCAND) ? si[lane] : 0x7fffffff;
        int out = 0;
#pragma unroll 1
        for (int it = 0; it < KSEL; ++it) {
            float rv = v; int ridx = id;
#pragma unroll
            for (int off = 1; off < 64; off <<= 1) {
                const float ov = __shfl_xor(rv, off);
                const int   oi = __shfl_xor(ridx, off);
                if (ov > rv || (ov == rv && oi < ridx)) { rv = ov; ridx = oi; }
            }
            if (lane == it) out = ridx;
            if (id == ridx) v = -3.4e38f;
        }
        if (lane < KSEL) topk[(size_t)row * KSEL + lane] = out;
    }
}

// ---------------- Kernel C: X(fp32) x W projections (LO=1 3-term / LO=0 1-term) ----------------
template <int LO>
__global__ __launch_bounds__(256)
void proj_split_kernel(const float* __restrict__ X, const unsigned short* __restrict__ Whi,
                       const unsigned short* __restrict__ Wlo, const float* __restrict__ bias,
                       void* __restrict__ outp, const int store_bf16)
{
    constexpr int WOFF = LO ? 32768 : 16384;
    __shared__ char smem[LO ? 65536 : 32768];
    const int tid  = threadIdx.x;
    const int lane = tid & 63;
    const int w    = tid >> 6;
    const int wr   = w >> 1, wc = w & 1;
    const int row0 = blockIdx.x * 128;
    const int col0 = blockIdx.y * 128;

    const f32x4 zero = {0.f, 0.f, 0.f, 0.f};
    f32x4 acc[4][4];
#pragma unroll
    for (int mi = 0; mi < 4; ++mi)
#pragma unroll
        for (int ni = 0; ni < 4; ++ni) acc[mi][ni] = zero;

    const int srow = lane >> 3;
    const int scol = (((lane & 7) ^ srow) << 4);
    const int xr = tid >> 1, xh = tid & 1;

    for (int step = 0; step < 16; ++step) {
        const int kbyte = step << 7;
        const int k0    = step << 6;
        __syncthreads();
#pragma unroll
        for (int i = 0; i < (LO ? 8 : 4); ++i) {
            const int chunk = w + (i << 2);
            const int plane = chunk >> 4;
            const int r     = ((chunk & 15) << 3) + srow;
            const unsigned short* Wb = plane ? Wlo : Whi;
            const char* src = (const char*)Wb + (((size_t)(col0 + r)) << 11) + kbyte + scol;
            gload16(src, smem + WOFF + (chunk << 10));
        }
        {
            const float* Xp = X + (size_t)(row0 + xr) * DDIM + k0 + xh * 32;
            float4 xa[8];
#pragma unroll
            for (int i = 0; i < 8; ++i) xa[i] = ((const float4*)Xp)[i];
            const int xbase = xr * 128;
#pragma unroll
            for (int s4 = 0; s4 < 4; ++s4) {
                const float4 a = xa[2 * s4], b = xa[2 * s4 + 1];
                uint4 hw, lw;
                if (LO) {
                    split2(a.x, a.y, hw.x, lw.x);
                    split2(a.z, a.w, hw.y, lw.y);
                    split2(b.x, b.y, hw.z, lw.z);
                    split2(b.z, b.w, hw.w, lw.w);
                } else {
                    hw.x = (unsigned int)f2bf(a.x) | ((unsigned int)f2bf(a.y) << 16);
                    hw.y = (unsigned int)f2bf(a.z) | ((unsigned int)f2bf(a.w) << 16);
                    hw.z = (unsigned int)f2bf(b.x) | ((unsigned int)f2bf(b.y) << 16);
                    hw.w = (unsigned int)f2bf(b.z) | ((unsigned int)f2bf(b.w) << 16);
                }
                const int off = xbase + ((((xh << 2) + s4) ^ (xr & 7)) << 4);
                *(uint4*)(smem + off) = hw;
                if (LO) *(uint4*)(smem + 16384 + off) = lw;
            }
        }
        asm volatile("s_waitcnt vmcnt(0)" ::: "memory");
        __syncthreads();
#pragma unroll
        for (int kk = 0; kk < 2; ++kk) {
            const int cb = (kk << 6) + ((lane >> 4) << 4);
            bf16x8 ah[4], bh[4];
#pragma unroll
            for (int mi = 0; mi < 4; ++mi) {
                const int r = wr * 64 + mi * 16 + (lane & 15);
                ah[mi] = *(const bf16x8*)(smem + r * 128 + (cb ^ ((r & 7) << 4)));
            }
#pragma unroll
            for (int ni = 0; ni < 4; ++ni) {
                const int r = wc * 64 + ni * 16 + (lane & 15);
                bh[ni] = *(const bf16x8*)(smem + WOFF + r * 128 + (cb ^ ((r & 7) << 4)));
            }
#pragma unroll
            for (int mi = 0; mi < 4; ++mi)
#pragma unroll
                for (int ni = 0; ni < 4; ++ni)
                    acc[mi][ni] = __builtin_amdgcn_mfma_f32_16x16x32_bf16(ah[mi], bh[ni], acc[mi][ni], 0, 0, 0);
            if (LO) {
                bf16x8 al[4];
#pragma unroll
                for (int mi = 0; mi < 4; ++mi) {
                    const int r = wr * 64 + mi * 16 + (lane & 15);
                    al[mi] = *(const bf16x8*)(smem + 16384 + r * 128 + (cb ^ ((r & 7) << 4)));
                }
#pragma unroll
                for (int mi = 0; mi < 4; ++mi)
#pragma unroll
                    for (int ni = 0; ni < 4; ++ni)
                        acc[mi][ni] = __builtin_amdgcn_mfma_f32_16x16x32_bf16(al[mi], bh[ni], acc[mi][ni], 0, 0, 0);
                bf16x8 bl[4];
#pragma unroll
                for (int ni = 0; ni < 4; ++ni) {
                    const int r = wc * 64 + ni * 16 + (lane & 15);
                    bl[ni] = *(const bf16x8*)(smem + WOFF + 16384 + r * 128 + (cb ^ ((r & 7) << 4)));
                }
#pragma unroll
                for (int mi = 0; mi < 4; ++mi)
#pragma unroll
                    for (int ni = 0; ni < 4; ++ni)
                        acc[mi][ni] = __builtin_amdgcn_mfma_f32_16x16x32_bf16(ah[mi], bl[ni], acc[mi][ni], 0, 0, 0);
            }
        }
    }

#pragma unroll
    for (int ni = 0; ni < 4; ++ni) {
        const int col = col0 + wc * 64 + ni * 16 + (lane & 15);
        const float bz = bias[col];
#pragma unroll
        for (int mi = 0; mi < 4; ++mi) {
            const int rbase = row0 + wr * 64 + mi * 16 + ((lane >> 4) << 2);
            const f32x4 v = acc[mi][ni];
#pragma unroll
            for (int j = 0; j < 4; ++j) {
                const float val = v[j] + bz;
                if (store_bf16)
                    ((unsigned short*)outp)[(size_t)(rbase + j) * DDIM + col] = f2bf(val);
                else
                    ((float*)outp)[(size_t)(rbase + j) * DDIM + col] = val;
            }
        }
    }
}

// ---------------- Kernel U: u[t, h*1024+j] = sum_c Qpb[t, h*128+c] * wkT[h][j][c]  (K=128) ----------------
__global__ __launch_bounds__(256)
void ugemm_kernel(const unsigned short* __restrict__ Qpb, const unsigned short* __restrict__ wkT,
                  unsigned short* __restrict__ u)
{
    __shared__ char smem[32768];
    const int tid  = threadIdx.x;
    const int lane = tid & 63;
    const int w    = tid >> 6;
    const int wr   = w >> 1, wc = w & 1;
    const int row0 = blockIdx.x * 128;
    const int j0   = blockIdx.y * 128;
    const int h    = blockIdx.z;

    const f32x4 zero = {0.f, 0.f, 0.f, 0.f};
    f32x4 acc[4][4];
#pragma unroll
    for (int mi = 0; mi < 4; ++mi)
#pragma unroll
        for (int ni = 0; ni < 4; ++ni) acc[mi][ni] = zero;

    const int srow = lane >> 3;
    const int scol = (((lane & 7) ^ srow) << 4);

#pragma unroll 1
    for (int step = 0; step < 2; ++step) {
        const int kbyte = step << 7;
        __syncthreads();
#pragma unroll
        for (int i = 0; i < 8; ++i) {
            const int chunk = w + (i << 2);
            const char* src;
            if (chunk < 16) {
                const int r = (chunk << 3) + srow;
                src = (const char*)Qpb + (((size_t)(row0 + r)) << 11) + h * 256 + kbyte + scol;
            } else {
                const int r = ((chunk - 16) << 3) + srow;
                src = (const char*)wkT + ((size_t)h << 18) + (((size_t)(j0 + r)) << 8) + kbyte + scol;
            }
            gload16(src, smem + (chunk << 10));
        }
        __syncthreads();
#pragma unroll
        for (int kk = 0; kk < 2; ++kk) {
            const int cb = (kk << 6) + ((lane >> 4) << 4);
            bf16x8 af[4], bf[4];
#pragma unroll
            for (int mi = 0; mi < 4; ++mi) {
                const int r = wr * 64 + mi * 16 + (lane & 15);
                af[mi] = *(const bf16x8*)(smem + r * 128 + (cb ^ ((r & 7) << 4)));
            }
#pragma unroll
            for (int ni = 0; ni < 4; ++ni) {
                const int r = wc * 64 + ni * 16 + (lane & 15);
                bf[ni] = *(const bf16x8*)(smem + 16384 + r * 128 + (cb ^ ((r & 7) << 4)));
            }
#pragma unroll
            for (int mi = 0; mi < 4; ++mi)
#pragma unroll
                for (int ni = 0; ni < 4; ++ni)
                    acc[mi][ni] = __builtin_amdgcn_mfma_f32_16x16x32_bf16(af[mi], bf[ni], acc[mi][ni], 0, 0, 0);
        }
    }

#pragma unroll
    for (int ni = 0; ni < 4; ++ni) {
        const int col = j0 + wc * 64 + ni * 16 + (lane & 15);
#pragma unroll
        for (int mi = 0; mi < 4; ++mi) {
            const int rbase = row0 + wr * 64 + mi * 16 + ((lane >> 4) << 2);
            const f32x4 v = acc[mi][ni];
#pragma unroll
            for (int j = 0; j < 4; ++j)
                u[(size_t)(rbase + j) * 8192 + h * 1024 + col] = f2bf(v[j]);
        }
    }
}

// ---------------- Kernel D2: scores from u . raw-K, softmax, z = attn @ raw-V ----------------
// LDS phase-reuse: K (swizzled) in 32KB -> scores -> barrier (reads retired) -> V (linear)
// into SAME 32KB -> z. 33.3KB total -> 4 blocks/CU (was 2 at 66KB).
__global__ __launch_bounds__(256)
void attn2_kernel(const unsigned short* __restrict__ Khi, const unsigned short* __restrict__ Vhi,
                  unsigned short* __restrict__ uz, const int* __restrict__ topk)
{
    __shared__ char smem[33344];                 // KV 32KB @0, idx@32768 (64B), sc@32832 (512B)
    int*   idx_s = (int*)(smem + 32768);
    float* sc_s  = (float*)(smem + 32832);       // [8][16]
    const int t   = blockIdx.x;
    const int tid = threadIdx.x;
    if (tid < KSEL) idx_s[tid] = topk[(size_t)t * KSEL + tid];
    __syncthreads();
    // phase 1: stage K (source-swizzled)
#pragma unroll
    for (int i = 0; i < 8; ++i) {
        const int s   = tid + (i << 8);
        const int row = s >> 7, col = s & 127;
        const size_t kb = ((size_t)idx_s[row]) << 11;
        gload16((const char*)Khi + kb + ((col ^ (row & 7)) << 4), smem + (s << 4));
    }
    __syncthreads();                             // K landed
    // scores: pair (h,k) handled by 2 threads (sub halves of 1024 dims)
    {
        const int p = tid >> 1, sub = tid & 1;
        const int h = p >> 4, k = p & 15;
        const unsigned short* urow = uz + (size_t)t * 8192 + h * 1024 + sub * 512;
        float s = 0.f;
#pragma unroll 8
        for (int j = 0; j < 64; ++j) {
            const uint4 uw = *(const uint4*)(urow + (j << 3));
            const uint4 kw = *(const uint4*)(smem + (k << 11) + ((((sub << 6) + j) ^ (k & 7)) << 4));
            s += bf2f((unsigned short)(uw.x & 0xffffu)) * bf2f((unsigned short)(kw.x & 0xffffu))
               + bf2f((unsigned short)(uw.x >> 16))     * bf2f((unsigned short)(kw.x >> 16))
               + bf2f((unsigned short)(uw.y & 0xffffu)) * bf2f((unsigned short)(kw.y & 0xffffu))
               + bf2f((unsigned short)(uw.y >> 16))     * bf2f((unsigned short)(kw.y >> 16))
               + bf2f((unsigned short)(uw.z & 0xffffu)) * bf2f((unsigned short)(kw.z & 0xffffu))
               + bf2f((unsigned short)(uw.z >> 16))     * bf2f((unsigned short)(kw.z >> 16))
               + bf2f((unsigned short)(uw.w & 0xffffu)) * bf2f((unsigned short)(kw.w & 0xffffu))
               + bf2f((unsigned short)(uw.w >> 16))     * bf2f((unsigned short)(kw.w >> 16));
        }
        s += __shfl_xor(s, 1);
        if (sub == 0) sc_s[h * 16 + k] = s;
    }
    __syncthreads();                             // K reads + u reads retired; sc ready
    // phase 2: stage V (linear) into the SAME 32KB
#pragma unroll
    for (int i = 0; i < 8; ++i) {
        const int s   = tid + (i << 8);
        const int row = s >> 7, col = s & 127;
        const size_t kb = ((size_t)idx_s[row]) << 11;
        gload16((const char*)Vhi + kb + (col << 4), smem + (s << 4));
    }
    __syncthreads();                             // V landed
    // softmax (redundant per 32-thread head group) + z (overwrites uz)
    const int h  = tid >> 5;
    const int dp = tid & 31;
    const float scale = 0.08838834764831845f;    // 1/sqrt(128)
    float mxv = -3.4e38f;
#pragma unroll
    for (int n = 0; n < KSEL; ++n) mxv = fmaxf(mxv, sc_s[h * 16 + n]);
    float wgt[KSEL]; float wsum = 0.f;
#pragma unroll
    for (int n = 0; n < KSEL; ++n) { wgt[n] = __expf((sc_s[h * 16 + n] - mxv) * scale); wsum += wgt[n]; }
    const float inv = 1.f / wsum;
#pragma unroll
    for (int n = 0; n < KSEL; ++n) wgt[n] *= inv;
#pragma unroll 1
    for (int j = 0; j < 16; ++j) {
        float z0 = 0.f, z1 = 0.f;
#pragma unroll
        for (int k = 0; k < 16; ++k) {
            const unsigned int vv = *(const unsigned int*)(smem + (k << 11) + (j << 7) + (dp << 2));
            z0 += wgt[k] * bf2f((unsigned short)(vv & 0xffffu));
            z1 += wgt[k] * bf2f((unsigned short)(vv >> 16));
        }
        *(unsigned int*)((char*)uz + (size_t)t * 16384 + (h << 11) + (j << 7) + (dp << 2)) =
            (unsigned int)f2bf(z0) | ((unsigned int)f2bf(z1) << 16);
    }
}

// ---------------- Kernel Z: attn_out[t, h*128+c] = sum_d z[t,h,d]*Wv_h[c,d] + bv ----------------
__global__ __launch_bounds__(256)
void zout_kernel(const unsigned short* __restrict__ z, const unsigned short* __restrict__ IPhi,
                 const float* __restrict__ ipb, float* __restrict__ attn_out)
{
    __shared__ char smem[32768];
    const int tid  = threadIdx.x;
    const int lane = tid & 63;
    const int w    = tid >> 6;
    const int wr   = w >> 1, wc = w & 1;
    const int row0 = blockIdx.x * 128;
    const int h    = blockIdx.y;

    const f32x4 zero = {0.f, 0.f, 0.f, 0.f};
    f32x4 acc[4][4];
#pragma unroll
    for (int mi = 0; mi < 4; ++mi)
#pragma unroll
        for (int ni = 0; ni < 4; ++ni) acc[mi][ni] = zero;

    const int srow = lane >> 3;
    const int scol = (((lane & 7) ^ srow) << 4);

#pragma unroll 1
    for (int step = 0; step < 16; ++step) {
        const int kbyte = step << 7;
        __syncthreads();
#pragma unroll
        for (int i = 0; i < 8; ++i) {
            const int chunk = w + (i << 2);
            const char* src;
            if (chunk < 16) {
                const int r = (chunk << 3) + srow;
                src = (const char*)z + (((size_t)(row0 + r)) << 14) + (h << 11) + kbyte + scol;
            } else {
                const int r = ((chunk - 16) << 3) + srow;
                src = (const char*)IPhi + (((size_t)(2048 + h * 128 + r)) << 11) + kbyte + scol;
            }
            gload16(src, smem + (chunk << 10));
        }
        __syncthreads();
#pragma unroll
        for (int kk = 0; kk < 2; ++kk) {
            const int cb = (kk << 6) + ((lane >> 4) << 4);
            bf16x8 af[4], bf[4];
#pragma unroll
            for (int mi = 0; mi < 4; ++mi) {
                const int r = wr * 64 + mi * 16 + (lane & 15);
                af[mi] = *(const bf16x8*)(smem + r * 128 + (cb ^ ((r & 7) << 4)));
            }
#pragma unroll
            for (int ni = 0; ni < 4; ++ni) {
                const int r = wc * 64 + ni * 16 + (lane & 15);
                bf[ni] = *(const bf16x8*)(smem + 16384 + r * 128 + (cb ^ ((r & 7) << 4)));
            }
#pragma unroll
            for (int mi = 0; mi < 4; ++mi)
#pragma unroll
                for (int ni = 0; ni < 4; ++ni)
                    acc[mi][ni] = __builtin_amdgcn_mfma_f32_16x16x32_bf16(af[mi], bf[ni], acc[mi][ni], 0, 0, 0);
        }
    }

#pragma unroll
    for (int ni = 0; ni < 4; ++ni) {
        const int cl = wc * 64 + ni * 16 + (lane & 15);
        const float bz = ipb[2048 + h * 128 + cl];
#pragma unroll
        for (int mi = 0; mi < 4; ++mi) {
            const int rbase = row0 + wr * 64 + mi * 16 + ((lane >> 4) << 2);
            const f32x4 v = acc[mi][ni];
#pragma unroll
            for (int j = 0; j < 4; ++j)
                attn_out[(size_t)(rbase + j) * 1024 + h * 128 + cl] = v[j] + bz;
        }
    }
}

extern "C" void kernel_launch(void* const* d_in, const int* in_sizes, int n_in,
                              void* d_out, int out_size, void* d_ws, size_t ws_size,
                              hipStream_t stream)
{
    const float* queries = (const float*)d_in[0];
    const float* mkeys   = (const float*)d_in[1];
    const float* mvals   = (const float*)d_in[2];
    const float* ipw     = (const float*)d_in[3];
    const float* ipb     = (const float*)d_in[4];
    const float* opw     = (const float*)d_in[5];
    const float* opb     = (const float*)d_in[6];

    char* ws = (char*)d_ws;
    size_t off = 0;
    auto alloc = [&](size_t bytes) -> char* {
        char* p = ws + off;
        off += (bytes + 255) & ~(size_t)255;
        return p;
    };
    unsigned short* Khi  = (unsigned short*)alloc((size_t)MKEYS * DDIM * 2);    // 67.1 MB
    unsigned short* Qhi  = (unsigned short*)alloc((size_t)NROWS * DDIM * 2);    // 8.4 MB
    unsigned short* IPhi = (unsigned short*)alloc((size_t)3 * DDIM * DDIM * 2); // 6.3 MB
    unsigned short* OPhi = (unsigned short*)alloc((size_t)DDIM * DDIM * 2);     // 2.1 MB
    unsigned short* OPlo = (unsigned short*)alloc((size_t)DDIM * DDIM * 2);     // 2.1 MB
    unsigned short* wkT  = (unsigned short*)alloc((size_t)DDIM * DDIM * 2);     // 2.1 MB
    float* cand_val = (float*)alloc((size_t)NROWS * CANDS_ALLOC * 4);           // 33.55 MB
    int*   cand_idx = (int*)  alloc((size_t)NROWS * CANDS_ALLOC * 4);           // 33.55 MB (contiguous)
    int*   cand32   = (int*)  alloc((size_t)NROWS * NCAND * 4);                 // 0.33 MB
    int*   topk     = (int*)  alloc((size_t)NROWS * KSEL * 4);                  // 0.26 MB
    unsigned short* u = (unsigned short*)alloc((size_t)NROWS * 8 * DDIM * 2);   // 67.1 MB (z in-place)
    // aliases (total ~222 MB <= 235 proven):
    unsigned short* Qpb = (unsigned short*)Qhi;       // Qhi dead after sims
    unsigned short* Vhi = (unsigned short*)cand_val;  // cand region (67.1MB) dead after merge
    float* attn_out     = (float*)Khi;                // Khi dead after attn2; zout runs after

    // 0) converts + weight preps
    conv_bf16_kernel<<<2048, 256, 0, stream>>>(queries, Qhi, NROWS * DDIM / 4);
    conv_bf16_kernel<<<2048, 256, 0, stream>>>(mkeys, Khi, MKEYS * DDIM / 4);
    conv_bf16_kernel<<<1024, 256, 0, stream>>>(ipw, IPhi, 3 * DDIM * DDIM / 4);
    split_bf16_kernel<<<512,  256, 0, stream>>>(opw, OPhi, OPlo, DDIM * DDIM / 4);
    wk_transpose_kernel<<<512, 256, 0, stream>>>(ipw, wkT);
    // 1) bf16 similarity GEMM + per-keyblock top-6
    sims_mfma_kernel<<<dim3(NROWS / SBM, MKEYS / SBN), 256, 0, stream>>>(Qhi, Khi, cand_val, cand_idx);
    // 2) merge to top-20 candidates
    topk_merge_kernel<<<NROWS / 4, 256, 0, stream>>>(cand_val, cand_idx, cand32);
    // 2b) raw values -> bf16 (into dead cand region)
    conv_bf16_kernel<<<2048, 256, 0, stream>>>(mvals, Vhi, MKEYS * DDIM / 4);
    // 3) exact fp32 rescore -> final top-16
    rescore_kernel<<<NROWS, 256, 0, stream>>>(queries, mkeys, cand32, topk);
    // 4) q projection (1-term: bf16 storage rounding dominates anyway)
    proj_split_kernel<0><<<dim3(NROWS / 128, 8), 256, 0, stream>>>(queries, IPhi, IPhi, ipb, Qpb, 1);
    // 5) u = Qpb @ wkT per head (K=128)
    ugemm_kernel<<<dim3(NROWS / 128, 8, 8), 256, 0, stream>>>(Qpb, wkT, u);
    // 6) scores/softmax/z over raw K,V (z overwrites u; 33KB LDS phase-reuse)
    attn2_kernel<<<NROWS, 256, 0, stream>>>(Khi, Vhi, u, topk);
    // 7) attn_out = z @ Wv^T + bv (into Khi region)
    zout_kernel<<<dim3(NROWS / 128, 8), 256, 0, stream>>>(u, IPhi, ipb, attn_out);
    // 8) output projection (3-term) -> d_out (f32)
    proj_split_kernel<1><<<dim3(NROWS / 128, 8), 256, 0, stream>>>(attn_out, OPhi, OPlo, opb, d_out, 0);
}

// Round 14
// 805.769 us; speedup vs baseline: 3.1115x; 1.0487x over previous
//
#include <hip/hip_runtime.h>
#include <hip/hip_bf16.h>

#define NROWS 4096    // B*S
#define DDIM  1024
#define MKEYS 32768
#define HDIM  128
#define KSEL  16
#define NCAND 20      // rescored candidates per row
#define BTOP  6       // per-keyblock kept candidates
#define LCAP  8       // merge per-lane list depth (lossless whp for top-20 at stride-64)

// ---- sims MFMA GEMM geometry: m97-style 128x128 tile, 4 waves, 32KB LDS ----
#define SBM 128
#define SBN 128
#define SNKB (MKEYS / SBN)            // 256 key blocks
#define CANDS_PER_ROW (SNKB * BTOP)   // 1536
#define CANDS_ALLOC   2048            // allocation stride
#define NSTEPS 16                     // K = 1024 bf16, BK = 64

typedef short bf16x8 __attribute__((ext_vector_type(8)));
typedef float f32x4  __attribute__((ext_vector_type(4)));

__device__ __forceinline__ float bf2f(unsigned short u) {
    union { unsigned int i; float f; } x; x.i = ((unsigned int)u) << 16; return x.f;
}
__device__ __forceinline__ unsigned short f2bf(float f) {
    union { float f; unsigned int u; } v; v.f = f;
    unsigned int r = (v.u + 0x7fffu + ((v.u >> 16) & 1u)) >> 16;   // RNE
    return (unsigned short)r;
}
__device__ __forceinline__ void gload16(const void* g, const void* l) {
    __builtin_amdgcn_global_load_lds((const __attribute__((address_space(1))) unsigned int*)g,
                                     (__attribute__((address_space(3))) unsigned int*)l, 16, 0, 0);
}
template <int N>
__device__ __forceinline__ void insN(float v, int id, float* lv, int* li) {
    if (v > lv[N - 1]) {
#pragma unroll
        for (int i = 0; i < N; ++i) {
            const bool gt = v > lv[i];
            const float tv = gt ? lv[i] : v;
            const int   ti = gt ? li[i] : id;
            if (gt) { lv[i] = v; li[i] = id; }
            v = tv; id = ti;
        }
    }
}
__device__ __forceinline__ void split2(float x0, float x1, unsigned int& hp, unsigned int& lp) {
    union { float f; unsigned int u; } u0, u1;
    u0.f = x0; u1.f = x1;
    hp = (u0.u >> 16) | (u1.u & 0xffff0000u);
    const float r0 = x0 - bf2f((unsigned short)(u0.u >> 16));
    const float r1 = x1 - bf2f((unsigned short)(u1.u >> 16));
    lp = (unsigned int)f2bf(r0) | ((unsigned int)f2bf(r1) << 16);
}

// ---------------- fp32 -> bf16 (RNE) ----------------
__global__ __launch_bounds__(256)
void conv_bf16_kernel(const float* __restrict__ x, unsigned short* __restrict__ hi, const int n4)
{
    int i = blockIdx.x * 256 + threadIdx.x;
    const int stride = gridDim.x * 256;
    for (; i < n4; i += stride) {
        const float4 f = ((const float4*)x)[i];
        ushort4 h;
        h.x = f2bf(f.x); h.y = f2bf(f.y); h.z = f2bf(f.z); h.w = f2bf(f.w);
        ((ushort4*)hi)[i] = h;
    }
}

// ---------------- fp32 -> (hi, lo) bf16 split (out-proj weights only) ----------------
__global__ __launch_bounds__(256)
void split_bf16_kernel(const float* __restrict__ x, unsigned short* __restrict__ hi,
                       unsigned short* __restrict__ lo, const int n4)
{
    int i = blockIdx.x * 256 + threadIdx.x;
    const int stride = gridDim.x * 256;
    for (; i < n4; i += stride) {
        const float4 f = ((const float4*)x)[i];
        ushort4 h, l;
        h.x = f2bf(f.x); l.x = f2bf(f.x - bf2f(h.x));
        h.y = f2bf(f.y); l.y = f2bf(f.y - bf2f(h.y));
        h.z = f2bf(f.z); l.z = f2bf(f.z - bf2f(h.z));
        h.w = f2bf(f.w); l.w = f2bf(f.w - bf2f(h.w));
        ((ushort4*)hi)[i] = h;
        ((ushort4*)lo)[i] = l;
    }
}

// ---------------- wkT[h][j][c] = bf16(ipw[1024 + h*128 + c][j]) — coalesced LDS transpose ----------------
// grid 64: h = bx>>3, j0 = bx&7. Read 128c x 128j f32 coalesced, transpose via padded LDS,
// write 256B rows as uint4.
__global__ __launch_bounds__(256)
void wk_transpose_kernel(const float* __restrict__ ipw, unsigned short* __restrict__ wkT)
{
    __shared__ unsigned short T[128 * 129];
    const int bx  = blockIdx.x;
    const int h   = bx >> 3, j0 = bx & 7;
    const int tid = threadIdx.x;
#pragma unroll 8
    for (int i = 0; i < 64; ++i) {
        const int idx = (i << 8) + tid;
        const int c = idx >> 7, j = idx & 127;
        T[c * 129 + j] = f2bf(ipw[((size_t)(1024 + h * 128 + c)) * 1024 + j0 * 128 + j]);
    }
    __syncthreads();
#pragma unroll
    for (int i = 0; i < 8; ++i) {
        const int g  = (i << 8) + tid;
        const int j  = g >> 4, c0 = (g & 15) << 3;
        uint4 o;
        o.x = (unsigned)T[(c0 + 0) * 129 + j] | ((unsigned)T[(c0 + 1) * 129 + j] << 16);
        o.y = (unsigned)T[(c0 + 2) * 129 + j] | ((unsigned)T[(c0 + 3) * 129 + j] << 16);
        o.z = (unsigned)T[(c0 + 4) * 129 + j] | ((unsigned)T[(c0 + 5) * 129 + j] << 16);
        o.w = (unsigned)T[(c0 + 6) * 129 + j] | ((unsigned)T[(c0 + 7) * 129 + j] << 16);
        *(uint4*)(wkT + ((size_t)h << 17) + ((size_t)(j0 * 128 + j) << 7) + c0) = o;
    }
}

// ---------------- Kernel A: sims(bf16) = Qhi.Khi^T, 128x128 (unchanged) ----------------
__global__ __launch_bounds__(256)
void sims_mfma_kernel(const unsigned short* __restrict__ Qhi, const unsigned short* __restrict__ Khi,
                      float* __restrict__ cand_val, int* __restrict__ cand_idx)
{
    __shared__ char smem[32768];
    const int tid  = threadIdx.x;
    const int lane = tid & 63;
    const int w    = tid >> 6;
    const int wr   = w >> 1, wc = w & 1;
    const int row0 = blockIdx.x * SBM;
    const int key0 = blockIdx.y * SBN;

    const f32x4 zero = {0.f, 0.f, 0.f, 0.f};
    f32x4 acc[4][4];
#pragma unroll
    for (int mi = 0; mi < 4; ++mi)
#pragma unroll
        for (int ni = 0; ni < 4; ++ni) acc[mi][ni] = zero;

    const int srow = lane >> 3;
    const int scol = (((lane & 7) ^ srow) << 4);

#pragma unroll 1
    for (int step = 0; step < NSTEPS; ++step) {
        const int kbyte = step << 7;
        __syncthreads();
#pragma unroll
        for (int i = 0; i < 8; ++i) {
            const int chunk = w + (i << 2);
            const char* src;
            if (chunk < 16) {
                const int r = (chunk << 3) + srow;
                src = (const char*)Qhi + (((size_t)(row0 + r)) << 11) + kbyte + scol;
            } else {
                const int r = ((chunk - 16) << 3) + srow;
                src = (const char*)Khi + (((size_t)(key0 + r)) << 11) + kbyte + scol;
            }
            gload16(src, smem + (chunk << 10));
        }
        __syncthreads();
#pragma unroll
        for (int kk = 0; kk < 2; ++kk) {
            const int cb = (kk << 6) + ((lane >> 4) << 4);
            bf16x8 af[4], bf[4];
#pragma unroll
            for (int mi = 0; mi < 4; ++mi) {
                const int r = wr * 64 + mi * 16 + (lane & 15);
                af[mi] = *(const bf16x8*)(smem + r * 128 + (cb ^ ((r & 7) << 4)));
            }
#pragma unroll
            for (int ni = 0; ni < 4; ++ni) {
                const int r = wc * 64 + ni * 16 + (lane & 15);
                bf[ni] = *(const bf16x8*)(smem + 16384 + r * 128 + (cb ^ ((r & 7) << 4)));
            }
#pragma unroll
            for (int mi = 0; mi < 4; ++mi)
#pragma unroll
                for (int ni = 0; ni < 4; ++ni)
                    acc[mi][ni] = __builtin_amdgcn_mfma_f32_16x16x32_bf16(af[mi], bf[ni], acc[mi][ni], 0, 0, 0);
        }
    }

    float lv[BTOP]; int li[BTOP];
#pragma unroll
    for (int i = 0; i < BTOP; ++i) { lv[i] = -3.4e38f; li[i] = 0; }
    float* C_lds = (float*)smem;
    const int rowt = tid & 127;
    const int half = tid >> 7;

#pragma unroll
    for (int q = 0; q < 4; ++q) {
        __syncthreads();
        if (wc == (q >> 1)) {
#pragma unroll
            for (int mi = 0; mi < 4; ++mi)
#pragma unroll
                for (int nn = 0; nn < 2; ++nn) {
                    const int ni = ((q & 1) << 1) + nn;
                    const int r  = wr * 64 + mi * 16 + ((lane >> 4) << 2);
                    const int c  = (nn << 4) + (lane & 15);
                    const f32x4 v = acc[mi][ni];
#pragma unroll
                    for (int j = 0; j < 4; ++j) C_lds[(r + j) * 33 + c] = v[j];
                }
        }
        __syncthreads();
        const int gbase = key0 + (q << 5) + (half << 4);
#pragma unroll
        for (int cc = 0; cc < 16; ++cc)
            insN<BTOP>(C_lds[rowt * 33 + (half << 4) + cc], gbase + cc, lv, li);
    }
    __syncthreads();
    float* mv = (float*)smem;
    int*   mx = (int*)(smem + 128 * 9 * 4);
    if (half == 1) {
#pragma unroll
        for (int i = 0; i < BTOP; ++i) { mv[rowt * 9 + i] = lv[i]; mx[rowt * 9 + i] = li[i]; }
    }
    __syncthreads();
    if (half == 0) {
#pragma unroll
        for (int i = 0; i < BTOP; ++i)
            insN<BTOP>(mv[rowt * 9 + i], mx[rowt * 9 + i], lv, li);
        const size_t o = (((size_t)(row0 + rowt)) * SNKB + blockIdx.y) * BTOP;
#pragma unroll
        for (int i = 0; i < BTOP; ++i) { cand_val[o + i] = lv[i]; cand_idx[o + i] = li[i]; }
    }
}

// ---------------- Kernel B: merge -> top-20 per row (per-lane top-8, whp lossless) ----------------
__global__ __launch_bounds__(256)
void topk_merge_kernel(const float* __restrict__ cand_val, const int* __restrict__ cand_idx,
                       int* __restrict__ cand32)
{
    const int row  = blockIdx.x * 4 + (threadIdx.x >> 6);
    const int lane = threadIdx.x & 63;
    const size_t base = (size_t)row * CANDS_PER_ROW;
    float lv[LCAP]; int li[LCAP];
#pragma unroll
    for (int i = 0; i < LCAP; ++i) { lv[i] = -3.4e38f; li[i] = 0x7fffffff; }
#pragma unroll 1
    for (int m = 0; m < CANDS_PER_ROW / 64; ++m) {                // 24 per lane
        const int p = lane + (m << 6);
        insN<LCAP>(cand_val[base + p], cand_idx[base + p], lv, li);
    }
    int out = 0;
#pragma unroll 1
    for (int it = 0; it < NCAND; ++it) {
        float rv = lv[0]; int ridx = li[0];
#pragma unroll
        for (int off = 1; off < 64; off <<= 1) {
            const float ov = __shfl_xor(rv, off);
            const int   oi = __shfl_xor(ridx, off);
            if (ov > rv || (ov == rv && oi < ridx)) { rv = ov; ridx = oi; }
        }
        if (lane == it) out = ridx;
        if (li[0] == ridx) {
#pragma unroll
            for (int i = 0; i < LCAP - 1; ++i) { lv[i] = lv[i + 1]; li[i] = li[i + 1]; }
            lv[LCAP - 1] = -3.4e38f; li[LCAP - 1] = 0x7fffffff;
        }
    }
    if (lane < NCAND) cand32[(size_t)row * NCAND + lane] = out;
}

// ---------------- Kernel B2: exact fp32 rescore of 20 candidates -> final top-16 ----------------
__global__ __launch_bounds__(256)
void rescore_kernel(const float* __restrict__ Q, const float* __restrict__ K,
                    const int* __restrict__ cand32, int* __restrict__ topk)
{
    const int row  = blockIdx.x;
    const int wv   = threadIdx.x >> 6;
    const int lane = threadIdx.x & 63;
    __shared__ float sv[NCAND];
    __shared__ int   si[NCAND];
    if (threadIdx.x < NCAND) si[threadIdx.x] = cand32[(size_t)row * NCAND + threadIdx.x];
    float4 qv[4];
#pragma unroll
    for (int u = 0; u < 4; ++u)
        qv[u] = ((const float4*)(Q + (size_t)row * DDIM))[(u << 6) + lane];
    __syncthreads();
#pragma unroll 1
    for (int c = 0; c < NCAND / 4; ++c) {
        const int slot = wv * (NCAND / 4) + c;
        const float* kr = K + (size_t)si[slot] * DDIM;
        float s = 0.f;
#pragma unroll
        for (int u = 0; u < 4; ++u) {
            const float4 kv = ((const float4*)kr)[(u << 6) + lane];
            s += kv.x * qv[u].x + kv.y * qv[u].y + kv.z * qv[u].z + kv.w * qv[u].w;
        }
#pragma unroll
        for (int off = 32; off >= 1; off >>= 1) s += __shfl_xor(s, off);
        if (lane == 0) sv[slot] = s;
    }
    __syncthreads();
    if (wv == 0) {
        float v = (lane < NCAND) ? sv[lane] : -3.4e38f;
        int  id = (lane < NCAND) ? si[lane] : 0x7fffffff;
        int out = 0;
#pragma unroll 1
        for (int it = 0; it < KSEL; ++it) {
            float rv = v; int ridx = id;
#pragma unroll
            for (int off = 1; off < 64; off <<= 1) {
                const float ov = __shfl_xor(rv, off);
                const int   oi = __shfl_xor(ridx, off);
                if (ov > rv || (ov == rv && oi < ridx)) { rv = ov; ridx = oi; }
            }
            if (lane == it) out = ridx;
            if (id == ridx) v = -3.4e38f;
        }
        if (lane < KSEL) topk[(size_t)row * KSEL + lane] = out;
    }
}

// ---------------- Kernel C: X(fp32) x W projections (LO=1 3-term / LO=0 1-term) ----------------
template <int LO>
__global__ __launch_bounds__(256)
void proj_split_kernel(const float* __restrict__ X, const unsigned short* __restrict__ Whi,
                       const unsigned short* __restrict__ Wlo, const float* __restrict__ bias,
                       void* __restrict__ outp, const int store_bf16)
{
    constexpr int WOFF = LO ? 32768 : 16384;
    __shared__ char smem[LO ? 65536 : 32768];
    const int tid  = threadIdx.x;
    const int lane = tid & 63;
    const int w    = tid >> 6;
    const int wr   = w >> 1, wc = w & 1;
    const int row0 = blockIdx.x * 128;
    const int col0 = blockIdx.y * 128;

    const f32x4 zero = {0.f, 0.f, 0.f, 0.f};
    f32x4 acc[4][4];
#pragma unroll
    for (int mi = 0; mi < 4; ++mi)
#pragma unroll
        for (int ni = 0; ni < 4; ++ni) acc[mi][ni] = zero;

    const int srow = lane >> 3;
    const int scol = (((lane & 7) ^ srow) << 4);
    const int xr = tid >> 1, xh = tid & 1;

    for (int step = 0; step < 16; ++step) {
        const int kbyte = step << 7;
        const int k0    = step << 6;
        __syncthreads();
#pragma unroll
        for (int i = 0; i < (LO ? 8 : 4); ++i) {
            const int chunk = w + (i << 2);
            const int plane = chunk >> 4;
            const int r     = ((chunk & 15) << 3) + srow;
            const unsigned short* Wb = plane ? Wlo : Whi;
            const char* src = (const char*)Wb + (((size_t)(col0 + r)) << 11) + kbyte + scol;
            gload16(src, smem + WOFF + (chunk << 10));
        }
        {
            const float* Xp = X + (size_t)(row0 + xr) * DDIM + k0 + xh * 32;
            float4 xa[8];
#pragma unroll
            for (int i = 0; i < 8; ++i) xa[i] = ((const float4*)Xp)[i];
            const int xbase = xr * 128;
#pragma unroll
            for (int s4 = 0; s4 < 4; ++s4) {
                const float4 a = xa[2 * s4], b = xa[2 * s4 + 1];
                uint4 hw, lw;
                if (LO) {
                    split2(a.x, a.y, hw.x, lw.x);
                    split2(a.z, a.w, hw.y, lw.y);
                    split2(b.x, b.y, hw.z, lw.z);
                    split2(b.z, b.w, hw.w, lw.w);
                } else {
                    hw.x = (unsigned int)f2bf(a.x) | ((unsigned int)f2bf(a.y) << 16);
                    hw.y = (unsigned int)f2bf(a.z) | ((unsigned int)f2bf(a.w) << 16);
                    hw.z = (unsigned int)f2bf(b.x) | ((unsigned int)f2bf(b.y) << 16);
                    hw.w = (unsigned int)f2bf(b.z) | ((unsigned int)f2bf(b.w) << 16);
                }
                const int off = xbase + ((((xh << 2) + s4) ^ (xr & 7)) << 4);
                *(uint4*)(smem + off) = hw;
                if (LO) *(uint4*)(smem + 16384 + off) = lw;
            }
        }
        asm volatile("s_waitcnt vmcnt(0)" ::: "memory");
        __syncthreads();
#pragma unroll
        for (int kk = 0; kk < 2; ++kk) {
            const int cb = (kk << 6) + ((lane >> 4) << 4);
            bf16x8 ah[4], bh[4];
#pragma unroll
            for (int mi = 0; mi < 4; ++mi) {
                const int r = wr * 64 + mi * 16 + (lane & 15);
                ah[mi] = *(const bf16x8*)(smem + r * 128 + (cb ^ ((r & 7) << 4)));
            }
#pragma unroll
            for (int ni = 0; ni < 4; ++ni) {
                const int r = wc * 64 + ni * 16 + (lane & 15);
                bh[ni] = *(const bf16x8*)(smem + WOFF + r * 128 + (cb ^ ((r & 7) << 4)));
            }
#pragma unroll
            for (int mi = 0; mi < 4; ++mi)
#pragma unroll
                for (int ni = 0; ni < 4; ++ni)
                    acc[mi][ni] = __builtin_amdgcn_mfma_f32_16x16x32_bf16(ah[mi], bh[ni], acc[mi][ni], 0, 0, 0);
            if (LO) {
                bf16x8 al[4];
#pragma unroll
                for (int mi = 0; mi < 4; ++mi) {
                    const int r = wr * 64 + mi * 16 + (lane & 15);
                    al[mi] = *(const bf16x8*)(smem + 16384 + r * 128 + (cb ^ ((r & 7) << 4)));
                }
#pragma unroll
                for (int mi = 0; mi < 4; ++mi)
#pragma unroll
                    for (int ni = 0; ni < 4; ++ni)
                        acc[mi][ni] = __builtin_amdgcn_mfma_f32_16x16x32_bf16(al[mi], bh[ni], acc[mi][ni], 0, 0, 0);
                bf16x8 bl[4];
#pragma unroll
                for (int ni = 0; ni < 4; ++ni) {
                    const int r = wc * 64 + ni * 16 + (lane & 15);
                    bl[ni] = *(const bf16x8*)(smem + WOFF + 16384 + r * 128 + (cb ^ ((r & 7) << 4)));
                }
#pragma unroll
                for (int mi = 0; mi < 4; ++mi)
#pragma unroll
                    for (int ni = 0; ni < 4; ++ni)
                        acc[mi][ni] = __builtin_amdgcn_mfma_f32_16x16x32_bf16(ah[mi], bl[ni], acc[mi][ni], 0, 0, 0);
            }
        }
    }

#pragma unroll
    for (int ni = 0; ni < 4; ++ni) {
        const int col = col0 + wc * 64 + ni * 16 + (lane & 15);
        const float bz = bias[col];
#pragma unroll
        for (int mi = 0; mi < 4; ++mi) {
            const int rbase = row0 + wr * 64 + mi * 16 + ((lane >> 4) << 2);
            const f32x4 v = acc[mi][ni];
#pragma unroll
            for (int j = 0; j < 4; ++j) {
                const float val = v[j] + bz;
                if (store_bf16)
                    ((unsigned short*)outp)[(size_t)(rbase + j) * DDIM + col] = f2bf(val);
                else
                    ((float*)outp)[(size_t)(rbase + j) * DDIM + col] = val;
            }
        }
    }
}

// ---------------- Kernel U: u[t, h*1024+j] = sum_c Qpb[t, h*128+c] * wkT[h][j][c]  (K=128) ----------------
__global__ __launch_bounds__(256)
void ugemm_kernel(const unsigned short* __restrict__ Qpb, const unsigned short* __restrict__ wkT,
                  unsigned short* __restrict__ u)
{
    __shared__ char smem[32768];
    const int tid  = threadIdx.x;
    const int lane = tid & 63;
    const int w    = tid >> 6;
    const int wr   = w >> 1, wc = w & 1;
    const int row0 = blockIdx.x * 128;
    const int j0   = blockIdx.y * 128;
    const int h    = blockIdx.z;

    const f32x4 zero = {0.f, 0.f, 0.f, 0.f};
    f32x4 acc[4][4];
#pragma unroll
    for (int mi = 0; mi < 4; ++mi)
#pragma unroll
        for (int ni = 0; ni < 4; ++ni) acc[mi][ni] = zero;

    const int srow = lane >> 3;
    const int scol = (((lane & 7) ^ srow) << 4);

#pragma unroll 1
    for (int step = 0; step < 2; ++step) {
        const int kbyte = step << 7;
        __syncthreads();
#pragma unroll
        for (int i = 0; i < 8; ++i) {
            const int chunk = w + (i << 2);
            const char* src;
            if (chunk < 16) {
                const int r = (chunk << 3) + srow;
                src = (const char*)Qpb + (((size_t)(row0 + r)) << 11) + h * 256 + kbyte + scol;
            } else {
                const int r = ((chunk - 16) << 3) + srow;
                src = (const char*)wkT + ((size_t)h << 18) + (((size_t)(j0 + r)) << 8) + kbyte + scol;
            }
            gload16(src, smem + (chunk << 10));
        }
        __syncthreads();
#pragma unroll
        for (int kk = 0; kk < 2; ++kk) {
            const int cb = (kk << 6) + ((lane >> 4) << 4);
            bf16x8 af[4], bf[4];
#pragma unroll
            for (int mi = 0; mi < 4; ++mi) {
                const int r = wr * 64 + mi * 16 + (lane & 15);
                af[mi] = *(const bf16x8*)(smem + r * 128 + (cb ^ ((r & 7) << 4)));
            }
#pragma unroll
            for (int ni = 0; ni < 4; ++ni) {
                const int r = wc * 64 + ni * 16 + (lane & 15);
                bf[ni] = *(const bf16x8*)(smem + 16384 + r * 128 + (cb ^ ((r & 7) << 4)));
            }
#pragma unroll
            for (int mi = 0; mi < 4; ++mi)
#pragma unroll
                for (int ni = 0; ni < 4; ++ni)
                    acc[mi][ni] = __builtin_amdgcn_mfma_f32_16x16x32_bf16(af[mi], bf[ni], acc[mi][ni], 0, 0, 0);
        }
    }

#pragma unroll
    for (int ni = 0; ni < 4; ++ni) {
        const int col = j0 + wc * 64 + ni * 16 + (lane & 15);
#pragma unroll
        for (int mi = 0; mi < 4; ++mi) {
            const int rbase = row0 + wr * 64 + mi * 16 + ((lane >> 4) << 2);
            const f32x4 v = acc[mi][ni];
#pragma unroll
            for (int j = 0; j < 4; ++j)
                u[(size_t)(rbase + j) * 8192 + h * 1024 + col] = f2bf(v[j]);
        }
    }
}

// ---------------- Kernel D2: scores from u . raw-K, softmax, z = attn @ raw-V ----------------
// K staged (src-swizzled) via gload_lds; V staged fp32->bf16 inline from mvals (convV kernel
// eliminated; bit-identical values). 33.3KB LDS, phase-reused.
__global__ __launch_bounds__(256)
void attn2_kernel(const unsigned short* __restrict__ Khi, const float* __restrict__ mvals,
                  unsigned short* __restrict__ uz, const int* __restrict__ topk)
{
    __shared__ char smem[33344];                 // KV 32KB @0, idx@32768, sc@32832
    int*   idx_s = (int*)(smem + 32768);
    float* sc_s  = (float*)(smem + 32832);       // [8][16]
    const int t   = blockIdx.x;
    const int tid = threadIdx.x;
    if (tid < KSEL) idx_s[tid] = topk[(size_t)t * KSEL + tid];
    __syncthreads();
    // phase 1: stage K (source-swizzled)
#pragma unroll
    for (int i = 0; i < 8; ++i) {
        const int s   = tid + (i << 8);
        const int row = s >> 7, col = s & 127;
        const size_t kb = ((size_t)idx_s[row]) << 11;
        gload16((const char*)Khi + kb + ((col ^ (row & 7)) << 4), smem + (s << 4));
    }
    __syncthreads();                             // K landed
    // scores: pair (h,k) handled by 2 threads (sub halves of 1024 dims)
    {
        const int p = tid >> 1, sub = tid & 1;
        const int h = p >> 4, k = p & 15;
        const unsigned short* urow = uz + (size_t)t * 8192 + h * 1024 + sub * 512;
        float s = 0.f;
#pragma unroll 8
        for (int j = 0; j < 64; ++j) {
            const uint4 uw = *(const uint4*)(urow + (j << 3));
            const uint4 kw = *(const uint4*)(smem + (k << 11) + ((((sub << 6) + j) ^ (k & 7)) << 4));
            s += bf2f((unsigned short)(uw.x & 0xffffu)) * bf2f((unsigned short)(kw.x & 0xffffu))
               + bf2f((unsigned short)(uw.x >> 16))     * bf2f((unsigned short)(kw.x >> 16))
               + bf2f((unsigned short)(uw.y & 0xffffu)) * bf2f((unsigned short)(kw.y & 0xffffu))
               + bf2f((unsigned short)(uw.y >> 16))     * bf2f((unsigned short)(kw.y >> 16))
               + bf2f((unsigned short)(uw.z & 0xffffu)) * bf2f((unsigned short)(kw.z & 0xffffu))
               + bf2f((unsigned short)(uw.z >> 16))     * bf2f((unsigned short)(kw.z >> 16))
               + bf2f((unsigned short)(uw.w & 0xffffu)) * bf2f((unsigned short)(kw.w & 0xffffu))
               + bf2f((unsigned short)(uw.w >> 16))     * bf2f((unsigned short)(kw.w >> 16));
        }
        s += __shfl_xor(s, 1);
        if (sub == 0) sc_s[h * 16 + k] = s;
    }
    __syncthreads();                             // K + u reads retired; sc ready
    // phase 2: stage V fp32 -> bf16 inline into the SAME 32KB
#pragma unroll
    for (int i = 0; i < 8; ++i) {
        const int s   = tid + (i << 8);
        const int row = s >> 7, col8 = s & 127;
        const float* vp = mvals + (((size_t)idx_s[row]) << 10) + (col8 << 3);
        const float4 a = *(const float4*)vp;
        const float4 b = *(const float4*)(vp + 4);
        uint4 o;
        o.x = (unsigned)f2bf(a.x) | ((unsigned)f2bf(a.y) << 16);
        o.y = (unsigned)f2bf(a.z) | ((unsigned)f2bf(a.w) << 16);
        o.z = (unsigned)f2bf(b.x) | ((unsigned)f2bf(b.y) << 16);
        o.w = (unsigned)f2bf(b.z) | ((unsigned)f2bf(b.w) << 16);
        *(uint4*)(smem + (s << 4)) = o;
    }
    __syncthreads();                             // V landed
    // softmax (redundant per 32-thread head group) + z (overwrites uz)
    const int h  = tid >> 5;
    const int dp = tid & 31;
    const float scale = 0.08838834764831845f;    // 1/sqrt(128)
    float mxv = -3.4e38f;
#pragma unroll
    for (int n = 0; n < KSEL; ++n) mxv = fmaxf(mxv, sc_s[h * 16 + n]);
    float wgt[KSEL]; float wsum = 0.f;
#pragma unroll
    for (int n = 0; n < KSEL; ++n) { wgt[n] = __expf((sc_s[h * 16 + n] - mxv) * scale); wsum += wgt[n]; }
    const float inv = 1.f / wsum;
#pragma unroll
    for (int n = 0; n < KSEL; ++n) wgt[n] *= inv;
#pragma unroll 1
    for (int j = 0; j < 16; ++j) {
        float z0 = 0.f, z1 = 0.f;
#pragma unroll
        for (int k = 0; k < 16; ++k) {
            const unsigned int vv = *(const unsigned int*)(smem + (k << 11) + (j << 7) + (dp << 2));
            z0 += wgt[k] * bf2f((unsigned short)(vv & 0xffffu));
            z1 += wgt[k] * bf2f((unsigned short)(vv >> 16));
        }
        *(unsigned int*)((char*)uz + (size_t)t * 16384 + (h << 11) + (j << 7) + (dp << 2)) =
            (unsigned int)f2bf(z0) | ((unsigned int)f2bf(z1) << 16);
    }
}

// ---------------- Kernel Z: attn_out[t, h*128+c] = sum_d z[t,h,d]*Wv_h[c,d] + bv ----------------
__global__ __launch_bounds__(256)
void zout_kernel(const unsigned short* __restrict__ z, const unsigned short* __restrict__ IPhi,
                 const float* __restrict__ ipb, float* __restrict__ attn_out)
{
    __shared__ char smem[32768];
    const int tid  = threadIdx.x;
    const int lane = tid & 63;
    const int w    = tid >> 6;
    const int wr   = w >> 1, wc = w & 1;
    const int row0 = blockIdx.x * 128;
    const int h    = blockIdx.y;

    const f32x4 zero = {0.f, 0.f, 0.f, 0.f};
    f32x4 acc[4][4];
#pragma unroll
    for (int mi = 0; mi < 4; ++mi)
#pragma unroll
        for (int ni = 0; ni < 4; ++ni) acc[mi][ni] = zero;

    const int srow = lane >> 3;
    const int scol = (((lane & 7) ^ srow) << 4);

#pragma unroll 1
    for (int step = 0; step < 16; ++step) {
        const int kbyte = step << 7;
        __syncthreads();
#pragma unroll
        for (int i = 0; i < 8; ++i) {
            const int chunk = w + (i << 2);
            const char* src;
            if (chunk < 16) {
                const int r = (chunk << 3) + srow;
                src = (const char*)z + (((size_t)(row0 + r)) << 14) + (h << 11) + kbyte + scol;
            } else {
                const int r = ((chunk - 16) << 3) + srow;
                src = (const char*)IPhi + (((size_t)(2048 + h * 128 + r)) << 11) + kbyte + scol;
            }
            gload16(src, smem + (chunk << 10));
        }
        __syncthreads();
#pragma unroll
        for (int kk = 0; kk < 2; ++kk) {
            const int cb = (kk << 6) + ((lane >> 4) << 4);
            bf16x8 af[4], bf[4];
#pragma unroll
            for (int mi = 0; mi < 4; ++mi) {
                const int r = wr * 64 + mi * 16 + (lane & 15);
                af[mi] = *(const bf16x8*)(smem + r * 128 + (cb ^ ((r & 7) << 4)));
            }
#pragma unroll
            for (int ni = 0; ni < 4; ++ni) {
                const int r = wc * 64 + ni * 16 + (lane & 15);
                bf[ni] = *(const bf16x8*)(smem + 16384 + r * 128 + (cb ^ ((r & 7) << 4)));
            }
#pragma unroll
            for (int mi = 0; mi < 4; ++mi)
#pragma unroll
                for (int ni = 0; ni < 4; ++ni)
                    acc[mi][ni] = __builtin_amdgcn_mfma_f32_16x16x32_bf16(af[mi], bf[ni], acc[mi][ni], 0, 0, 0);
        }
    }

#pragma unroll
    for (int ni = 0; ni < 4; ++ni) {
        const int cl = wc * 64 + ni * 16 + (lane & 15);
        const float bz = ipb[2048 + h * 128 + cl];
#pragma unroll
        for (int mi = 0; mi < 4; ++mi) {
            const int rbase = row0 + wr * 64 + mi * 16 + ((lane >> 4) << 2);
            const f32x4 v = acc[mi][ni];
#pragma unroll
            for (int j = 0; j < 4; ++j)
                attn_out[(size_t)(rbase + j) * 1024 + h * 128 + cl] = v[j] + bz;
        }
    }
}

extern "C" void kernel_launch(void* const* d_in, const int* in_sizes, int n_in,
                              void* d_out, int out_size, void* d_ws, size_t ws_size,
                              hipStream_t stream)
{
    const float* queries = (const float*)d_in[0];
    const float* mkeys   = (const float*)d_in[1];
    const float* mvals   = (const float*)d_in[2];
    const float* ipw     = (const float*)d_in[3];
    const float* ipb     = (const float*)d_in[4];
    const float* opw     = (const float*)d_in[5];
    const float* opb     = (const float*)d_in[6];

    char* ws = (char*)d_ws;
    size_t off = 0;
    auto alloc = [&](size_t bytes) -> char* {
        char* p = ws + off;
        off += (bytes + 255) & ~(size_t)255;
        return p;
    };
    unsigned short* Khi  = (unsigned short*)alloc((size_t)MKEYS * DDIM * 2);    // 67.1 MB
    unsigned short* Qhi  = (unsigned short*)alloc((size_t)NROWS * DDIM * 2);    // 8.4 MB
    unsigned short* IPhi = (unsigned short*)alloc((size_t)3 * DDIM * DDIM * 2); // 6.3 MB
    unsigned short* OPhi = (unsigned short*)alloc((size_t)DDIM * DDIM * 2);     // 2.1 MB
    unsigned short* OPlo = (unsigned short*)alloc((size_t)DDIM * DDIM * 2);     // 2.1 MB
    unsigned short* wkT  = (unsigned short*)alloc((size_t)DDIM * DDIM * 2);     // 2.1 MB
    float* cand_val = (float*)alloc((size_t)NROWS * CANDS_ALLOC * 4);           // 33.55 MB
    int*   cand_idx = (int*)  alloc((size_t)NROWS * CANDS_ALLOC * 4);           // 33.55 MB
    int*   cand32   = (int*)  alloc((size_t)NROWS * NCAND * 4);                 // 0.33 MB
    int*   topk     = (int*)  alloc((size_t)NROWS * KSEL * 4);                  // 0.26 MB
    unsigned short* u = (unsigned short*)alloc((size_t)NROWS * 8 * DDIM * 2);   // 67.1 MB (z in-place)
    // aliases (total ~222 MB <= 235 proven):
    unsigned short* Qpb = (unsigned short*)Qhi;       // Qhi dead after sims
    float* attn_out     = (float*)Khi;                // Khi dead after attn2; zout runs after

    // 0) converts + weight preps
    conv_bf16_kernel<<<2048, 256, 0, stream>>>(queries, Qhi, NROWS * DDIM / 4);
    conv_bf16_kernel<<<2048, 256, 0, stream>>>(mkeys, Khi, MKEYS * DDIM / 4);
    conv_bf16_kernel<<<1024, 256, 0, stream>>>(ipw, IPhi, 3 * DDIM * DDIM / 4);
    split_bf16_kernel<<<512,  256, 0, stream>>>(opw, OPhi, OPlo, DDIM * DDIM / 4);
    wk_transpose_kernel<<<64, 256, 0, stream>>>(ipw, wkT);
    // 1) bf16 similarity GEMM + per-keyblock top-6
    sims_mfma_kernel<<<dim3(NROWS / SBM, MKEYS / SBN), 256, 0, stream>>>(Qhi, Khi, cand_val, cand_idx);
    // 2) merge to top-20 candidates
    topk_merge_kernel<<<NROWS / 4, 256, 0, stream>>>(cand_val, cand_idx, cand32);
    // 3) exact fp32 rescore -> final top-16
    rescore_kernel<<<NROWS, 256, 0, stream>>>(queries, mkeys, cand32, topk);
    // 4) q projection (1-term, bf16 out into Qhi region)
    proj_split_kernel<0><<<dim3(NROWS / 128, 8), 256, 0, stream>>>(queries, IPhi, IPhi, ipb, Qpb, 1);
    // 5) u = Qpb @ wkT per head (K=128)
    ugemm_kernel<<<dim3(NROWS / 128, 8, 8), 256, 0, stream>>>(Qpb, wkT, u);
    // 6) scores/softmax/z over raw K (bf16) and raw V (fp32, converted inline); z overwrites u
    attn2_kernel<<<NROWS, 256, 0, stream>>>(Khi, mvals, u, topk);
    // 7) attn_out = z @ Wv^T + bv (into Khi region)
    zout_kernel<<<dim3(NROWS / 128, 8), 256, 0, stream>>>(u, IPhi, ipb, attn_out);
    // 8) output projection (3-term) -> d_out (f32)
    proj_split_kernel<1><<<dim3(NROWS / 128, 8), 256, 0, stream>>>(attn_out, OPhi, OPlo, opb, d_out, 0);
}

// Round 15
// 761.969 us; speedup vs baseline: 3.2903x; 1.0575x over previous
//
#include <hip/hip_runtime.h>
#include <hip/hip_bf16.h>

#define NROWS 4096    // B*S
#define DDIM  1024
#define MKEYS 32768
#define HDIM  128
#define KSEL  16
#define NCAND 20      // rescored candidates per row
#define BTOP  6       // per-keyblock kept candidates
#define LCAP  8       // merge per-lane list depth

// ---- sims MFMA GEMM geometry: m97-style 128x128 tile, 4 waves, 32KB LDS ----
#define SBM 128
#define SBN 128
#define SNKB (MKEYS / SBN)            // 256 key blocks
#define CANDS_PER_ROW (SNKB * BTOP)   // 1536
#define CANDS_ALLOC   2048            // allocation stride
#define NSTEPS 16                     // K = 1024 bf16, BK = 64

typedef short bf16x8 __attribute__((ext_vector_type(8)));
typedef float f32x4  __attribute__((ext_vector_type(4)));

__device__ __forceinline__ float bf2f(unsigned short u) {
    union { unsigned int i; float f; } x; x.i = ((unsigned int)u) << 16; return x.f;
}
__device__ __forceinline__ unsigned short f2bf(float f) {
    union { float f; unsigned int u; } v; v.f = f;
    unsigned int r = (v.u + 0x7fffu + ((v.u >> 16) & 1u)) >> 16;   // RNE
    return (unsigned short)r;
}
__device__ __forceinline__ void gload16(const void* g, const void* l) {
    __builtin_amdgcn_global_load_lds((const __attribute__((address_space(1))) unsigned int*)g,
                                     (__attribute__((address_space(3))) unsigned int*)l, 16, 0, 0);
}
template <int N>
__device__ __forceinline__ void insN(float v, int id, float* lv, int* li) {
    if (v > lv[N - 1]) {
#pragma unroll
        for (int i = 0; i < N; ++i) {
            const bool gt = v > lv[i];
            const float tv = gt ? lv[i] : v;
            const int   ti = gt ? li[i] : id;
            if (gt) { lv[i] = v; li[i] = id; }
            v = tv; id = ti;
        }
    }
}
__device__ __forceinline__ void split2(float x0, float x1, unsigned int& hp, unsigned int& lp) {
    union { float f; unsigned int u; } u0, u1;
    u0.f = x0; u1.f = x1;
    hp = (u0.u >> 16) | (u1.u & 0xffff0000u);
    const float r0 = x0 - bf2f((unsigned short)(u0.u >> 16));
    const float r1 = x1 - bf2f((unsigned short)(u1.u >> 16));
    lp = (unsigned int)f2bf(r0) | ((unsigned int)f2bf(r1) << 16);
}

// ---------------- fp32 -> bf16 (RNE) ----------------
__global__ __launch_bounds__(256)
void conv_bf16_kernel(const float* __restrict__ x, unsigned short* __restrict__ hi, const int n4)
{
    int i = blockIdx.x * 256 + threadIdx.x;
    const int stride = gridDim.x * 256;
    for (; i < n4; i += stride) {
        const float4 f = ((const float4*)x)[i];
        ushort4 h;
        h.x = f2bf(f.x); h.y = f2bf(f.y); h.z = f2bf(f.z); h.w = f2bf(f.w);
        ((ushort4*)hi)[i] = h;
    }
}

// ---------------- fp32 -> (hi, lo) bf16 split (out-proj weights only) ----------------
__global__ __launch_bounds__(256)
void split_bf16_kernel(const float* __restrict__ x, unsigned short* __restrict__ hi,
                       unsigned short* __restrict__ lo, const int n4)
{
    int i = blockIdx.x * 256 + threadIdx.x;
    const int stride = gridDim.x * 256;
    for (; i < n4; i += stride) {
        const float4 f = ((const float4*)x)[i];
        ushort4 h, l;
        h.x = f2bf(f.x); l.x = f2bf(f.x - bf2f(h.x));
        h.y = f2bf(f.y); l.y = f2bf(f.y - bf2f(h.y));
        h.z = f2bf(f.z); l.z = f2bf(f.z - bf2f(h.z));
        h.w = f2bf(f.w); l.w = f2bf(f.w - bf2f(h.w));
        ((ushort4*)hi)[i] = h;
        ((ushort4*)lo)[i] = l;
    }
}

// ---------------- wkT[h][j][c] = bf16(ipw[1024 + h*128 + c][j]) — coalesced LDS transpose ----------------
__global__ __launch_bounds__(256)
void wk_transpose_kernel(const float* __restrict__ ipw, unsigned short* __restrict__ wkT)
{
    __shared__ unsigned short T[128 * 129];
    const int bx  = blockIdx.x;
    const int h   = bx >> 3, j0 = bx & 7;
    const int tid = threadIdx.x;
#pragma unroll 8
    for (int i = 0; i < 64; ++i) {
        const int idx = (i << 8) + tid;
        const int c = idx >> 7, j = idx & 127;
        T[c * 129 + j] = f2bf(ipw[((size_t)(1024 + h * 128 + c)) * 1024 + j0 * 128 + j]);
    }
    __syncthreads();
#pragma unroll
    for (int i = 0; i < 8; ++i) {
        const int g  = (i << 8) + tid;
        const int j  = g >> 4, c0 = (g & 15) << 3;
        uint4 o;
        o.x = (unsigned)T[(c0 + 0) * 129 + j] | ((unsigned)T[(c0 + 1) * 129 + j] << 16);
        o.y = (unsigned)T[(c0 + 2) * 129 + j] | ((unsigned)T[(c0 + 3) * 129 + j] << 16);
        o.z = (unsigned)T[(c0 + 4) * 129 + j] | ((unsigned)T[(c0 + 5) * 129 + j] << 16);
        o.w = (unsigned)T[(c0 + 6) * 129 + j] | ((unsigned)T[(c0 + 7) * 129 + j] << 16);
        *(uint4*)(wkT + ((size_t)h << 17) + ((size_t)(j0 * 128 + j) << 7) + c0) = o;
    }
}

// ---------------- Kernel A: sims(bf16) = Qhi.Khi^T, 128x128; packed branch-free top-6 epilogue ----------------
// Packed key: bits[31:8] = sortable(f32 score) truncated, bits[7:0] = in-block key idx (0..127).
// Unconditional 2-op/level min-max bubble: no divergence (r14 lesson: exec-masked float cascade
// ran ~every value anyway at ~2x the ops).
__global__ __launch_bounds__(256)
void sims_mfma_kernel(const unsigned short* __restrict__ Qhi, const unsigned short* __restrict__ Khi,
                      float* __restrict__ cand_val, int* __restrict__ cand_idx)
{
    __shared__ char smem[32768];
    const int tid  = threadIdx.x;
    const int lane = tid & 63;
    const int w    = tid >> 6;
    const int wr   = w >> 1, wc = w & 1;
    const int row0 = blockIdx.x * SBM;
    const int key0 = blockIdx.y * SBN;

    const f32x4 zero = {0.f, 0.f, 0.f, 0.f};
    f32x4 acc[4][4];
#pragma unroll
    for (int mi = 0; mi < 4; ++mi)
#pragma unroll
        for (int ni = 0; ni < 4; ++ni) acc[mi][ni] = zero;

    const int srow = lane >> 3;
    const int scol = (((lane & 7) ^ srow) << 4);

#pragma unroll 1
    for (int step = 0; step < NSTEPS; ++step) {
        const int kbyte = step << 7;
        __syncthreads();
#pragma unroll
        for (int i = 0; i < 8; ++i) {
            const int chunk = w + (i << 2);
            const char* src;
            if (chunk < 16) {
                const int r = (chunk << 3) + srow;
                src = (const char*)Qhi + (((size_t)(row0 + r)) << 11) + kbyte + scol;
            } else {
                const int r = ((chunk - 16) << 3) + srow;
                src = (const char*)Khi + (((size_t)(key0 + r)) << 11) + kbyte + scol;
            }
            gload16(src, smem + (chunk << 10));
        }
        __syncthreads();
#pragma unroll
        for (int kk = 0; kk < 2; ++kk) {
            const int cb = (kk << 6) + ((lane >> 4) << 4);
            bf16x8 af[4], bf[4];
#pragma unroll
            for (int mi = 0; mi < 4; ++mi) {
                const int r = wr * 64 + mi * 16 + (lane & 15);
                af[mi] = *(const bf16x8*)(smem + r * 128 + (cb ^ ((r & 7) << 4)));
            }
#pragma unroll
            for (int ni = 0; ni < 4; ++ni) {
                const int r = wc * 64 + ni * 16 + (lane & 15);
                bf[ni] = *(const bf16x8*)(smem + 16384 + r * 128 + (cb ^ ((r & 7) << 4)));
            }
#pragma unroll
            for (int mi = 0; mi < 4; ++mi)
#pragma unroll
                for (int ni = 0; ni < 4; ++ni)
                    acc[mi][ni] = __builtin_amdgcn_mfma_f32_16x16x32_bf16(af[mi], bf[ni], acc[mi][ni], 0, 0, 0);
        }
    }

    // ---- packed top-6: 4 passes of 32 cols through LDS C tile [128][33] f32 ----
    unsigned int lp[BTOP];
#pragma unroll
    for (int i = 0; i < BTOP; ++i) lp[i] = 0u;
    float* C_lds = (float*)smem;
    const int rowt = tid & 127;
    const int half = tid >> 7;

#pragma unroll
    for (int q = 0; q < 4; ++q) {
        __syncthreads();
        if (wc == (q >> 1)) {
#pragma unroll
            for (int mi = 0; mi < 4; ++mi)
#pragma unroll
                for (int nn = 0; nn < 2; ++nn) {
                    const int ni = ((q & 1) << 1) + nn;
                    const int r  = wr * 64 + mi * 16 + ((lane >> 4) << 2);
                    const int c  = (nn << 4) + (lane & 15);
                    const f32x4 v = acc[mi][ni];
#pragma unroll
                    for (int j = 0; j < 4; ++j) C_lds[(r + j) * 33 + c] = v[j];
                }
        }
        __syncthreads();
        const int lbase = (q << 5) + (half << 4);      // in-block key index base
#pragma unroll
        for (int cc = 0; cc < 16; ++cc) {
            const unsigned int ub = __float_as_uint(C_lds[rowt * 33 + (half << 4) + cc]);
            unsigned int p = ub ^ ((unsigned int)((int)ub >> 31) | 0x80000000u);
            p = (p & 0xFFFFFF00u) | (unsigned int)(lbase + cc);
#pragma unroll
            for (int i = 0; i < BTOP; ++i) {           // unconditional bubble: 2 VALU/level
                const unsigned int hi2 = p > lp[i] ? p : lp[i];
                p = p > lp[i] ? lp[i] : p;
                lp[i] = hi2;
            }
        }
    }
    // merge the two half-lists per row (packed; stride 9 -> conflict-free)
    __syncthreads();
    unsigned int* mp = (unsigned int*)smem;            // [128][9]
    if (half == 1) {
#pragma unroll
        for (int i = 0; i < BTOP; ++i) mp[rowt * 9 + i] = lp[i];
    }
    __syncthreads();
    if (half == 0) {
#pragma unroll
        for (int i = 0; i < BTOP; ++i) {
            unsigned int p = mp[rowt * 9 + i];
#pragma unroll
            for (int k = 0; k < BTOP; ++k) {
                const unsigned int hi2 = p > lp[k] ? p : lp[k];
                p = p > lp[k] ? lp[k] : p;
                lp[k] = hi2;
            }
        }
        const size_t o = (((size_t)(row0 + rowt)) * SNKB + blockIdx.y) * BTOP;
#pragma unroll
        for (int i = 0; i < BTOP; ++i) {               // unpack: value (approx) + global idx
            const unsigned int s  = lp[i];
            const unsigned int vb = s & 0xFFFFFF00u;
            const unsigned int fb = (vb & 0x80000000u) ? (vb & 0x7FFFFFFFu) : ~vb;
            cand_val[o + i] = __uint_as_float(fb);
            cand_idx[o + i] = key0 + (int)(s & 0xFFu);
        }
    }
}

// ---------------- Kernel B: merge -> top-20 per row (per-lane top-8, whp lossless) ----------------
__global__ __launch_bounds__(256)
void topk_merge_kernel(const float* __restrict__ cand_val, const int* __restrict__ cand_idx,
                       int* __restrict__ cand32)
{
    const int row  = blockIdx.x * 4 + (threadIdx.x >> 6);
    const int lane = threadIdx.x & 63;
    const size_t base = (size_t)row * CANDS_PER_ROW;
    float lv[LCAP]; int li[LCAP];
#pragma unroll
    for (int i = 0; i < LCAP; ++i) { lv[i] = -3.4e38f; li[i] = 0x7fffffff; }
#pragma unroll 1
    for (int m = 0; m < CANDS_PER_ROW / 64; ++m) {                // 24 per lane
        const int p = lane + (m << 6);
        insN<LCAP>(cand_val[base + p], cand_idx[base + p], lv, li);
    }
    int out = 0;
#pragma unroll 1
    for (int it = 0; it < NCAND; ++it) {
        float rv = lv[0]; int ridx = li[0];
#pragma unroll
        for (int off = 1; off < 64; off <<= 1) {
            const float ov = __shfl_xor(rv, off);
            const int   oi = __shfl_xor(ridx, off);
            if (ov > rv || (ov == rv && oi < ridx)) { rv = ov; ridx = oi; }
        }
        if (lane == it) out = ridx;
        if (li[0] == ridx) {
#pragma unroll
            for (int i = 0; i < LCAP - 1; ++i) { lv[i] = lv[i + 1]; li[i] = li[i + 1]; }
            lv[LCAP - 1] = -3.4e38f; li[LCAP - 1] = 0x7fffffff;
        }
    }
    if (lane < NCAND) cand32[(size_t)row * NCAND + lane] = out;
}

// ---------------- Kernel B2: exact fp32 rescore of 20 candidates -> final top-16 ----------------
__global__ __launch_bounds__(256)
void rescore_kernel(const float* __restrict__ Q, const float* __restrict__ K,
                    const int* __restrict__ cand32, int* __restrict__ topk)
{
    const int row  = blockIdx.x;
    const int wv   = threadIdx.x >> 6;
    const int lane = threadIdx.x & 63;
    __shared__ float sv[NCAND];
    __shared__ int   si[NCAND];
    if (threadIdx.x < NCAND) si[threadIdx.x] = cand32[(size_t)row * NCAND + threadIdx.x];
    float4 qv[4];
#pragma unroll
    for (int u = 0; u < 4; ++u)
        qv[u] = ((const float4*)(Q + (size_t)row * DDIM))[(u << 6) + lane];
    __syncthreads();
#pragma unroll 1
    for (int c = 0; c < NCAND / 4; ++c) {
        const int slot = wv * (NCAND / 4) + c;
        const float* kr = K + (size_t)si[slot] * DDIM;
        float s = 0.f;
#pragma unroll
        for (int u = 0; u < 4; ++u) {
            const float4 kv = ((const float4*)kr)[(u << 6) + lane];
            s += kv.x * qv[u].x + kv.y * qv[u].y + kv.z * qv[u].z + kv.w * qv[u].w;
        }
#pragma unroll
        for (int off = 32; off >= 1; off >>= 1) s += __shfl_xor(s, off);
        if (lane == 0) sv[slot] = s;
    }
    __syncthreads();
    if (wv == 0) {
        float v = (lane < NCAND) ? sv[lane] : -3.4e38f;
        int  id = (lane < NCAND) ? si[lane] : 0x7fffffff;
        int out = 0;
#pragma unroll 1
        for (int it = 0; it < KSEL; ++it) {
            float rv = v; int ridx = id;
#pragma unroll
            for (int off = 1; off < 64; off <<= 1) {
                const float ov = __shfl_xor(rv, off);
                const int   oi = __shfl_xor(ridx, off);
                if (ov > rv || (ov == rv && oi < ridx)) { rv = ov; ridx = oi; }
            }
            if (lane == it) out = ridx;
            if (id == ridx) v = -3.4e38f;
        }
        if (lane < KSEL) topk[(size_t)row * KSEL + lane] = out;
    }
}

// ---------------- Kernel C: X(fp32) x W projections (LO=1 3-term / LO=0 1-term) ----------------
template <int LO>
__global__ __launch_bounds__(256)
void proj_split_kernel(const float* __restrict__ X, const unsigned short* __restrict__ Whi,
                       const unsigned short* __restrict__ Wlo, const float* __restrict__ bias,
                       void* __restrict__ outp, const int store_bf16)
{
    constexpr int WOFF = LO ? 32768 : 16384;
    __shared__ char smem[LO ? 65536 : 32768];
    const int tid  = threadIdx.x;
    const int lane = tid & 63;
    const int w    = tid >> 6;
    const int wr   = w >> 1, wc = w & 1;
    const int row0 = blockIdx.x * 128;
    const int col0 = blockIdx.y * 128;

    const f32x4 zero = {0.f, 0.f, 0.f, 0.f};
    f32x4 acc[4][4];
#pragma unroll
    for (int mi = 0; mi < 4; ++mi)
#pragma unroll
        for (int ni = 0; ni < 4; ++ni) acc[mi][ni] = zero;

    const int srow = lane >> 3;
    const int scol = (((lane & 7) ^ srow) << 4);
    const int xr = tid >> 1, xh = tid & 1;

    for (int step = 0; step < 16; ++step) {
        const int kbyte = step << 7;
        const int k0    = step << 6;
        __syncthreads();
#pragma unroll
        for (int i = 0; i < (LO ? 8 : 4); ++i) {
            const int chunk = w + (i << 2);
            const int plane = chunk >> 4;
            const int r     = ((chunk & 15) << 3) + srow;
            const unsigned short* Wb = plane ? Wlo : Whi;
            const char* src = (const char*)Wb + (((size_t)(col0 + r)) << 11) + kbyte + scol;
            gload16(src, smem + WOFF + (chunk << 10));
        }
        {
            const float* Xp = X + (size_t)(row0 + xr) * DDIM + k0 + xh * 32;
            float4 xa[8];
#pragma unroll
            for (int i = 0; i < 8; ++i) xa[i] = ((const float4*)Xp)[i];
            const int xbase = xr * 128;
#pragma unroll
            for (int s4 = 0; s4 < 4; ++s4) {
                const float4 a = xa[2 * s4], b = xa[2 * s4 + 1];
                uint4 hw, lw;
                if (LO) {
                    split2(a.x, a.y, hw.x, lw.x);
                    split2(a.z, a.w, hw.y, lw.y);
                    split2(b.x, b.y, hw.z, lw.z);
                    split2(b.z, b.w, hw.w, lw.w);
                } else {
                    hw.x = (unsigned int)f2bf(a.x) | ((unsigned int)f2bf(a.y) << 16);
                    hw.y = (unsigned int)f2bf(a.z) | ((unsigned int)f2bf(a.w) << 16);
                    hw.z = (unsigned int)f2bf(b.x) | ((unsigned int)f2bf(b.y) << 16);
                    hw.w = (unsigned int)f2bf(b.z) | ((unsigned int)f2bf(b.w) << 16);
                }
                const int off = xbase + ((((xh << 2) + s4) ^ (xr & 7)) << 4);
                *(uint4*)(smem + off) = hw;
                if (LO) *(uint4*)(smem + 16384 + off) = lw;
            }
        }
        asm volatile("s_waitcnt vmcnt(0)" ::: "memory");
        __syncthreads();
#pragma unroll
        for (int kk = 0; kk < 2; ++kk) {
            const int cb = (kk << 6) + ((lane >> 4) << 4);
            bf16x8 ah[4], bh[4];
#pragma unroll
            for (int mi = 0; mi < 4; ++mi) {
                const int r = wr * 64 + mi * 16 + (lane & 15);
                ah[mi] = *(const bf16x8*)(smem + r * 128 + (cb ^ ((r & 7) << 4)));
            }
#pragma unroll
            for (int ni = 0; ni < 4; ++ni) {
                const int r = wc * 64 + ni * 16 + (lane & 15);
                bh[ni] = *(const bf16x8*)(smem + WOFF + r * 128 + (cb ^ ((r & 7) << 4)));
            }
#pragma unroll
            for (int mi = 0; mi < 4; ++mi)
#pragma unroll
                for (int ni = 0; ni < 4; ++ni)
                    acc[mi][ni] = __builtin_amdgcn_mfma_f32_16x16x32_bf16(ah[mi], bh[ni], acc[mi][ni], 0, 0, 0);
            if (LO) {
                bf16x8 al[4];
#pragma unroll
                for (int mi = 0; mi < 4; ++mi) {
                    const int r = wr * 64 + mi * 16 + (lane & 15);
                    al[mi] = *(const bf16x8*)(smem + 16384 + r * 128 + (cb ^ ((r & 7) << 4)));
                }
#pragma unroll
                for (int mi = 0; mi < 4; ++mi)
#pragma unroll
                    for (int ni = 0; ni < 4; ++ni)
                        acc[mi][ni] = __builtin_amdgcn_mfma_f32_16x16x32_bf16(al[mi], bh[ni], acc[mi][ni], 0, 0, 0);
                bf16x8 bl[4];
#pragma unroll
                for (int ni = 0; ni < 4; ++ni) {
                    const int r = wc * 64 + ni * 16 + (lane & 15);
                    bl[ni] = *(const bf16x8*)(smem + WOFF + 16384 + r * 128 + (cb ^ ((r & 7) << 4)));
                }
#pragma unroll
                for (int mi = 0; mi < 4; ++mi)
#pragma unroll
                    for (int ni = 0; ni < 4; ++ni)
                        acc[mi][ni] = __builtin_amdgcn_mfma_f32_16x16x32_bf16(ah[mi], bl[ni], acc[mi][ni], 0, 0, 0);
            }
        }
    }

#pragma unroll
    for (int ni = 0; ni < 4; ++ni) {
        const int col = col0 + wc * 64 + ni * 16 + (lane & 15);
        const float bz = bias[col];
#pragma unroll
        for (int mi = 0; mi < 4; ++mi) {
            const int rbase = row0 + wr * 64 + mi * 16 + ((lane >> 4) << 2);
            const f32x4 v = acc[mi][ni];
#pragma unroll
            for (int j = 0; j < 4; ++j) {
                const float val = v[j] + bz;
                if (store_bf16)
                    ((unsigned short*)outp)[(size_t)(rbase + j) * DDIM + col] = f2bf(val);
                else
                    ((float*)outp)[(size_t)(rbase + j) * DDIM + col] = val;
            }
        }
    }
}

// ---------------- Kernel U: u[t, h*1024+j] = sum_c Qpb[t, h*128+c] * wkT[h][j][c]  (K=128) ----------------
__global__ __launch_bounds__(256)
void ugemm_kernel(const unsigned short* __restrict__ Qpb, const unsigned short* __restrict__ wkT,
                  unsigned short* __restrict__ u)
{
    __shared__ char smem[32768];
    const int tid  = threadIdx.x;
    const int lane = tid & 63;
    const int w    = tid >> 6;
    const int wr   = w >> 1, wc = w & 1;
    const int row0 = blockIdx.x * 128;
    const int j0   = blockIdx.y * 128;
    const int h    = blockIdx.z;

    const f32x4 zero = {0.f, 0.f, 0.f, 0.f};
    f32x4 acc[4][4];
#pragma unroll
    for (int mi = 0; mi < 4; ++mi)
#pragma unroll
        for (int ni = 0; ni < 4; ++ni) acc[mi][ni] = zero;

    const int srow = lane >> 3;
    const int scol = (((lane & 7) ^ srow) << 4);

#pragma unroll 1
    for (int step = 0; step < 2; ++step) {
        const int kbyte = step << 7;
        __syncthreads();
#pragma unroll
        for (int i = 0; i < 8; ++i) {
            const int chunk = w + (i << 2);
            const char* src;
            if (chunk < 16) {
                const int r = (chunk << 3) + srow;
                src = (const char*)Qpb + (((size_t)(row0 + r)) << 11) + h * 256 + kbyte + scol;
            } else {
                const int r = ((chunk - 16) << 3) + srow;
                src = (const char*)wkT + ((size_t)h << 18) + (((size_t)(j0 + r)) << 8) + kbyte + scol;
            }
            gload16(src, smem + (chunk << 10));
        }
        __syncthreads();
#pragma unroll
        for (int kk = 0; kk < 2; ++kk) {
            const int cb = (kk << 6) + ((lane >> 4) << 4);
            bf16x8 af[4], bf[4];
#pragma unroll
            for (int mi = 0; mi < 4; ++mi) {
                const int r = wr * 64 + mi * 16 + (lane & 15);
                af[mi] = *(const bf16x8*)(smem + r * 128 + (cb ^ ((r & 7) << 4)));
            }
#pragma unroll
            for (int ni = 0; ni < 4; ++ni) {
                const int r = wc * 64 + ni * 16 + (lane & 15);
                bf[ni] = *(const bf16x8*)(smem + 16384 + r * 128 + (cb ^ ((r & 7) << 4)));
            }
#pragma unroll
            for (int mi = 0; mi < 4; ++mi)
#pragma unroll
                for (int ni = 0; ni < 4; ++ni)
                    acc[mi][ni] = __builtin_amdgcn_mfma_f32_16x16x32_bf16(af[mi], bf[ni], acc[mi][ni], 0, 0, 0);
        }
    }

#pragma unroll
    for (int ni = 0; ni < 4; ++ni) {
        const int col = j0 + wc * 64 + ni * 16 + (lane & 15);
#pragma unroll
        for (int mi = 0; mi < 4; ++mi) {
            const int rbase = row0 + wr * 64 + mi * 16 + ((lane >> 4) << 2);
            const f32x4 v = acc[mi][ni];
#pragma unroll
            for (int j = 0; j < 4; ++j)
                u[(size_t)(rbase + j) * 8192 + h * 1024 + col] = f2bf(v[j]);
        }
    }
}

// ---------------- Kernel D2: scores from u . raw-K, softmax, z = attn @ raw-V ----------------
__global__ __launch_bounds__(256)
void attn2_kernel(const unsigned short* __restrict__ Khi, const float* __restrict__ mvals,
                  unsigned short* __restrict__ uz, const int* __restrict__ topk)
{
    __shared__ char smem[33344];                 // KV 32KB @0, idx@32768, sc@32832
    int*   idx_s = (int*)(smem + 32768);
    float* sc_s  = (float*)(smem + 32832);       // [8][16]
    const int t   = blockIdx.x;
    const int tid = threadIdx.x;
    if (tid < KSEL) idx_s[tid] = topk[(size_t)t * KSEL + tid];
    __syncthreads();
    // phase 1: stage K (source-swizzled)
#pragma unroll
    for (int i = 0; i < 8; ++i) {
        const int s   = tid + (i << 8);
        const int row = s >> 7, col = s & 127;
        const size_t kb = ((size_t)idx_s[row]) << 11;
        gload16((const char*)Khi + kb + ((col ^ (row & 7)) << 4), smem + (s << 4));
    }
    __syncthreads();
    // scores: pair (h,k) handled by 2 threads (sub halves of 1024 dims)
    {
        const int p = tid >> 1, sub = tid & 1;
        const int h = p >> 4, k = p & 15;
        const unsigned short* urow = uz + (size_t)t * 8192 + h * 1024 + sub * 512;
        float s = 0.f;
#pragma unroll 8
        for (int j = 0; j < 64; ++j) {
            const uint4 uw = *(const uint4*)(urow + (j << 3));
            const uint4 kw = *(const uint4*)(smem + (k << 11) + ((((sub << 6) + j) ^ (k & 7)) << 4));
            s += bf2f((unsigned short)(uw.x & 0xffffu)) * bf2f((unsigned short)(kw.x & 0xffffu))
               + bf2f((unsigned short)(uw.x >> 16))     * bf2f((unsigned short)(kw.x >> 16))
               + bf2f((unsigned short)(uw.y & 0xffffu)) * bf2f((unsigned short)(kw.y & 0xffffu))
               + bf2f((unsigned short)(uw.y >> 16))     * bf2f((unsigned short)(kw.y >> 16))
               + bf2f((unsigned short)(uw.z & 0xffffu)) * bf2f((unsigned short)(kw.z & 0xffffu))
               + bf2f((unsigned short)(uw.z >> 16))     * bf2f((unsigned short)(kw.z >> 16))
               + bf2f((unsigned short)(uw.w & 0xffffu)) * bf2f((unsigned short)(kw.w & 0xffffu))
               + bf2f((unsigned short)(uw.w >> 16))     * bf2f((unsigned short)(kw.w >> 16));
        }
        s += __shfl_xor(s, 1);
        if (sub == 0) sc_s[h * 16 + k] = s;
    }
    __syncthreads();
    // phase 2: stage V fp32 -> bf16 inline into the SAME 32KB
#pragma unroll
    for (int i = 0; i < 8; ++i) {
        const int s   = tid + (i << 8);
        const int row = s >> 7, col8 = s & 127;
        const float* vp = mvals + (((size_t)idx_s[row]) << 10) + (col8 << 3);
        const float4 a = *(const float4*)vp;
        const float4 b = *(const float4*)(vp + 4);
        uint4 o;
        o.x = (unsigned)f2bf(a.x) | ((unsigned)f2bf(a.y) << 16);
        o.y = (unsigned)f2bf(a.z) | ((unsigned)f2bf(a.w) << 16);
        o.z = (unsigned)f2bf(b.x) | ((unsigned)f2bf(b.y) << 16);
        o.w = (unsigned)f2bf(b.z) | ((unsigned)f2bf(b.w) << 16);
        *(uint4*)(smem + (s << 4)) = o;
    }
    __syncthreads();
    // softmax + z (overwrites uz)
    const int h  = tid >> 5;
    const int dp = tid & 31;
    const float scale = 0.08838834764831845f;    // 1/sqrt(128)
    float mxv = -3.4e38f;
#pragma unroll
    for (int n = 0; n < KSEL; ++n) mxv = fmaxf(mxv, sc_s[h * 16 + n]);
    float wgt[KSEL]; float wsum = 0.f;
#pragma unroll
    for (int n = 0; n < KSEL; ++n) { wgt[n] = __expf((sc_s[h * 16 + n] - mxv) * scale); wsum += wgt[n]; }
    const float inv = 1.f / wsum;
#pragma unroll
    for (int n = 0; n < KSEL; ++n) wgt[n] *= inv;
#pragma unroll 1
    for (int j = 0; j < 16; ++j) {
        float z0 = 0.f, z1 = 0.f;
#pragma unroll
        for (int k = 0; k < 16; ++k) {
            const unsigned int vv = *(const unsigned int*)(smem + (k << 11) + (j << 7) + (dp << 2));
            z0 += wgt[k] * bf2f((unsigned short)(vv & 0xffffu));
            z1 += wgt[k] * bf2f((unsigned short)(vv >> 16));
        }
        *(unsigned int*)((char*)uz + (size_t)t * 16384 + (h << 11) + (j << 7) + (dp << 2)) =
            (unsigned int)f2bf(z0) | ((unsigned int)f2bf(z1) << 16);
    }
}

// ---------------- Kernel Z: attn_out[t, h*128+c] = sum_d z[t,h,d]*Wv_h[c,d] + bv ----------------
__global__ __launch_bounds__(256)
void zout_kernel(const unsigned short* __restrict__ z, const unsigned short* __restrict__ IPhi,
                 const float* __restrict__ ipb, float* __restrict__ attn_out)
{
    __shared__ char smem[32768];
    const int tid  = threadIdx.x;
    const int lane = tid & 63;
    const int w    = tid >> 6;
    const int wr   = w >> 1, wc = w & 1;
    const int row0 = blockIdx.x * 128;
    const int h    = blockIdx.y;

    const f32x4 zero = {0.f, 0.f, 0.f, 0.f};
    f32x4 acc[4][4];
#pragma unroll
    for (int mi = 0; mi < 4; ++mi)
#pragma unroll
        for (int ni = 0; ni < 4; ++ni) acc[mi][ni] = zero;

    const int srow = lane >> 3;
    const int scol = (((lane & 7) ^ srow) << 4);

#pragma unroll 1
    for (int step = 0; step < 16; ++step) {
        const int kbyte = step << 7;
        __syncthreads();
#pragma unroll
        for (int i = 0; i < 8; ++i) {
            const int chunk = w + (i << 2);
            const char* src;
            if (chunk < 16) {
                const int r = (chunk << 3) + srow;
                src = (const char*)z + (((size_t)(row0 + r)) << 14) + (h << 11) + kbyte + scol;
            } else {
                const int r = ((chunk - 16) << 3) + srow;
                src = (const char*)IPhi + (((size_t)(2048 + h * 128 + r)) << 11) + kbyte + scol;
            }
            gload16(src, smem + (chunk << 10));
        }
        __syncthreads();
#pragma unroll
        for (int kk = 0; kk < 2; ++kk) {
            const int cb = (kk << 6) + ((lane >> 4) << 4);
            bf16x8 af[4], bf[4];
#pragma unroll
            for (int mi = 0; mi < 4; ++mi) {
                const int r = wr * 64 + mi * 16 + (lane & 15);
                af[mi] = *(const bf16x8*)(smem + r * 128 + (cb ^ ((r & 7) << 4)));
            }
#pragma unroll
            for (int ni = 0; ni < 4; ++ni) {
                const int r = wc * 64 + ni * 16 + (lane & 15);
                bf[ni] = *(const bf16x8*)(smem + 16384 + r * 128 + (cb ^ ((r & 7) << 4)));
            }
#pragma unroll
            for (int mi = 0; mi < 4; ++mi)
#pragma unroll
                for (int ni = 0; ni < 4; ++ni)
                    acc[mi][ni] = __builtin_amdgcn_mfma_f32_16x16x32_bf16(af[mi], bf[ni], acc[mi][ni], 0, 0, 0);
        }
    }

#pragma unroll
    for (int ni = 0; ni < 4; ++ni) {
        const int cl = wc * 64 + ni * 16 + (lane & 15);
        const float bz = ipb[2048 + h * 128 + cl];
#pragma unroll
        for (int mi = 0; mi < 4; ++mi) {
            const int rbase = row0 + wr * 64 + mi * 16 + ((lane >> 4) << 2);
            const f32x4 v = acc[mi][ni];
#pragma unroll
            for (int j = 0; j < 4; ++j)
                attn_out[(size_t)(rbase + j) * 1024 + h * 128 + cl] = v[j] + bz;
        }
    }
}

extern "C" void kernel_launch(void* const* d_in, const int* in_sizes, int n_in,
                              void* d_out, int out_size, void* d_ws, size_t ws_size,
                              hipStream_t stream)
{
    const float* queries = (const float*)d_in[0];
    const float* mkeys   = (const float*)d_in[1];
    const float* mvals   = (const float*)d_in[2];
    const float* ipw     = (const float*)d_in[3];
    const float* ipb     = (const float*)d_in[4];
    const float* opw     = (const float*)d_in[5];
    const float* opb     = (const float*)d_in[6];

    char* ws = (char*)d_ws;
    size_t off = 0;
    auto alloc = [&](size_t bytes) -> char* {
        char* p = ws + off;
        off += (bytes + 255) & ~(size_t)255;
        return p;
    };
    unsigned short* Khi  = (unsigned short*)alloc((size_t)MKEYS * DDIM * 2);    // 67.1 MB
    unsigned short* Qhi  = (unsigned short*)alloc((size_t)NROWS * DDIM * 2);    // 8.4 MB
    unsigned short* IPhi = (unsigned short*)alloc((size_t)3 * DDIM * DDIM * 2); // 6.3 MB
    unsigned short* OPhi = (unsigned short*)alloc((size_t)DDIM * DDIM * 2);     // 2.1 MB
    unsigned short* OPlo = (unsigned short*)alloc((size_t)DDIM * DDIM * 2);     // 2.1 MB
    unsigned short* wkT  = (unsigned short*)alloc((size_t)DDIM * DDIM * 2);     // 2.1 MB
    float* cand_val = (float*)alloc((size_t)NROWS * CANDS_ALLOC * 4);           // 33.55 MB
    int*   cand_idx = (int*)  alloc((size_t)NROWS * CANDS_ALLOC * 4);           // 33.55 MB
    int*   cand32   = (int*)  alloc((size_t)NROWS * NCAND * 4);                 // 0.33 MB
    int*   topk     = (int*)  alloc((size_t)NROWS * KSEL * 4);                  // 0.26 MB
    unsigned short* u = (unsigned short*)alloc((size_t)NROWS * 8 * DDIM * 2);   // 67.1 MB (z in-place)
    // aliases (total ~222 MB <= 235 proven):
    unsigned short* Qpb = (unsigned short*)Qhi;       // Qhi dead after sims
    float* attn_out     = (float*)Khi;                // Khi dead after attn2; zout runs after

    // 0) converts + weight preps
    conv_bf16_kernel<<<2048, 256, 0, stream>>>(queries, Qhi, NROWS * DDIM / 4);
    conv_bf16_kernel<<<2048, 256, 0, stream>>>(mkeys, Khi, MKEYS * DDIM / 4);
    conv_bf16_kernel<<<1024, 256, 0, stream>>>(ipw, IPhi, 3 * DDIM * DDIM / 4);
    split_bf16_kernel<<<512,  256, 0, stream>>>(opw, OPhi, OPlo, DDIM * DDIM / 4);
    wk_transpose_kernel<<<64, 256, 0, stream>>>(ipw, wkT);
    // 1) bf16 similarity GEMM + per-keyblock top-6 (packed)
    sims_mfma_kernel<<<dim3(NROWS / SBM, MKEYS / SBN), 256, 0, stream>>>(Qhi, Khi, cand_val, cand_idx);
    // 2) merge to top-20 candidates
    topk_merge_kernel<<<NROWS / 4, 256, 0, stream>>>(cand_val, cand_idx, cand32);
    // 3) exact fp32 rescore -> final top-16
    rescore_kernel<<<NROWS, 256, 0, stream>>>(queries, mkeys, cand32, topk);
    // 4) q projection (1-term, bf16 out into Qhi region)
    proj_split_kernel<0><<<dim3(NROWS / 128, 8), 256, 0, stream>>>(queries, IPhi, IPhi, ipb, Qpb, 1);
    // 5) u = Qpb @ wkT per head (K=128)
    ugemm_kernel<<<dim3(NROWS / 128, 8, 8), 256, 0, stream>>>(Qpb, wkT, u);
    // 6) scores/softmax/z over raw K (bf16) and raw V (fp32, converted inline); z overwrites u
    attn2_kernel<<<NROWS, 256, 0, stream>>>(Khi, mvals, u, topk);
    // 7) attn_out = z @ Wv^T + bv (into Khi region)
    zout_kernel<<<dim3(NROWS / 128, 8), 256, 0, stream>>>(u, IPhi, ipb, attn_out);
    // 8) output projection (3-term) -> d_out (f32)
    proj_split_kernel<1><<<dim3(NROWS / 128, 8), 256, 0, stream>>>(attn_out, OPhi, OPlo, opb, d_out, 0);
}

// Round 16
// 724.855 us; speedup vs baseline: 3.4588x; 1.0512x over previous
//
#include <hip/hip_runtime.h>
#include <hip/hip_bf16.h>

#define NROWS 4096    // B*S
#define DDIM  1024
#define MKEYS 32768
#define HDIM  128
#define KSEL  16
#define NCAND 20      // rescored candidates per row
#define BTOP  6       // per-keyblock kept candidates
#define LCAP  8       // merge per-lane list depth

// ---- sims MFMA GEMM geometry: m97-style 128x128 tile, 4 waves, 32KB LDS ----
#define SBM 128
#define SBN 128
#define SNKB (MKEYS / SBN)            // 256 key blocks
#define CANDS_PER_ROW (SNKB * BTOP)   // 1536
#define NSTEPS 16                     // K = 1024 bf16, BK = 64

typedef short bf16x8 __attribute__((ext_vector_type(8)));
typedef float f32x4  __attribute__((ext_vector_type(4)));

__device__ __forceinline__ float bf2f(unsigned short u) {
    union { unsigned int i; float f; } x; x.i = ((unsigned int)u) << 16; return x.f;
}
__device__ __forceinline__ unsigned short f2bf(float f) {
    union { float f; unsigned int u; } v; v.f = f;
    unsigned int r = (v.u + 0x7fffu + ((v.u >> 16) & 1u)) >> 16;   // RNE
    return (unsigned short)r;
}
__device__ __forceinline__ void gload16(const void* g, const void* l) {
    __builtin_amdgcn_global_load_lds((const __attribute__((address_space(1))) unsigned int*)g,
                                     (__attribute__((address_space(3))) unsigned int*)l, 16, 0, 0);
}
__device__ __forceinline__ void split2(float x0, float x1, unsigned int& hp, unsigned int& lp) {
    union { float f; unsigned int u; } u0, u1;
    u0.f = x0; u1.f = x1;
    hp = (u0.u >> 16) | (u1.u & 0xffff0000u);
    const float r0 = x0 - bf2f((unsigned short)(u0.u >> 16));
    const float r1 = x1 - bf2f((unsigned short)(u1.u >> 16));
    lp = (unsigned int)f2bf(r0) | ((unsigned int)f2bf(r1) << 16);
}

// ---------------- fp32 -> bf16 (RNE) ----------------
__global__ __launch_bounds__(256)
void conv_bf16_kernel(const float* __restrict__ x, unsigned short* __restrict__ hi, const int n4)
{
    int i = blockIdx.x * 256 + threadIdx.x;
    const int stride = gridDim.x * 256;
    for (; i < n4; i += stride) {
        const float4 f = ((const float4*)x)[i];
        ushort4 h;
        h.x = f2bf(f.x); h.y = f2bf(f.y); h.z = f2bf(f.z); h.w = f2bf(f.w);
        ((ushort4*)hi)[i] = h;
    }
}

// ---------------- wkT[h][j][c] = bf16(ipw[1024 + h*128 + c][j]) — coalesced LDS transpose ----------------
__global__ __launch_bounds__(256)
void wk_transpose_kernel(const float* __restrict__ ipw, unsigned short* __restrict__ wkT)
{
    __shared__ unsigned short T[128 * 129];
    const int bx  = blockIdx.x;
    const int h   = bx >> 3, j0 = bx & 7;
    const int tid = threadIdx.x;
#pragma unroll 8
    for (int i = 0; i < 64; ++i) {
        const int idx = (i << 8) + tid;
        const int c = idx >> 7, j = idx & 127;
        T[c * 129 + j] = f2bf(ipw[((size_t)(1024 + h * 128 + c)) * 1024 + j0 * 128 + j]);
    }
    __syncthreads();
#pragma unroll
    for (int i = 0; i < 8; ++i) {
        const int g  = (i << 8) + tid;
        const int j  = g >> 4, c0 = (g & 15) << 3;
        uint4 o;
        o.x = (unsigned)T[(c0 + 0) * 129 + j] | ((unsigned)T[(c0 + 1) * 129 + j] << 16);
        o.y = (unsigned)T[(c0 + 2) * 129 + j] | ((unsigned)T[(c0 + 3) * 129 + j] << 16);
        o.z = (unsigned)T[(c0 + 4) * 129 + j] | ((unsigned)T[(c0 + 5) * 129 + j] << 16);
        o.w = (unsigned)T[(c0 + 6) * 129 + j] | ((unsigned)T[(c0 + 7) * 129 + j] << 16);
        *(uint4*)(wkT + ((size_t)h << 17) + ((size_t)(j0 * 128 + j) << 7) + c0) = o;
    }
}

// ---------------- Kernel A: sims(bf16) = Qhi.Khi^T, 128x128; packed branch-free top-6 epilogue ----------------
// Working pack: bits[31:8] sortable score, bits[7:0] in-block idx. Stored pack: bits[31:15]
// truncated score (17b), bits[14:0] global key idx (trunc err <=0.3 << rank-24 margin 3.3).
__global__ __launch_bounds__(256)
void sims_mfma_kernel(const unsigned short* __restrict__ Qhi, const unsigned short* __restrict__ Khi,
                      unsigned int* __restrict__ cand_packed)
{
    __shared__ char smem[32768];
    const int tid  = threadIdx.x;
    const int lane = tid & 63;
    const int w    = tid >> 6;
    const int wr   = w >> 1, wc = w & 1;
    const int row0 = blockIdx.x * SBM;
    const int key0 = blockIdx.y * SBN;

    const f32x4 zero = {0.f, 0.f, 0.f, 0.f};
    f32x4 acc[4][4];
#pragma unroll
    for (int mi = 0; mi < 4; ++mi)
#pragma unroll
        for (int ni = 0; ni < 4; ++ni) acc[mi][ni] = zero;

    const int srow = lane >> 3;
    const int scol = (((lane & 7) ^ srow) << 4);

#pragma unroll 1
    for (int step = 0; step < NSTEPS; ++step) {
        const int kbyte = step << 7;
        __syncthreads();
#pragma unroll
        for (int i = 0; i < 8; ++i) {
            const int chunk = w + (i << 2);
            const char* src;
            if (chunk < 16) {
                const int r = (chunk << 3) + srow;
                src = (const char*)Qhi + (((size_t)(row0 + r)) << 11) + kbyte + scol;
            } else {
                const int r = ((chunk - 16) << 3) + srow;
                src = (const char*)Khi + (((size_t)(key0 + r)) << 11) + kbyte + scol;
            }
            gload16(src, smem + (chunk << 10));
        }
        __syncthreads();
#pragma unroll
        for (int kk = 0; kk < 2; ++kk) {
            const int cb = (kk << 6) + ((lane >> 4) << 4);
            bf16x8 af[4], bf[4];
#pragma unroll
            for (int mi = 0; mi < 4; ++mi) {
                const int r = wr * 64 + mi * 16 + (lane & 15);
                af[mi] = *(const bf16x8*)(smem + r * 128 + (cb ^ ((r & 7) << 4)));
            }
#pragma unroll
            for (int ni = 0; ni < 4; ++ni) {
                const int r = wc * 64 + ni * 16 + (lane & 15);
                bf[ni] = *(const bf16x8*)(smem + 16384 + r * 128 + (cb ^ ((r & 7) << 4)));
            }
#pragma unroll
            for (int mi = 0; mi < 4; ++mi)
#pragma unroll
                for (int ni = 0; ni < 4; ++ni)
                    acc[mi][ni] = __builtin_amdgcn_mfma_f32_16x16x32_bf16(af[mi], bf[ni], acc[mi][ni], 0, 0, 0);
        }
    }

    // ---- packed top-6: 4 passes of 32 cols through LDS C tile [128][33] f32 ----
    unsigned int lp[BTOP];
#pragma unroll
    for (int i = 0; i < BTOP; ++i) lp[i] = 0u;
    float* C_lds = (float*)smem;
    const int rowt = tid & 127;
    const int half = tid >> 7;

#pragma unroll
    for (int q = 0; q < 4; ++q) {
        __syncthreads();
        if (wc == (q >> 1)) {
#pragma unroll
            for (int mi = 0; mi < 4; ++mi)
#pragma unroll
                for (int nn = 0; nn < 2; ++nn) {
                    const int ni = ((q & 1) << 1) + nn;
                    const int r  = wr * 64 + mi * 16 + ((lane >> 4) << 2);
                    const int c  = (nn << 4) + (lane & 15);
                    const f32x4 v = acc[mi][ni];
#pragma unroll
                    for (int j = 0; j < 4; ++j) C_lds[(r + j) * 33 + c] = v[j];
                }
        }
        __syncthreads();
        const int lbase = (q << 5) + (half << 4);      // in-block key index base
#pragma unroll
        for (int cc = 0; cc < 16; ++cc) {
            const unsigned int ub = __float_as_uint(C_lds[rowt * 33 + (half << 4) + cc]);
            unsigned int p = ub ^ ((unsigned int)((int)ub >> 31) | 0x80000000u);
            p = (p & 0xFFFFFF00u) | (unsigned int)(lbase + cc);
#pragma unroll
            for (int i = 0; i < BTOP; ++i) {           // unconditional bubble: 2 VALU/level
                const unsigned int hi2 = p > lp[i] ? p : lp[i];
                p = p > lp[i] ? lp[i] : p;
                lp[i] = hi2;
            }
        }
    }
    // merge the two half-lists per row (packed; stride 9 -> conflict-free)
    __syncthreads();
    unsigned int* mp = (unsigned int*)smem;            // [128][9]
    if (half == 1) {
#pragma unroll
        for (int i = 0; i < BTOP; ++i) mp[rowt * 9 + i] = lp[i];
    }
    __syncthreads();
    if (half == 0) {
#pragma unroll
        for (int i = 0; i < BTOP; ++i) {
            unsigned int p = mp[rowt * 9 + i];
#pragma unroll
            for (int k = 0; k < BTOP; ++k) {
                const unsigned int hi2 = p > lp[k] ? p : lp[k];
                p = p > lp[k] ? lp[k] : p;
                lp[k] = hi2;
            }
        }
        const size_t o = (((size_t)(row0 + rowt)) * SNKB + blockIdx.y) * BTOP;
#pragma unroll
        for (int i = 0; i < BTOP; ++i)                 // repack: 17b value | 15b global idx
            cand_packed[o + i] = (lp[i] & 0xFFFF8000u) | (unsigned int)(key0 + (int)(lp[i] & 0xFFu));
    }
}

// ---------------- Kernel B: packed merge -> top-20 idx per row ----------------
// Per-lane top-8 packed bubble over 24 values, then 20 bfly-max selections.
// Packed uniqueness (15-bit idx field) makes winner-removal exact.
__global__ __launch_bounds__(256)
void topk_merge_kernel(const unsigned int* __restrict__ cand_packed, int* __restrict__ cand32)
{
    const int row  = blockIdx.x * 4 + (threadIdx.x >> 6);
    const int lane = threadIdx.x & 63;
    const size_t base = (size_t)row * CANDS_PER_ROW;
    unsigned int lp[LCAP];
#pragma unroll
    for (int i = 0; i < LCAP; ++i) lp[i] = 0u;
#pragma unroll 1
    for (int m = 0; m < CANDS_PER_ROW / 64; ++m) {                // 24 per lane
        unsigned int p = cand_packed[base + lane + (m << 6)];
#pragma unroll
        for (int i = 0; i < LCAP; ++i) {
            const unsigned int hi2 = p > lp[i] ? p : lp[i];
            p = p > lp[i] ? lp[i] : p;
            lp[i] = hi2;
        }
    }
    int out = 0;
#pragma unroll 1
    for (int it = 0; it < NCAND; ++it) {
        unsigned int r = lp[0];
#pragma unroll
        for (int off = 1; off < 64; off <<= 1) {
            const unsigned int orv = __shfl_xor(r, off);
            r = orv > r ? orv : r;
        }
        if (lane == it) out = (int)(r & 0x7FFFu);
        if (lp[0] == r) {                              // unique winner pops head
#pragma unroll
            for (int i = 0; i < LCAP - 1; ++i) lp[i] = lp[i + 1];
            lp[LCAP - 1] = 0u;
        }
    }
    if (lane < NCAND) cand32[(size_t)row * NCAND + lane] = out;
}

// ---------------- Kernel B2: exact fp32 rescore of 20 candidates -> final top-16 ----------------
__global__ __launch_bounds__(256)
void rescore_kernel(const float* __restrict__ Q, const float* __restrict__ K,
                    const int* __restrict__ cand32, int* __restrict__ topk)
{
    const int row  = blockIdx.x;
    const int wv   = threadIdx.x >> 6;
    const int lane = threadIdx.x & 63;
    __shared__ float sv[NCAND];
    __shared__ int   si[NCAND];
    if (threadIdx.x < NCAND) si[threadIdx.x] = cand32[(size_t)row * NCAND + threadIdx.x];
    float4 qv[4];
#pragma unroll
    for (int u = 0; u < 4; ++u)
        qv[u] = ((const float4*)(Q + (size_t)row * DDIM))[(u << 6) + lane];
    __syncthreads();
#pragma unroll 1
    for (int c = 0; c < NCAND / 4; ++c) {
        const int slot = wv * (NCAND / 4) + c;
        const float* kr = K + (size_t)si[slot] * DDIM;
        float s = 0.f;
#pragma unroll
        for (int u = 0; u < 4; ++u) {
            const float4 kv = ((const float4*)kr)[(u << 6) + lane];
            s += kv.x * qv[u].x + kv.y * qv[u].y + kv.z * qv[u].z + kv.w * qv[u].w;
        }
#pragma unroll
        for (int off = 32; off >= 1; off >>= 1) s += __shfl_xor(s, off);
        if (lane == 0) sv[slot] = s;
    }
    __syncthreads();
    if (wv == 0) {
        float v = (lane < NCAND) ? sv[lane] : -3.4e38f;
        int  id = (lane < NCAND) ? si[lane] : 0x7fffffff;
        int out = 0;
#pragma unroll 1
        for (int it = 0; it < KSEL; ++it) {
            float rv = v; int ridx = id;
#pragma unroll
            for (int off = 1; off < 64; off <<= 1) {
                const float ov = __shfl_xor(rv, off);
                const int   oi = __shfl_xor(ridx, off);
                if (ov > rv || (ov == rv && oi < ridx)) { rv = ov; ridx = oi; }
            }
            if (lane == it) out = ridx;
            if (id == ridx) v = -3.4e38f;
        }
        if (lane < KSEL) topk[(size_t)row * KSEL + lane] = out;
    }
}

// ---------------- Kernel C: X(fp32) x W 1-term projection (bf16 W, inline X convert) ----------------
__global__ __launch_bounds__(256)
void proj_split_kernel(const float* __restrict__ X, const unsigned short* __restrict__ Whi,
                       const float* __restrict__ bias, void* __restrict__ outp,
                       const int store_bf16)
{
    __shared__ char smem[32768];
    const int tid  = threadIdx.x;
    const int lane = tid & 63;
    const int w    = tid >> 6;
    const int wr   = w >> 1, wc = w & 1;
    const int row0 = blockIdx.x * 128;
    const int col0 = blockIdx.y * 128;

    const f32x4 zero = {0.f, 0.f, 0.f, 0.f};
    f32x4 acc[4][4];
#pragma unroll
    for (int mi = 0; mi < 4; ++mi)
#pragma unroll
        for (int ni = 0; ni < 4; ++ni) acc[mi][ni] = zero;

    const int srow = lane >> 3;
    const int scol = (((lane & 7) ^ srow) << 4);
    const int xr = tid >> 1, xh = tid & 1;

    for (int step = 0; step < 16; ++step) {
        const int kbyte = step << 7;
        const int k0    = step << 6;
        __syncthreads();
#pragma unroll
        for (int i = 0; i < 4; ++i) {
            const int chunk = w + (i << 2);            // 0..15
            const int r     = (chunk << 3) + srow;
            const char* src = (const char*)Whi + (((size_t)(col0 + r)) << 11) + kbyte + scol;
            gload16(src, smem + 16384 + (chunk << 10));
        }
        {
            const float* Xp = X + (size_t)(row0 + xr) * DDIM + k0 + xh * 32;
            float4 xa[8];
#pragma unroll
            for (int i = 0; i < 8; ++i) xa[i] = ((const float4*)Xp)[i];
            const int xbase = xr * 128;
#pragma unroll
            for (int s4 = 0; s4 < 4; ++s4) {
                const float4 a = xa[2 * s4], b = xa[2 * s4 + 1];
                uint4 hw;
                hw.x = (unsigned int)f2bf(a.x) | ((unsigned int)f2bf(a.y) << 16);
                hw.y = (unsigned int)f2bf(a.z) | ((unsigned int)f2bf(a.w) << 16);
                hw.z = (unsigned int)f2bf(b.x) | ((unsigned int)f2bf(b.y) << 16);
                hw.w = (unsigned int)f2bf(b.z) | ((unsigned int)f2bf(b.w) << 16);
                const int off = xbase + ((((xh << 2) + s4) ^ (xr & 7)) << 4);
                *(uint4*)(smem + off) = hw;
            }
        }
        asm volatile("s_waitcnt vmcnt(0)" ::: "memory");
        __syncthreads();
#pragma unroll
        for (int kk = 0; kk < 2; ++kk) {
            const int cb = (kk << 6) + ((lane >> 4) << 4);
            bf16x8 ah[4], bh[4];
#pragma unroll
            for (int mi = 0; mi < 4; ++mi) {
                const int r = wr * 64 + mi * 16 + (lane & 15);
                ah[mi] = *(const bf16x8*)(smem + r * 128 + (cb ^ ((r & 7) << 4)));
            }
#pragma unroll
            for (int ni = 0; ni < 4; ++ni) {
                const int r = wc * 64 + ni * 16 + (lane & 15);
                bh[ni] = *(const bf16x8*)(smem + 16384 + r * 128 + (cb ^ ((r & 7) << 4)));
            }
#pragma unroll
            for (int mi = 0; mi < 4; ++mi)
#pragma unroll
                for (int ni = 0; ni < 4; ++ni)
                    acc[mi][ni] = __builtin_amdgcn_mfma_f32_16x16x32_bf16(ah[mi], bh[ni], acc[mi][ni], 0, 0, 0);
        }
    }

#pragma unroll
    for (int ni = 0; ni < 4; ++ni) {
        const int col = col0 + wc * 64 + ni * 16 + (lane & 15);
        const float bz = bias[col];
#pragma unroll
        for (int mi = 0; mi < 4; ++mi) {
            const int rbase = row0 + wr * 64 + mi * 16 + ((lane >> 4) << 2);
            const f32x4 v = acc[mi][ni];
#pragma unroll
            for (int j = 0; j < 4; ++j) {
                const float val = v[j] + bz;
                if (store_bf16)
                    ((unsigned short*)outp)[(size_t)(rbase + j) * DDIM + col] = f2bf(val);
                else
                    ((float*)outp)[(size_t)(rbase + j) * DDIM + col] = val;
            }
        }
    }
}

// ---------------- Kernel U: u[t, h*1024+j] = sum_c Qpb[t, h*128+c] * wkT[h][j][c]  (K=128) ----------------
__global__ __launch_bounds__(256)
void ugemm_kernel(const unsigned short* __restrict__ Qpb, const unsigned short* __restrict__ wkT,
                  unsigned short* __restrict__ u)
{
    __shared__ char smem[32768];
    const int tid  = threadIdx.x;
    const int lane = tid & 63;
    const int w    = tid >> 6;
    const int wr   = w >> 1, wc = w & 1;
    const int row0 = blockIdx.x * 128;
    const int j0   = blockIdx.y * 128;
    const int h    = blockIdx.z;

    const f32x4 zero = {0.f, 0.f, 0.f, 0.f};
    f32x4 acc[4][4];
#pragma unroll
    for (int mi = 0; mi < 4; ++mi)
#pragma unroll
        for (int ni = 0; ni < 4; ++ni) acc[mi][ni] = zero;

    const int srow = lane >> 3;
    const int scol = (((lane & 7) ^ srow) << 4);

#pragma unroll 1
    for (int step = 0; step < 2; ++step) {
        const int kbyte = step << 7;
        __syncthreads();
#pragma unroll
        for (int i = 0; i < 8; ++i) {
            const int chunk = w + (i << 2);
            const char* src;
            if (chunk < 16) {
                const int r = (chunk << 3) + srow;
                src = (const char*)Qpb + (((size_t)(row0 + r)) << 11) + h * 256 + kbyte + scol;
            } else {
                const int r = ((chunk - 16) << 3) + srow;
                src = (const char*)wkT + ((size_t)h << 18) + (((size_t)(j0 + r)) << 8) + kbyte + scol;
            }
            gload16(src, smem + (chunk << 10));
        }
        __syncthreads();
#pragma unroll
        for (int kk = 0; kk < 2; ++kk) {
            const int cb = (kk << 6) + ((lane >> 4) << 4);
            bf16x8 af[4], bf[4];
#pragma unroll
            for (int mi = 0; mi < 4; ++mi) {
                const int r = wr * 64 + mi * 16 + (lane & 15);
                af[mi] = *(const bf16x8*)(smem + r * 128 + (cb ^ ((r & 7) << 4)));
            }
#pragma unroll
            for (int ni = 0; ni < 4; ++ni) {
                const int r = wc * 64 + ni * 16 + (lane & 15);
                bf[ni] = *(const bf16x8*)(smem + 16384 + r * 128 + (cb ^ ((r & 7) << 4)));
            }
#pragma unroll
            for (int mi = 0; mi < 4; ++mi)
#pragma unroll
                for (int ni = 0; ni < 4; ++ni)
                    acc[mi][ni] = __builtin_amdgcn_mfma_f32_16x16x32_bf16(af[mi], bf[ni], acc[mi][ni], 0, 0, 0);
        }
    }

#pragma unroll
    for (int ni = 0; ni < 4; ++ni) {
        const int col = j0 + wc * 64 + ni * 16 + (lane & 15);
#pragma unroll
        for (int mi = 0; mi < 4; ++mi) {
            const int rbase = row0 + wr * 64 + mi * 16 + ((lane >> 4) << 2);
            const f32x4 v = acc[mi][ni];
#pragma unroll
            for (int j = 0; j < 4; ++j)
                u[(size_t)(rbase + j) * 8192 + h * 1024 + col] = f2bf(v[j]);
        }
    }
}

// ---------------- Kernel D2: scores from u . raw-K, softmax, z = attn @ raw-V ----------------
__global__ __launch_bounds__(256)
void attn2_kernel(const unsigned short* __restrict__ Khi, const float* __restrict__ mvals,
                  unsigned short* __restrict__ uz, const int* __restrict__ topk)
{
    __shared__ char smem[33344];                 // KV 32KB @0, idx@32768, sc@32832
    int*   idx_s = (int*)(smem + 32768);
    float* sc_s  = (float*)(smem + 32832);       // [8][16]
    const int t   = blockIdx.x;
    const int tid = threadIdx.x;
    if (tid < KSEL) idx_s[tid] = topk[(size_t)t * KSEL + tid];
    __syncthreads();
    // phase 1: stage K (source-swizzled)
#pragma unroll
    for (int i = 0; i < 8; ++i) {
        const int s   = tid + (i << 8);
        const int row = s >> 7, col = s & 127;
        const size_t kb = ((size_t)idx_s[row]) << 11;
        gload16((const char*)Khi + kb + ((col ^ (row & 7)) << 4), smem + (s << 4));
    }
    __syncthreads();
    // scores: pair (h,k) handled by 2 threads (sub halves of 1024 dims)
    {
        const int p = tid >> 1, sub = tid & 1;
        const int h = p >> 4, k = p & 15;
        const unsigned short* urow = uz + (size_t)t * 8192 + h * 1024 + sub * 512;
        float s = 0.f;
#pragma unroll 8
        for (int j = 0; j < 64; ++j) {
            const uint4 uw = *(const uint4*)(urow + (j << 3));
            const uint4 kw = *(const uint4*)(smem + (k << 11) + ((((sub << 6) + j) ^ (k & 7)) << 4));
            s += bf2f((unsigned short)(uw.x & 0xffffu)) * bf2f((unsigned short)(kw.x & 0xffffu))
               + bf2f((unsigned short)(uw.x >> 16))     * bf2f((unsigned short)(kw.x >> 16))
               + bf2f((unsigned short)(uw.y & 0xffffu)) * bf2f((unsigned short)(kw.y & 0xffffu))
               + bf2f((unsigned short)(uw.y >> 16))     * bf2f((unsigned short)(kw.y >> 16))
               + bf2f((unsigned short)(uw.z & 0xffffu)) * bf2f((unsigned short)(kw.z & 0xffffu))
               + bf2f((unsigned short)(uw.z >> 16))     * bf2f((unsigned short)(kw.z >> 16))
               + bf2f((unsigned short)(uw.w & 0xffffu)) * bf2f((unsigned short)(kw.w & 0xffffu))
               + bf2f((unsigned short)(uw.w >> 16))     * bf2f((unsigned short)(kw.w >> 16));
        }
        s += __shfl_xor(s, 1);
        if (sub == 0) sc_s[h * 16 + k] = s;
    }
    __syncthreads();
    // phase 2: stage V fp32 -> bf16 inline into the SAME 32KB
#pragma unroll
    for (int i = 0; i < 8; ++i) {
        const int s   = tid + (i << 8);
        const int row = s >> 7, col8 = s & 127;
        const float* vp = mvals + (((size_t)idx_s[row]) << 10) + (col8 << 3);
        const float4 a = *(const float4*)vp;
        const float4 b = *(const float4*)(vp + 4);
        uint4 o;
        o.x = (unsigned)f2bf(a.x) | ((unsigned)f2bf(a.y) << 16);
        o.y = (unsigned)f2bf(a.z) | ((unsigned)f2bf(a.w) << 16);
        o.z = (unsigned)f2bf(b.x) | ((unsigned)f2bf(b.y) << 16);
        o.w = (unsigned)f2bf(b.z) | ((unsigned)f2bf(b.w) << 16);
        *(uint4*)(smem + (s << 4)) = o;
    }
    __syncthreads();
    // softmax + z (overwrites uz)
    const int h  = tid >> 5;
    const int dp = tid & 31;
    const float scale = 0.08838834764831845f;    // 1/sqrt(128)
    float mxv = -3.4e38f;
#pragma unroll
    for (int n = 0; n < KSEL; ++n) mxv = fmaxf(mxv, sc_s[h * 16 + n]);
    float wgt[KSEL]; float wsum = 0.f;
#pragma unroll
    for (int n = 0; n < KSEL; ++n) { wgt[n] = __expf((sc_s[h * 16 + n] - mxv) * scale); wsum += wgt[n]; }
    const float inv = 1.f / wsum;
#pragma unroll
    for (int n = 0; n < KSEL; ++n) wgt[n] *= inv;
#pragma unroll 1
    for (int j = 0; j < 16; ++j) {
        float z0 = 0.f, z1 = 0.f;
#pragma unroll
        for (int k = 0; k < 16; ++k) {
            const unsigned int vv = *(const unsigned int*)(smem + (k << 11) + (j << 7) + (dp << 2));
            z0 += wgt[k] * bf2f((unsigned short)(vv & 0xffffu));
            z1 += wgt[k] * bf2f((unsigned short)(vv >> 16));
        }
        *(unsigned int*)((char*)uz + (size_t)t * 16384 + (h << 11) + (j << 7) + (dp << 2)) =
            (unsigned int)f2bf(z0) | ((unsigned int)f2bf(z1) << 16);
    }
}

// ---------------- Kernel Z: attn_out[t, h*128+c] = sum_d z[t,h,d]*Wv_h[c,d] + bv ----------------
__global__ __launch_bounds__(256)
void zout_kernel(const unsigned short* __restrict__ z, const unsigned short* __restrict__ IPhi,
                 const float* __restrict__ ipb, float* __restrict__ attn_out)
{
    __shared__ char smem[32768];
    const int tid  = threadIdx.x;
    const int lane = tid & 63;
    const int w    = tid >> 6;
    const int wr   = w >> 1, wc = w & 1;
    const int row0 = blockIdx.x * 128;
    const int h    = blockIdx.y;

    const f32x4 zero = {0.f, 0.f, 0.f, 0.f};
    f32x4 acc[4][4];
#pragma unroll
    for (int mi = 0; mi < 4; ++mi)
#pragma unroll
        for (int ni = 0; ni < 4; ++ni) acc[mi][ni] = zero;

    const int srow = lane >> 3;
    const int scol = (((lane & 7) ^ srow) << 4);

#pragma unroll 1
    for (int step = 0; step < 16; ++step) {
        const int kbyte = step << 7;
        __syncthreads();
#pragma unroll
        for (int i = 0; i < 8; ++i) {
            const int chunk = w + (i << 2);
            const char* src;
            if (chunk < 16) {
                const int r = (chunk << 3) + srow;
                src = (const char*)z + (((size_t)(row0 + r)) << 14) + (h << 11) + kbyte + scol;
            } else {
                const int r = ((chunk - 16) << 3) + srow;
                src = (const char*)IPhi + (((size_t)(2048 + h * 128 + r)) << 11) + kbyte + scol;
            }
            gload16(src, smem + (chunk << 10));
        }
        __syncthreads();
#pragma unroll
        for (int kk = 0; kk < 2; ++kk) {
            const int cb = (kk << 6) + ((lane >> 4) << 4);
            bf16x8 af[4], bf[4];
#pragma unroll
            for (int mi = 0; mi < 4; ++mi) {
                const int r = wr * 64 + mi * 16 + (lane & 15);
                af[mi] = *(const bf16x8*)(smem + r * 128 + (cb ^ ((r & 7) << 4)));
            }
#pragma unroll
            for (int ni = 0; ni < 4; ++ni) {
                const int r = wc * 64 + ni * 16 + (lane & 15);
                bf[ni] = *(const bf16x8*)(smem + 16384 + r * 128 + (cb ^ ((r & 7) << 4)));
            }
#pragma unroll
            for (int mi = 0; mi < 4; ++mi)
#pragma unroll
                for (int ni = 0; ni < 4; ++ni)
                    acc[mi][ni] = __builtin_amdgcn_mfma_f32_16x16x32_bf16(af[mi], bf[ni], acc[mi][ni], 0, 0, 0);
        }
    }

#pragma unroll
    for (int ni = 0; ni < 4; ++ni) {
        const int cl = wc * 64 + ni * 16 + (lane & 15);
        const float bz = ipb[2048 + h * 128 + cl];
#pragma unroll
        for (int mi = 0; mi < 4; ++mi) {
            const int rbase = row0 + wr * 64 + mi * 16 + ((lane >> 4) << 2);
            const f32x4 v = acc[mi][ni];
#pragma unroll
            for (int j = 0; j < 4; ++j)
                attn_out[(size_t)(rbase + j) * 1024 + h * 128 + cl] = v[j] + bz;
        }
    }
}

extern "C" void kernel_launch(void* const* d_in, const int* in_sizes, int n_in,
                              void* d_out, int out_size, void* d_ws, size_t ws_size,
                              hipStream_t stream)
{
    const float* queries = (const float*)d_in[0];
    const float* mkeys   = (const float*)d_in[1];
    const float* mvals   = (const float*)d_in[2];
    const float* ipw     = (const float*)d_in[3];
    const float* ipb     = (const float*)d_in[4];
    const float* opw     = (const float*)d_in[5];
    const float* opb     = (const float*)d_in[6];

    char* ws = (char*)d_ws;
    size_t off = 0;
    auto alloc = [&](size_t bytes) -> char* {
        char* p = ws + off;
        off += (bytes + 255) & ~(size_t)255;
        return p;
    };
    unsigned short* Khi  = (unsigned short*)alloc((size_t)MKEYS * DDIM * 2);    // 67.1 MB
    unsigned short* Qhi  = (unsigned short*)alloc((size_t)NROWS * DDIM * 2);    // 8.4 MB
    unsigned short* IPhi = (unsigned short*)alloc((size_t)3 * DDIM * DDIM * 2); // 6.3 MB
    unsigned short* OPhi = (unsigned short*)alloc((size_t)DDIM * DDIM * 2);     // 2.1 MB
    unsigned short* wkT  = (unsigned short*)alloc((size_t)DDIM * DDIM * 2);     // 2.1 MB
    unsigned int* cand_packed = (unsigned int*)alloc((size_t)NROWS * CANDS_PER_ROW * 4); // 25.2 MB
    int*   cand32   = (int*)  alloc((size_t)NROWS * NCAND * 4);                 // 0.33 MB
    int*   topk     = (int*)  alloc((size_t)NROWS * KSEL * 4);                  // 0.26 MB
    unsigned short* u = (unsigned short*)alloc((size_t)NROWS * 8 * DDIM * 2);   // 67.1 MB (z in-place)
    // aliases (total ~179 MB <= 235 proven):
    unsigned short* Qpb = (unsigned short*)Qhi;       // Qhi dead after sims
    float* attn_out     = (float*)Khi;                // Khi dead after attn2; zout runs after

    // 0) converts + weight preps
    conv_bf16_kernel<<<2048, 256, 0, stream>>>(queries, Qhi, NROWS * DDIM / 4);
    conv_bf16_kernel<<<2048, 256, 0, stream>>>(mkeys, Khi, MKEYS * DDIM / 4);
    conv_bf16_kernel<<<1024, 256, 0, stream>>>(ipw, IPhi, 3 * DDIM * DDIM / 4);
    conv_bf16_kernel<<<512,  256, 0, stream>>>(opw, OPhi, DDIM * DDIM / 4);
    wk_transpose_kernel<<<64, 256, 0, stream>>>(ipw, wkT);
    // 1) bf16 similarity GEMM + per-keyblock top-6 (packed 17b-val|15b-idx)
    sims_mfma_kernel<<<dim3(NROWS / SBM, MKEYS / SBN), 256, 0, stream>>>(Qhi, Khi, cand_packed);
    // 2) packed merge to top-20 candidate indices
    topk_merge_kernel<<<NROWS / 4, 256, 0, stream>>>(cand_packed, cand32);
    // 3) exact fp32 rescore -> final top-16
    rescore_kernel<<<NROWS, 256, 0, stream>>>(queries, mkeys, cand32, topk);
    // 4) q projection (1-term, bf16 out into Qhi region)
    proj_split_kernel<<<dim3(NROWS / 128, 8), 256, 0, stream>>>(queries, IPhi, ipb, Qpb, 1);
    // 5) u = Qpb @ wkT per head (K=128)
    ugemm_kernel<<<dim3(NROWS / 128, 8, 8), 256, 0, stream>>>(Qpb, wkT, u);
    // 6) scores/softmax/z over raw K (bf16) and raw V (fp32, converted inline); z overwrites u
    attn2_kernel<<<NROWS, 256, 0, stream>>>(Khi, mvals, u, topk);
    // 7) attn_out = z @ Wv^T + bv (into Khi region)
    zout_kernel<<<dim3(NROWS / 128, 8), 256, 0, stream>>>(u, IPhi, ipb, attn_out);
    // 8) output projection (1-term) -> d_out (f32)
    proj_split_kernel<<<dim3(NROWS / 128, 8), 256, 0, stream>>>(attn_out, OPhi, opb, d_out, 0);
}